// Round 1
// baseline (25212.077 us; speedup 1.0000x reference)
//
#include <hip/hip_runtime.h>
#include <hip/hip_cooperative_groups.h>
#include <hip/hip_bf16.h>

namespace cg = cooperative_groups;

#define V_  32000
#define E_  512
#define H_  1024
#define B_  16
#define T_  256
#define H3  3072

// ---------------- embedding gather: EmbG[row][e] = emb[x[row]][e] ----------------
__global__ __launch_bounds__(128) void k_embed(const int* __restrict__ x,
                                               const float* __restrict__ emb,
                                               float* __restrict__ EmbG) {
  const int row = blockIdx.x;                 // row = b*T + t (matches x layout)
  const int idx = x[row];
  const float4* src = (const float4*)(emb + (size_t)idx * E_);
  float4* dst = (float4*)(EmbG + (size_t)row * E_);
  dst[threadIdx.x] = src[threadIdx.x];        // 128 float4 = 512 floats
}

// ---------------- 32x32 tiled transpose: WT[c][r] = W[r][c] ----------------
__global__ __launch_bounds__(256) void k_transpose(const float* __restrict__ W,
                                                   float* __restrict__ WT,
                                                   int R, int C) {
  __shared__ float tile[32][33];
  const int c0 = blockIdx.x * 32, r0 = blockIdx.y * 32;
  const int tx = threadIdx.x & 31, ty = threadIdx.x >> 5;   // ty 0..7
  #pragma unroll
  for (int i = ty; i < 32; i += 8)
    tile[i][tx] = W[(size_t)(r0 + i) * C + c0 + tx];
  __syncthreads();
  #pragma unroll
  for (int i = ty; i < 32; i += 8)
    WT[(size_t)(c0 + i) * R + r0 + tx] = tile[tx][i];
}

// ---------------- f32 GEMM: C[m][n] = sum_k A[m][k]*B[k][n] + bias[n] ----------------
// BM=128 BN=64 BK=16, 256 threads, 8x4 per-thread tile. M%128==0, N%64==0, K%16==0.
__global__ __launch_bounds__(256) void k_gemm(const float* __restrict__ A,
                                              const float* __restrict__ B,
                                              const float* __restrict__ bias,
                                              float* __restrict__ C,
                                              int M, int N, int K, int ldc) {
  __shared__ float As[16][128];
  __shared__ float Bs[16][64];
  const int bn = blockIdx.x * 64;
  const int bm = blockIdx.y * 128;
  const int tid = threadIdx.x;
  const int tr = (tid >> 4) << 3;     // 0..120 step 8
  const int tc = (tid & 15) << 2;     // 0..60 step 4
  const int lr = tid >> 2;            // 0..63  (A-tile load row)
  const int lc = (tid & 3) << 2;      // 0,4,8,12
  const int br = tid >> 4;            // 0..15  (B-tile load row)
  const int bc = (tid & 15) << 2;
  float acc[8][4] = {};
  for (int k0 = 0; k0 < K; k0 += 16) {
    const float4 a0 = *(const float4*)(A + (size_t)(bm + lr) * K + k0 + lc);
    const float4 a1 = *(const float4*)(A + (size_t)(bm + lr + 64) * K + k0 + lc);
    const float4 b0 = *(const float4*)(B + (size_t)(k0 + br) * N + bn + bc);
    __syncthreads();
    As[lc + 0][lr] = a0.x; As[lc + 1][lr] = a0.y; As[lc + 2][lr] = a0.z; As[lc + 3][lr] = a0.w;
    As[lc + 0][lr + 64] = a1.x; As[lc + 1][lr + 64] = a1.y; As[lc + 2][lr + 64] = a1.z; As[lc + 3][lr + 64] = a1.w;
    *(float4*)&Bs[br][bc] = b0;
    __syncthreads();
    #pragma unroll
    for (int kk = 0; kk < 16; ++kk) {
      const float4 av0 = *(const float4*)&As[kk][tr];
      const float4 av1 = *(const float4*)&As[kk][tr + 4];
      const float4 bv  = *(const float4*)&Bs[kk][tc];
      const float a[8] = {av0.x, av0.y, av0.z, av0.w, av1.x, av1.y, av1.z, av1.w};
      #pragma unroll
      for (int i = 0; i < 8; ++i) {
        acc[i][0] += a[i] * bv.x;
        acc[i][1] += a[i] * bv.y;
        acc[i][2] += a[i] * bv.z;
        acc[i][3] += a[i] * bv.w;
      }
    }
  }
  float4 b4;
  b4.x = bias[bn + tc + 0]; b4.y = bias[bn + tc + 1];
  b4.z = bias[bn + tc + 2]; b4.w = bias[bn + tc + 3];
  #pragma unroll
  for (int i = 0; i < 8; ++i) {
    const size_t row = bm + tr + i;
    float4 o;
    o.x = acc[i][0] + b4.x; o.y = acc[i][1] + b4.y;
    o.z = acc[i][2] + b4.z; o.w = acc[i][3] + b4.w;
    *(float4*)(C + row * (size_t)ldc + bn + tc) = o;
  }
}

// ---------------- layer-0 recurrence (cooperative, 1 grid-sync per step) ----------------
// WG w owns h-columns [4w,4w+4). Its 12 WhT gate-rows live in LDS for the whole kernel.
__global__ __launch_bounds__(256, 1) void k_recur(const float* __restrict__ WhT,  // [3H][H]
                                                  const float* __restrict__ GX0,  // [B*T][3H] (incl. bx0)
                                                  const float* __restrict__ bh0,  // [3H]
                                                  float* __restrict__ H0) {       // [B*T][H], row=b*T+t
  cg::grid_group grid = cg::this_grid();
  __shared__ float h_lds[16 * 1028];          // padded stride 1028 (bank spread + 16B align)
  __shared__ float w_lds[12 * 1024];          // [g*4+jj][k]
  const int w = blockIdx.x;
  const int jbase = w << 2;
  const int tid = threadIdx.x;

  for (int i = tid; i < 12 * 256; i += 256) { // 12 rows x 256 float4
    const int cc = i >> 8;
    const int g = cc >> 2, jj = cc & 3;
    const int wrow = g * H_ + jbase + jj;
    ((float4*)w_lds)[i] = ((const float4*)(WhT + (size_t)wrow * H_))[i & 255];
  }

  const int out = tid >> 2;   // 0..63
  const int q   = tid & 3;    // k-quarter
  const int b   = out >> 2;   // 0..15
  const int jj  = out & 3;
  const int j   = jbase + jj;

  const float bhr = bh0[j];
  const float bhz = bh0[H_ + j];
  const float bhn = bh0[2 * H_ + j];

  const float* __restrict__ wr = w_lds + (0 + jj) * 1024 + (q << 8);
  const float* __restrict__ wz = w_lds + (4 + jj) * 1024 + (q << 8);
  const float* __restrict__ wn = w_lds + (8 + jj) * 1024 + (q << 8);
  const float* __restrict__ hq = h_lds + b * 1028 + (q << 8);

  for (int t = 0; t < T_; ++t) {
    __syncthreads();                          // w_lds ready (t=0); h_lds free to overwrite
    if (t == 0) {
      for (int i = tid; i < 16 * 1028; i += 256) h_lds[i] = 0.f;
    } else {
      for (int i = tid; i < 4096; i += 256) { // 16 rows x 256 float4
        const int bb = i >> 8;
        const int kq = i & 255;
        const float4 v = ((const float4*)(H0 + ((size_t)(bb * T_ + t - 1) << 10)))[kq];
        *(float4*)(h_lds + bb * 1028 + (kq << 2)) = v;
      }
    }
    __syncthreads();

    float pr = 0.f, pz = 0.f, pn = 0.f;
    #pragma unroll 4
    for (int k = 0; k < 256; k += 4) {
      const float4 h4 = *(const float4*)(hq + k);
      const float4 r4 = *(const float4*)(wr + k);
      const float4 z4 = *(const float4*)(wz + k);
      const float4 n4 = *(const float4*)(wn + k);
      pr += h4.x * r4.x + h4.y * r4.y + h4.z * r4.z + h4.w * r4.w;
      pz += h4.x * z4.x + h4.y * z4.y + h4.z * z4.z + h4.w * z4.w;
      pn += h4.x * n4.x + h4.y * n4.y + h4.z * n4.z + h4.w * n4.w;
    }
    pr += __shfl_xor(pr, 1); pr += __shfl_xor(pr, 2);
    pz += __shfl_xor(pz, 1); pz += __shfl_xor(pz, 2);
    pn += __shfl_xor(pn, 1); pn += __shfl_xor(pn, 2);

    if (q == 0) {
      const size_t row = (size_t)b * T_ + t;
      const float xr = GX0[row * H3 + j];
      const float xz = GX0[row * H3 + H_ + j];
      const float xn = GX0[row * H3 + 2 * H_ + j];
      const float r = 1.f / (1.f + expf(-(xr + pr + bhr)));
      const float z = 1.f / (1.f + expf(-(xz + pz + bhz)));
      const float n = tanhf(xn + r * (pn + bhn));
      const float hp = h_lds[b * 1028 + j];
      H0[(row << 10) + j] = (1.f - z) * n + z * hp;
    }
    __threadfence();
    grid.sync();
  }
}

// ---------------- layer-1 elementwise (gx|gh precomputed in G1 [rows][6144]) ----------------
__global__ __launch_bounds__(256) void k_gru1(const float* __restrict__ G1,
                                              const float* __restrict__ H0,
                                              float* __restrict__ H1, int row0) {
  const int lrow = blockIdx.x;
  const size_t row = (size_t)row0 + lrow;
  const float* g = G1 + (size_t)lrow * 6144;
  for (int j = threadIdx.x; j < H_; j += 256) {
    const float xr = g[j], xz = g[1024 + j], xn = g[2048 + j];
    const float hr = g[3072 + j], hz = g[4096 + j], hn = g[5120 + j];
    const float h = H0[(row << 10) + j];
    const float r = 1.f / (1.f + expf(-(xr + hr)));
    const float z = 1.f / (1.f + expf(-(xz + hz)));
    const float n = tanhf(xn + r * hn);
    H1[(row << 10) + j] = (1.f - z) * n + z * h;
  }
}

// ---------------- final hidden: out[2][B][H] ----------------
__global__ __launch_bounds__(256) void k_hidden(const float* __restrict__ H0,
                                                const float* __restrict__ H1,
                                                float* __restrict__ out) {
  const int i = blockIdx.x * 256 + threadIdx.x;   // 0..32767
  const int l = i >> 14;
  const int b = (i >> 10) & 15;
  const int j = i & 1023;
  const float* src = l ? H1 : H0;
  out[i] = src[((size_t)(b * T_ + T_ - 1) << 10) + j];
}

extern "C" void kernel_launch(void* const* d_in, const int* in_sizes, int n_in,
                              void* d_out, int out_size, void* d_ws, size_t ws_size,
                              hipStream_t stream) {
  const int*   x   = (const int*)d_in[0];
  const float* emb = (const float*)d_in[1];
  const float* Wx0 = (const float*)d_in[2];
  const float* Wh0 = (const float*)d_in[3];
  const float* bx0 = (const float*)d_in[4];
  const float* bh0 = (const float*)d_in[5];
  const float* Wx1 = (const float*)d_in[6];
  const float* Wh1 = (const float*)d_in[7];
  const float* bx1 = (const float*)d_in[8];
  const float* bh1 = (const float*)d_in[9];
  const float* fcW = (const float*)d_in[10];
  const float* fcb = (const float*)d_in[11];
  float* out = (float*)d_out;

  char* ws = (char*)d_ws;
  float* WhT  = (float*)(ws + 0);          // 12.0 MiB  [3072][1024]
  float* H0   = (float*)(ws + 12582912);   // 16 MiB    [4096][1024]
  float* H1   = (float*)(ws + 29360128);   // 16 MiB    [4096][1024]
  float* EmbG = (float*)(ws + 46137344);   // 8 MiB     [4096][512]   (dead after GX0)
  float* GX0  = (float*)(ws + 54525952);   // 48 MiB    [4096][3072]  (dead after recur)
  float* G1   = (float*)(ws + 46137344);   // 48 MiB    [2048][6144]  reuses EmbG+GX0

  // 1) gather embeddings
  k_embed<<<dim3(B_ * T_), dim3(128), 0, stream>>>(x, emb, EmbG);
  // 2) transpose Wh0 -> WhT for column streaming in recurrence
  k_transpose<<<dim3(H3 / 32, H_ / 32), dim3(256), 0, stream>>>(Wh0, WhT, H_, H3);
  // 3) GX0 = EmbG @ Wx0 + bx0
  k_gemm<<<dim3(H3 / 64, (B_ * T_) / 128), dim3(256), 0, stream>>>(
      EmbG, Wx0, bx0, GX0, B_ * T_, H3, E_, H3);
  // 4) serial layer-0 recurrence (cooperative)
  {
    void* args[] = {(void*)&WhT, (void*)&GX0, (void*)&bh0, (void*)&H0};
    hipLaunchCooperativeKernel((const void*)k_recur, dim3(256), dim3(256), args, 0, stream);
  }
  // 5) layer 1, chunked over rows (2 x 2048) to fit scratch
  for (int chunk = 0; chunk < 2; ++chunk) {
    const float* Ac = H0 + (size_t)chunk * 2048 * H_;
    k_gemm<<<dim3(H3 / 64, 2048 / 128), dim3(256), 0, stream>>>(
        Ac, Wx1, bx1, G1, 2048, H3, H_, 6144);
    k_gemm<<<dim3(H3 / 64, 2048 / 128), dim3(256), 0, stream>>>(
        Ac, Wh1, bh1, G1 + 3072, 2048, H3, H_, 6144);
    k_gru1<<<dim3(2048), dim3(256), 0, stream>>>(G1, H0, H1, chunk * 2048);
  }
  // 6) logits = H1 @ fcW + fcb
  k_gemm<<<dim3(V_ / 64, (B_ * T_) / 128), dim3(256), 0, stream>>>(
      H1, fcW, fcb, out, B_ * T_, V_, H_, V_);
  // 7) final hidden states
  k_hidden<<<dim3(32768 / 256), dim3(256), 0, stream>>>(H0, H1, out + (size_t)B_ * T_ * V_);
}

// Round 2
// 18415.723 us; speedup vs baseline: 1.3691x; 1.3691x over previous
//
#include <hip/hip_runtime.h>
#include <hip/hip_bf16.h>

#define V_  32000
#define E_  512
#define H_  1024
#define B_  16
#define T_  256
#define H3  3072

// Skewed LDS quarter layout: base(row, q) = row*1060 + q*264  (+k within quarter).
// 1060 % 32 == 4, 264 % 32 == 8  ->  (4*row + 8*q + k) mod 32: the 16 (row,q)
// combos per wave spread 2-per-bank-quad => bandwidth-minimal ds_read_b128.
#define WROW_STRIDE 1060
#define QSTRIDE     264
#define W_LDS_FLOATS (11 * WROW_STRIDE + 3 * QSTRIDE + 256)   // 12708
#define H_LDS_FLOATS (15 * WROW_STRIDE + 3 * QSTRIDE + 256)   // 16948

// ---------------- embedding gather ----------------
__global__ __launch_bounds__(128) void k_embed(const int* __restrict__ x,
                                               const float* __restrict__ emb,
                                               float* __restrict__ EmbG) {
  const int row = blockIdx.x;
  const int idx = x[row];
  const float4* src = (const float4*)(emb + (size_t)idx * E_);
  float4* dst = (float4*)(EmbG + (size_t)row * E_);
  dst[threadIdx.x] = src[threadIdx.x];
}

// ---------------- 32x32 tiled transpose ----------------
__global__ __launch_bounds__(256) void k_transpose(const float* __restrict__ W,
                                                   float* __restrict__ WT,
                                                   int R, int C) {
  __shared__ float tile[32][33];
  const int c0 = blockIdx.x * 32, r0 = blockIdx.y * 32;
  const int tx = threadIdx.x & 31, ty = threadIdx.x >> 5;
  #pragma unroll
  for (int i = ty; i < 32; i += 8)
    tile[i][tx] = W[(size_t)(r0 + i) * C + c0 + tx];
  __syncthreads();
  #pragma unroll
  for (int i = ty; i < 32; i += 8)
    WT[(size_t)(c0 + i) * R + r0 + tx] = tile[tx][i];
}

// ---------------- f32 GEMM: BM=128 BN=64 BK=16, 8x4/thread ----------------
__global__ __launch_bounds__(256) void k_gemm(const float* __restrict__ A,
                                              const float* __restrict__ B,
                                              const float* __restrict__ bias,
                                              float* __restrict__ C,
                                              int M, int N, int K, int ldc) {
  __shared__ float As[16][128];
  __shared__ float Bs[16][64];
  const int bn = blockIdx.x * 64;
  const int bm = blockIdx.y * 128;
  const int tid = threadIdx.x;
  const int tr = (tid >> 4) << 3;
  const int tc = (tid & 15) << 2;
  const int lr = tid >> 2;
  const int lc = (tid & 3) << 2;
  const int br = tid >> 4;
  const int bc = (tid & 15) << 2;
  float acc[8][4] = {};
  for (int k0 = 0; k0 < K; k0 += 16) {
    const float4 a0 = *(const float4*)(A + (size_t)(bm + lr) * K + k0 + lc);
    const float4 a1 = *(const float4*)(A + (size_t)(bm + lr + 64) * K + k0 + lc);
    const float4 b0 = *(const float4*)(B + (size_t)(k0 + br) * N + bn + bc);
    __syncthreads();
    As[lc + 0][lr] = a0.x; As[lc + 1][lr] = a0.y; As[lc + 2][lr] = a0.z; As[lc + 3][lr] = a0.w;
    As[lc + 0][lr + 64] = a1.x; As[lc + 1][lr + 64] = a1.y; As[lc + 2][lr + 64] = a1.z; As[lc + 3][lr + 64] = a1.w;
    *(float4*)&Bs[br][bc] = b0;
    __syncthreads();
    #pragma unroll
    for (int kk = 0; kk < 16; ++kk) {
      const float4 av0 = *(const float4*)&As[kk][tr];
      const float4 av1 = *(const float4*)&As[kk][tr + 4];
      const float4 bv  = *(const float4*)&Bs[kk][tc];
      const float a[8] = {av0.x, av0.y, av0.z, av0.w, av1.x, av1.y, av1.z, av1.w};
      #pragma unroll
      for (int i = 0; i < 8; ++i) {
        acc[i][0] += a[i] * bv.x;
        acc[i][1] += a[i] * bv.y;
        acc[i][2] += a[i] * bv.z;
        acc[i][3] += a[i] * bv.w;
      }
    }
  }
  float4 b4;
  b4.x = bias[bn + tc + 0]; b4.y = bias[bn + tc + 1];
  b4.z = bias[bn + tc + 2]; b4.w = bias[bn + tc + 3];
  #pragma unroll
  for (int i = 0; i < 8; ++i) {
    const size_t row = bm + tr + i;
    float4 o;
    o.x = acc[i][0] + b4.x; o.y = acc[i][1] + b4.y;
    o.z = acc[i][2] + b4.z; o.w = acc[i][3] + b4.w;
    *(float4*)(C + row * (size_t)ldc + bn + tc) = o;
  }
}

// ---------------- layer-0 recurrence: skewed LDS + fast 2-level barrier ----------------
__global__ __launch_bounds__(256, 1) void k_recur(const float* __restrict__ WhT,  // [3H][H]
                                                  const float* __restrict__ GX0,  // [B*T][3H]
                                                  const float* __restrict__ bh0,
                                                  float* __restrict__ H0,         // [B*T][H]
                                                  unsigned* __restrict__ bar) {
  __shared__ __align__(16) float w_lds[W_LDS_FLOATS];
  __shared__ __align__(16) float h_lds[H_LDS_FLOATS];
  const int w = blockIdx.x;
  const int jbase = w << 2;
  const int tid = threadIdx.x;

  // one-time W staging: rows 0..3 = r (jj 0..3), 4..7 = z, 8..11 = n
  for (int i = tid; i < 12 * 256; i += 256) {
    const int rr = i >> 8, kq = i & 255;          // kq = float4 index in row
    const int q = kq >> 6, k4 = kq & 63;
    const int wrow = (rr >> 2) * H_ + jbase + (rr & 3);
    const float4 v = ((const float4*)(WhT + (size_t)wrow * H_))[kq];
    *(float4*)&w_lds[rr * WROW_STRIDE + q * QSTRIDE + (k4 << 2)] = v;
  }

  const int out = tid >> 2;   // 0..63
  const int q   = tid & 3;    // k-quarter
  const int b   = out >> 2;   // 0..15
  const int jj  = out & 3;
  const int j   = jbase + jj;

  const float bhr = bh0[j];
  const float bhz = bh0[H_ + j];
  const float bhn = bh0[2 * H_ + j];

  const float* __restrict__ wr = w_lds + (0 + jj) * WROW_STRIDE + q * QSTRIDE;
  const float* __restrict__ wz = w_lds + (4 + jj) * WROW_STRIDE + q * QSTRIDE;
  const float* __restrict__ wn = w_lds + (8 + jj) * WROW_STRIDE + q * QSTRIDE;
  const float* __restrict__ hq = h_lds + b * WROW_STRIDE + q * QSTRIDE;

  for (int t = 0; t < T_; ++t) {
    // stage h_{t-1} into LDS (skewed, lane-consecutive writes within a quarter)
    if (t == 0) {
      for (int i = tid; i < H_LDS_FLOATS; i += 256) h_lds[i] = 0.f;
    } else {
      for (int i = tid; i < 4096; i += 256) {
        const int bb = i >> 8, kq = i & 255;
        const int qq = kq >> 6, k4 = kq & 63;
        const float4 v = ((const float4*)(H0 + ((size_t)(bb * T_ + t - 1) << 10)))[kq];
        *(float4*)&h_lds[bb * WROW_STRIDE + qq * QSTRIDE + (k4 << 2)] = v;
      }
    }
    __syncthreads();

    // prefetch GX0 early (independent of LDS dot)
    float xr = 0.f, xz = 0.f, xn = 0.f;
    if (q == 0) {
      const size_t grow = (size_t)(b * T_ + t) * H3;
      xr = GX0[grow + j];
      xz = GX0[grow + H_ + j];
      xn = GX0[grow + 2 * H_ + j];
    }

    float pr = 0.f, pz = 0.f, pn = 0.f;
    #pragma unroll 4
    for (int k = 0; k < 256; k += 4) {
      const float4 h4 = *(const float4*)(hq + k);
      const float4 r4 = *(const float4*)(wr + k);
      const float4 z4 = *(const float4*)(wz + k);
      const float4 n4 = *(const float4*)(wn + k);
      pr += h4.x * r4.x + h4.y * r4.y + h4.z * r4.z + h4.w * r4.w;
      pz += h4.x * z4.x + h4.y * z4.y + h4.z * z4.z + h4.w * z4.w;
      pn += h4.x * n4.x + h4.y * n4.y + h4.z * n4.z + h4.w * n4.w;
    }
    pr += __shfl_xor(pr, 1); pr += __shfl_xor(pr, 2);
    pz += __shfl_xor(pz, 1); pz += __shfl_xor(pz, 2);
    pn += __shfl_xor(pn, 1); pn += __shfl_xor(pn, 2);

    if (q == 0) {
      const float r = 1.f / (1.f + expf(-(xr + pr + bhr)));
      const float z = 1.f / (1.f + expf(-(xz + pz + bhz)));
      const float n = tanhf(xn + r * (pn + bhn));
      const float hp = h_lds[b * WROW_STRIDE + ((j >> 8) * QSTRIDE) + (j & 255)];
      H0[((size_t)(b * T_ + t) << 10) + j] = (1.f - z) * n + z * hp;
    }

    if (t < T_ - 1) {
      // ---- fast 2-level device barrier (release/acquire, monotonic phase) ----
      __threadfence();                 // each wave releases its own H0 stores
      __syncthreads();
      if (tid == 0) {
        const unsigned g = (unsigned)blockIdx.x >> 4;
        if ((atomicAdd(&bar[g * 64], 1u) & 15u) == 15u) {
          __threadfence();
          if ((atomicAdd(&bar[1024], 1u) & 15u) == 15u) {
            __threadfence();
            atomicAdd(&bar[1088], 1u); // phase = t+1
          }
        }
        while (__hip_atomic_load(&bar[1088], __ATOMIC_ACQUIRE,
                                 __HIP_MEMORY_SCOPE_AGENT) < (unsigned)(t + 1)) {
          __builtin_amdgcn_s_sleep(1);
        }
      }
      __syncthreads();
      __threadfence();                 // acquire: invalidate L1 before next reload
    }
  }
}

// ---------------- layer-1 elementwise ----------------
__global__ __launch_bounds__(256) void k_gru1(const float* __restrict__ G1,
                                              const float* __restrict__ H0,
                                              float* __restrict__ H1, int row0) {
  const int lrow = blockIdx.x;
  const size_t row = (size_t)row0 + lrow;
  const float* g = G1 + (size_t)lrow * 6144;
  for (int j = threadIdx.x; j < H_; j += 256) {
    const float xr = g[j], xz = g[1024 + j], xn = g[2048 + j];
    const float hr = g[3072 + j], hz = g[4096 + j], hn = g[5120 + j];
    const float h = H0[(row << 10) + j];
    const float r = 1.f / (1.f + expf(-(xr + hr)));
    const float z = 1.f / (1.f + expf(-(xz + hz)));
    const float n = tanhf(xn + r * hn);
    H1[(row << 10) + j] = (1.f - z) * n + z * h;
  }
}

// ---------------- final hidden: out[2][B][H] ----------------
__global__ __launch_bounds__(256) void k_hidden(const float* __restrict__ H0,
                                                const float* __restrict__ H1,
                                                float* __restrict__ out) {
  const int i = blockIdx.x * 256 + threadIdx.x;
  const int l = i >> 14;
  const int b = (i >> 10) & 15;
  const int j = i & 1023;
  const float* src = l ? H1 : H0;
  out[i] = src[((size_t)(b * T_ + T_ - 1) << 10) + j];
}

extern "C" void kernel_launch(void* const* d_in, const int* in_sizes, int n_in,
                              void* d_out, int out_size, void* d_ws, size_t ws_size,
                              hipStream_t stream) {
  const int*   x   = (const int*)d_in[0];
  const float* emb = (const float*)d_in[1];
  const float* Wx0 = (const float*)d_in[2];
  const float* Wh0 = (const float*)d_in[3];
  const float* bx0 = (const float*)d_in[4];
  const float* bh0 = (const float*)d_in[5];
  const float* Wx1 = (const float*)d_in[6];
  const float* Wh1 = (const float*)d_in[7];
  const float* bx1 = (const float*)d_in[8];
  const float* bh1 = (const float*)d_in[9];
  const float* fcW = (const float*)d_in[10];
  const float* fcb = (const float*)d_in[11];
  float* out = (float*)d_out;

  char* ws = (char*)d_ws;
  float*    WhT  = (float*)(ws + 0);          // 12 MiB   [3072][1024]
  float*    H0   = (float*)(ws + 12582912);   // 16 MiB   [4096][1024]
  float*    H1   = (float*)(ws + 29360128);   // 16 MiB   [4096][1024]
  float*    EmbG = (float*)(ws + 46137344);   // 8 MiB    (dead after GX0)
  float*    GX0  = (float*)(ws + 54525952);   // 48 MiB   (dead after recur)
  float*    G1   = (float*)(ws + 46137344);   // 48 MiB   reuses EmbG+GX0
  unsigned* bar  = (unsigned*)(ws + 46137344);// 8 KiB    (EmbG region, dead during recur)

  k_embed<<<dim3(B_ * T_), dim3(128), 0, stream>>>(x, emb, EmbG);
  k_transpose<<<dim3(H3 / 32, H_ / 32), dim3(256), 0, stream>>>(Wh0, WhT, H_, H3);
  k_gemm<<<dim3(H3 / 64, (B_ * T_) / 128), dim3(256), 0, stream>>>(
      EmbG, Wx0, bx0, GX0, B_ * T_, H3, E_, H3);

  hipMemsetAsync(bar, 0, 8192, stream);       // zero barrier counters every launch
  {
    void* args[] = {(void*)&WhT, (void*)&GX0, (void*)&bh0, (void*)&H0, (void*)&bar};
    hipLaunchCooperativeKernel((const void*)k_recur, dim3(256), dim3(256), args, 0, stream);
  }

  for (int chunk = 0; chunk < 2; ++chunk) {
    const float* Ac = H0 + (size_t)chunk * 2048 * H_;
    k_gemm<<<dim3(H3 / 64, 2048 / 128), dim3(256), 0, stream>>>(
        Ac, Wx1, bx1, G1, 2048, H3, H_, 6144);
    k_gemm<<<dim3(H3 / 64, 2048 / 128), dim3(256), 0, stream>>>(
        Ac, Wh1, bh1, G1 + 3072, 2048, H3, H_, 6144);
    k_gru1<<<dim3(2048), dim3(256), 0, stream>>>(G1, H0, H1, chunk * 2048);
  }
  k_gemm<<<dim3(V_ / 64, (B_ * T_) / 128), dim3(256), 0, stream>>>(
      H1, fcW, fcb, out, B_ * T_, V_, H_, V_);
  k_hidden<<<dim3(32768 / 256), dim3(256), 0, stream>>>(H0, H1, out + (size_t)B_ * T_ * V_);
}

// Round 3
// 13501.660 us; speedup vs baseline: 1.8673x; 1.3640x over previous
//
#include <hip/hip_runtime.h>
#include <hip/hip_bf16.h>

#define V_  32000
#define E_  512
#define H_  1024
#define B_  16
#define T_  256
#define H3  3072

// Skewed LDS quarter layout: base(row, q) = row*1060 + q*264  (+k within quarter).
#define WROW_STRIDE 1060
#define QSTRIDE     264
#define W_LDS_FLOATS (11 * WROW_STRIDE + 3 * QSTRIDE + 256)   // 12708
#define H_LDS_FLOATS (15 * WROW_STRIDE + 3 * QSTRIDE + 256)   // 16948

#define BAR_REL 8192   // uint index of release flag (WG slots at wg*32, 128B stride)

// ---------------- embedding gather ----------------
__global__ __launch_bounds__(128) void k_embed(const int* __restrict__ x,
                                               const float* __restrict__ emb,
                                               float* __restrict__ EmbG) {
  const int row = blockIdx.x;
  const int idx = x[row];
  const float4* src = (const float4*)(emb + (size_t)idx * E_);
  float4* dst = (float4*)(EmbG + (size_t)row * E_);
  dst[threadIdx.x] = src[threadIdx.x];
}

// ---------------- 32x32 tiled transpose ----------------
__global__ __launch_bounds__(256) void k_transpose(const float* __restrict__ W,
                                                   float* __restrict__ WT,
                                                   int R, int C) {
  __shared__ float tile[32][33];
  const int c0 = blockIdx.x * 32, r0 = blockIdx.y * 32;
  const int tx = threadIdx.x & 31, ty = threadIdx.x >> 5;
  #pragma unroll
  for (int i = ty; i < 32; i += 8)
    tile[i][tx] = W[(size_t)(r0 + i) * C + c0 + tx];
  __syncthreads();
  #pragma unroll
  for (int i = ty; i < 32; i += 8)
    WT[(size_t)(c0 + i) * R + r0 + tx] = tile[tx][i];
}

// ---------------- f32 GEMM: BM=128 BN=64 BK=16, 8x4/thread ----------------
__global__ __launch_bounds__(256) void k_gemm(const float* __restrict__ A,
                                              const float* __restrict__ B,
                                              const float* __restrict__ bias,
                                              float* __restrict__ C,
                                              int M, int N, int K, int ldc) {
  __shared__ float As[16][128];
  __shared__ float Bs[16][64];
  const int bn = blockIdx.x * 64;
  const int bm = blockIdx.y * 128;
  const int tid = threadIdx.x;
  const int tr = (tid >> 4) << 3;
  const int tc = (tid & 15) << 2;
  const int lr = tid >> 2;
  const int lc = (tid & 3) << 2;
  const int br = tid >> 4;
  const int bc = (tid & 15) << 2;
  float acc[8][4] = {};
  for (int k0 = 0; k0 < K; k0 += 16) {
    const float4 a0 = *(const float4*)(A + (size_t)(bm + lr) * K + k0 + lc);
    const float4 a1 = *(const float4*)(A + (size_t)(bm + lr + 64) * K + k0 + lc);
    const float4 b0 = *(const float4*)(B + (size_t)(k0 + br) * N + bn + bc);
    __syncthreads();
    As[lc + 0][lr] = a0.x; As[lc + 1][lr] = a0.y; As[lc + 2][lr] = a0.z; As[lc + 3][lr] = a0.w;
    As[lc + 0][lr + 64] = a1.x; As[lc + 1][lr + 64] = a1.y; As[lc + 2][lr + 64] = a1.z; As[lc + 3][lr + 64] = a1.w;
    *(float4*)&Bs[br][bc] = b0;
    __syncthreads();
    #pragma unroll
    for (int kk = 0; kk < 16; ++kk) {
      const float4 av0 = *(const float4*)&As[kk][tr];
      const float4 av1 = *(const float4*)&As[kk][tr + 4];
      const float4 bv  = *(const float4*)&Bs[kk][tc];
      const float a[8] = {av0.x, av0.y, av0.z, av0.w, av1.x, av1.y, av1.z, av1.w};
      #pragma unroll
      for (int i = 0; i < 8; ++i) {
        acc[i][0] += a[i] * bv.x;
        acc[i][1] += a[i] * bv.y;
        acc[i][2] += a[i] * bv.z;
        acc[i][3] += a[i] * bv.w;
      }
    }
  }
  float4 b4;
  b4.x = bias[bn + tc + 0]; b4.y = bias[bn + tc + 1];
  b4.z = bias[bn + tc + 2]; b4.w = bias[bn + tc + 3];
  #pragma unroll
  for (int i = 0; i < 8; ++i) {
    const size_t row = bm + tr + i;
    float4 o;
    o.x = acc[i][0] + b4.x; o.y = acc[i][1] + b4.y;
    o.z = acc[i][2] + b4.z; o.w = acc[i][3] + b4.w;
    *(float4*)(C + row * (size_t)ldc + bn + tc) = o;
  }
}

// ---------------- layer-0 recurrence: skewed LDS + flag-array barrier ----------------
__global__ __launch_bounds__(256, 1) void k_recur(const float* __restrict__ WhT,  // [3H][H]
                                                  const float* __restrict__ GX0,  // [B*T][3H]
                                                  const float* __restrict__ bh0,
                                                  float* __restrict__ H0,         // [B*T][H]
                                                  unsigned* __restrict__ bar) {
  __shared__ __align__(16) float w_lds[W_LDS_FLOATS];
  __shared__ __align__(16) float h_lds[H_LDS_FLOATS];
  const int w = blockIdx.x;
  const int jbase = w << 2;
  const int tid = threadIdx.x;

  // one-time W staging: rows 0..3 = r (jj 0..3), 4..7 = z, 8..11 = n
  for (int i = tid; i < 12 * 256; i += 256) {
    const int rr = i >> 8, kq = i & 255;
    const int q = kq >> 6, k4 = kq & 63;
    const int wrow = (rr >> 2) * H_ + jbase + (rr & 3);
    const float4 v = ((const float4*)(WhT + (size_t)wrow * H_))[kq];
    *(float4*)&w_lds[rr * WROW_STRIDE + q * QSTRIDE + (k4 << 2)] = v;
  }

  const int out = tid >> 2;   // 0..63
  const int q   = tid & 3;    // k-quarter
  const int b   = out >> 2;   // 0..15
  const int jj  = out & 3;
  const int j   = jbase + jj;

  const float bhr = bh0[j];
  const float bhz = bh0[H_ + j];
  const float bhn = bh0[2 * H_ + j];

  const float* __restrict__ wr = w_lds + (0 + jj) * WROW_STRIDE + q * QSTRIDE;
  const float* __restrict__ wz = w_lds + (4 + jj) * WROW_STRIDE + q * QSTRIDE;
  const float* __restrict__ wn = w_lds + (8 + jj) * WROW_STRIDE + q * QSTRIDE;
  const float* __restrict__ hq = h_lds + b * WROW_STRIDE + q * QSTRIDE;

  // GX0 prefetch for t=0 (independent of recurrence)
  float xr = 0.f, xz = 0.f, xn = 0.f;
  if (q == 0) {
    const size_t grow = (size_t)(b * T_) * H3;
    xr = GX0[grow + j];
    xz = GX0[grow + H_ + j];
    xn = GX0[grow + 2 * H_ + j];
  }

  for (int t = 0; t < T_; ++t) {
    // stage h_{t-1} into LDS (skewed, lane-consecutive writes within a quarter)
    if (t == 0) {
      for (int i = tid; i < H_LDS_FLOATS; i += 256) h_lds[i] = 0.f;
    } else {
      for (int i = tid; i < 4096; i += 256) {
        const int bb = i >> 8, kq = i & 255;
        const int qq = kq >> 6, k4 = kq & 63;
        const float4 v = ((const float4*)(H0 + ((size_t)(bb * T_ + t - 1) << 10)))[kq];
        *(float4*)&h_lds[bb * WROW_STRIDE + qq * QSTRIDE + (k4 << 2)] = v;
      }
    }
    __syncthreads();

    float pr = 0.f, pz = 0.f, pn = 0.f;
    #pragma unroll 4
    for (int k = 0; k < 256; k += 4) {
      const float4 h4 = *(const float4*)(hq + k);
      const float4 r4 = *(const float4*)(wr + k);
      const float4 z4 = *(const float4*)(wz + k);
      const float4 n4 = *(const float4*)(wn + k);
      pr += h4.x * r4.x + h4.y * r4.y + h4.z * r4.z + h4.w * r4.w;
      pz += h4.x * z4.x + h4.y * z4.y + h4.z * z4.z + h4.w * z4.w;
      pn += h4.x * n4.x + h4.y * n4.y + h4.z * n4.z + h4.w * n4.w;
    }
    pr += __shfl_xor(pr, 1); pr += __shfl_xor(pr, 2);
    pz += __shfl_xor(pz, 1); pz += __shfl_xor(pz, 2);
    pn += __shfl_xor(pn, 1); pn += __shfl_xor(pn, 2);

    if (q == 0) {
      const float r = 1.f / (1.f + expf(-(xr + pr + bhr)));
      const float z = 1.f / (1.f + expf(-(xz + pz + bhz)));
      const float n = tanhf(xn + r * (pn + bhn));
      const float hp = h_lds[b * WROW_STRIDE + ((j >> 8) * QSTRIDE) + (j & 255)];
      H0[((size_t)(b * T_ + t) << 10) + j] = (1.f - z) * n + z * hp;
      // prefetch next step's GX0 before the barrier (off the critical path)
      if (t + 1 < T_) {
        const size_t grow = (size_t)(b * T_ + t + 1) * H3;
        xr = GX0[grow + j];
        xz = GX0[grow + H_ + j];
        xn = GX0[grow + 2 * H_ + j];
      }
    }

    if (t < T_ - 1) {
      // ---- flag-array barrier: store-own-slot / wave-parallel poll / 1 release flag ----
      __syncthreads();                               // drains all waves' H0 stores (vmcnt 0)
      const unsigned p = (unsigned)(t + 1);
      if (tid == 0) {
        __threadfence();                             // push dirty L2 to coherence point
        __hip_atomic_store(&bar[(unsigned)w * 32], p,
                           __ATOMIC_RELAXED, __HIP_MEMORY_SCOPE_AGENT);
      }
      if (w == 0) {
        if (tid < 64) {
          for (;;) {
            const unsigned v0 = __hip_atomic_load(&bar[(tid      ) * 32], __ATOMIC_RELAXED, __HIP_MEMORY_SCOPE_AGENT);
            const unsigned v1 = __hip_atomic_load(&bar[(tid +  64) * 32], __ATOMIC_RELAXED, __HIP_MEMORY_SCOPE_AGENT);
            const unsigned v2 = __hip_atomic_load(&bar[(tid + 128) * 32], __ATOMIC_RELAXED, __HIP_MEMORY_SCOPE_AGENT);
            const unsigned v3 = __hip_atomic_load(&bar[(tid + 192) * 32], __ATOMIC_RELAXED, __HIP_MEMORY_SCOPE_AGENT);
            if (__all(v0 >= p && v1 >= p && v2 >= p && v3 >= p)) break;
            __builtin_amdgcn_s_sleep(1);
          }
          if (tid == 0) {
            __threadfence();
            __hip_atomic_store(&bar[BAR_REL], p,
                               __ATOMIC_RELAXED, __HIP_MEMORY_SCOPE_AGENT);
          }
        }
      } else if (tid == 0) {
        while (__hip_atomic_load(&bar[BAR_REL], __ATOMIC_RELAXED,
                                 __HIP_MEMORY_SCOPE_AGENT) < p) {
          __builtin_amdgcn_s_sleep(1);
        }
      }
      __syncthreads();
      __threadfence();                               // acquire: invalidate before h reload
    }
  }
}

// ---------------- layer-1 elementwise ----------------
__global__ __launch_bounds__(256) void k_gru1(const float* __restrict__ G1,
                                              const float* __restrict__ H0,
                                              float* __restrict__ H1, int row0) {
  const int lrow = blockIdx.x;
  const size_t row = (size_t)row0 + lrow;
  const float* g = G1 + (size_t)lrow * 6144;
  for (int j = threadIdx.x; j < H_; j += 256) {
    const float xr = g[j], xz = g[1024 + j], xn = g[2048 + j];
    const float hr = g[3072 + j], hz = g[4096 + j], hn = g[5120 + j];
    const float h = H0[(row << 10) + j];
    const float r = 1.f / (1.f + expf(-(xr + hr)));
    const float z = 1.f / (1.f + expf(-(xz + hz)));
    const float n = tanhf(xn + r * hn);
    H1[(row << 10) + j] = (1.f - z) * n + z * h;
  }
}

// ---------------- final hidden: out[2][B][H] ----------------
__global__ __launch_bounds__(256) void k_hidden(const float* __restrict__ H0,
                                                const float* __restrict__ H1,
                                                float* __restrict__ out) {
  const int i = blockIdx.x * 256 + threadIdx.x;
  const int l = i >> 14;
  const int b = (i >> 10) & 15;
  const int j = i & 1023;
  const float* src = l ? H1 : H0;
  out[i] = src[((size_t)(b * T_ + T_ - 1) << 10) + j];
}

extern "C" void kernel_launch(void* const* d_in, const int* in_sizes, int n_in,
                              void* d_out, int out_size, void* d_ws, size_t ws_size,
                              hipStream_t stream) {
  const int*   x   = (const int*)d_in[0];
  const float* emb = (const float*)d_in[1];
  const float* Wx0 = (const float*)d_in[2];
  const float* Wh0 = (const float*)d_in[3];
  const float* bx0 = (const float*)d_in[4];
  const float* bh0 = (const float*)d_in[5];
  const float* Wx1 = (const float*)d_in[6];
  const float* Wh1 = (const float*)d_in[7];
  const float* bx1 = (const float*)d_in[8];
  const float* bh1 = (const float*)d_in[9];
  const float* fcW = (const float*)d_in[10];
  const float* fcb = (const float*)d_in[11];
  float* out = (float*)d_out;

  char* ws = (char*)d_ws;
  float*    WhT  = (float*)(ws + 0);          // 12 MiB   [3072][1024]
  float*    H0   = (float*)(ws + 12582912);   // 16 MiB   [4096][1024]
  float*    H1   = (float*)(ws + 29360128);   // 16 MiB   [4096][1024]
  float*    EmbG = (float*)(ws + 46137344);   // 8 MiB    (dead after GX0)
  float*    GX0  = (float*)(ws + 54525952);   // 48 MiB   (dead after recur)
  float*    G1   = (float*)(ws + 46137344);   // 48 MiB   reuses EmbG+GX0
  unsigned* bar  = (unsigned*)(ws + 46137344);// 36 KiB   (EmbG region, dead during recur)

  k_embed<<<dim3(B_ * T_), dim3(128), 0, stream>>>(x, emb, EmbG);
  k_transpose<<<dim3(H3 / 32, H_ / 32), dim3(256), 0, stream>>>(Wh0, WhT, H_, H3);
  k_gemm<<<dim3(H3 / 64, (B_ * T_) / 128), dim3(256), 0, stream>>>(
      EmbG, Wx0, bx0, GX0, B_ * T_, H3, E_, H3);

  hipMemsetAsync(bar, 0, 36864, stream);      // zero barrier flags every launch
  {
    void* args[] = {(void*)&WhT, (void*)&GX0, (void*)&bh0, (void*)&H0, (void*)&bar};
    hipLaunchCooperativeKernel((const void*)k_recur, dim3(256), dim3(256), args, 0, stream);
  }

  for (int chunk = 0; chunk < 2; ++chunk) {
    const float* Ac = H0 + (size_t)chunk * 2048 * H_;
    k_gemm<<<dim3(H3 / 64, 2048 / 128), dim3(256), 0, stream>>>(
        Ac, Wx1, bx1, G1, 2048, H3, H_, 6144);
    k_gemm<<<dim3(H3 / 64, 2048 / 128), dim3(256), 0, stream>>>(
        Ac, Wh1, bh1, G1 + 3072, 2048, H3, H_, 6144);
    k_gru1<<<dim3(2048), dim3(256), 0, stream>>>(G1, H0, H1, chunk * 2048);
  }
  k_gemm<<<dim3(V_ / 64, (B_ * T_) / 128), dim3(256), 0, stream>>>(
      H1, fcW, fcb, out, B_ * T_, V_, H_, V_);
  k_hidden<<<dim3(32768 / 256), dim3(256), 0, stream>>>(H0, H1, out + (size_t)B_ * T_ * V_);
}

// Round 4
// 10747.634 us; speedup vs baseline: 2.3458x; 1.2562x over previous
//
#include <hip/hip_runtime.h>
#include <hip/hip_bf16.h>

#define V_  32000
#define E_  512
#define H_  1024
#define B_  16
#define T_  256
#define H3  3072

// Skewed LDS quarter layout: base(row, q) = row*1060 + q*264  (+k within quarter).
#define WROW_STRIDE 1060
#define QSTRIDE     264
#define W_LDS_FLOATS (11 * WROW_STRIDE + 3 * QSTRIDE + 256)   // 12708
#define H_LDS_FLOATS (15 * WROW_STRIDE + 3 * QSTRIDE + 256)   // 16948

#define AGENT_LD(p)    __hip_atomic_load((p),  __ATOMIC_RELAXED, __HIP_MEMORY_SCOPE_AGENT)
#define AGENT_ST(p, v) __hip_atomic_store((p), (v), __ATOMIC_RELAXED, __HIP_MEMORY_SCOPE_AGENT)

// ---------------- embedding gather ----------------
__global__ __launch_bounds__(128) void k_embed(const int* __restrict__ x,
                                               const float* __restrict__ emb,
                                               float* __restrict__ EmbG) {
  const int row = blockIdx.x;
  const int idx = x[row];
  const float4* src = (const float4*)(emb + (size_t)idx * E_);
  float4* dst = (float4*)(EmbG + (size_t)row * E_);
  dst[threadIdx.x] = src[threadIdx.x];
}

// ---------------- 32x32 tiled transpose ----------------
__global__ __launch_bounds__(256) void k_transpose(const float* __restrict__ W,
                                                   float* __restrict__ WT,
                                                   int R, int C) {
  __shared__ float tile[32][33];
  const int c0 = blockIdx.x * 32, r0 = blockIdx.y * 32;
  const int tx = threadIdx.x & 31, ty = threadIdx.x >> 5;
  #pragma unroll
  for (int i = ty; i < 32; i += 8)
    tile[i][tx] = W[(size_t)(r0 + i) * C + c0 + tx];
  __syncthreads();
  #pragma unroll
  for (int i = ty; i < 32; i += 8)
    WT[(size_t)(c0 + i) * R + r0 + tx] = tile[tx][i];
}

// ---------------- f32 GEMM: BM=128 BN=64 BK=16, 8x4/thread ----------------
__global__ __launch_bounds__(256) void k_gemm(const float* __restrict__ A,
                                              const float* __restrict__ B,
                                              const float* __restrict__ bias,
                                              float* __restrict__ C,
                                              int M, int N, int K, int ldc) {
  __shared__ float As[16][128];
  __shared__ float Bs[16][64];
  const int bn = blockIdx.x * 64;
  const int bm = blockIdx.y * 128;
  const int tid = threadIdx.x;
  const int tr = (tid >> 4) << 3;
  const int tc = (tid & 15) << 2;
  const int lr = tid >> 2;
  const int lc = (tid & 3) << 2;
  const int br = tid >> 4;
  const int bc = (tid & 15) << 2;
  float acc[8][4] = {};
  for (int k0 = 0; k0 < K; k0 += 16) {
    const float4 a0 = *(const float4*)(A + (size_t)(bm + lr) * K + k0 + lc);
    const float4 a1 = *(const float4*)(A + (size_t)(bm + lr + 64) * K + k0 + lc);
    const float4 b0 = *(const float4*)(B + (size_t)(k0 + br) * N + bn + bc);
    __syncthreads();
    As[lc + 0][lr] = a0.x; As[lc + 1][lr] = a0.y; As[lc + 2][lr] = a0.z; As[lc + 3][lr] = a0.w;
    As[lc + 0][lr + 64] = a1.x; As[lc + 1][lr + 64] = a1.y; As[lc + 2][lr + 64] = a1.z; As[lc + 3][lr + 64] = a1.w;
    *(float4*)&Bs[br][bc] = b0;
    __syncthreads();
    #pragma unroll
    for (int kk = 0; kk < 16; ++kk) {
      const float4 av0 = *(const float4*)&As[kk][tr];
      const float4 av1 = *(const float4*)&As[kk][tr + 4];
      const float4 bv  = *(const float4*)&Bs[kk][tc];
      const float a[8] = {av0.x, av0.y, av0.z, av0.w, av1.x, av1.y, av1.z, av1.w};
      #pragma unroll
      for (int i = 0; i < 8; ++i) {
        acc[i][0] += a[i] * bv.x;
        acc[i][1] += a[i] * bv.y;
        acc[i][2] += a[i] * bv.z;
        acc[i][3] += a[i] * bv.w;
      }
    }
  }
  float4 b4;
  b4.x = bias[bn + tc + 0]; b4.y = bias[bn + tc + 1];
  b4.z = bias[bn + tc + 2]; b4.w = bias[bn + tc + 3];
  #pragma unroll
  for (int i = 0; i < 8; ++i) {
    const size_t row = bm + tr + i;
    float4 o;
    o.x = acc[i][0] + b4.x; o.y = acc[i][1] + b4.y;
    o.z = acc[i][2] + b4.z; o.w = acc[i][3] + b4.w;
    *(float4*)(C + row * (size_t)ldc + bn + tc) = o;
  }
}

// ---------------- layer-0 recurrence ----------------
// h exchange: compact double buffer hbuf[2][16*1024], agent-scope atomics (no fences).
// barrier: per-WG arrival lines (WG0 sole reader) + per-WG release lines (1 writer,
// 1 reader each) => no shared hot line anywhere.
__global__ __launch_bounds__(256, 1) void k_recur(const float* __restrict__ WhT,  // [3H][H]
                                                  const float* __restrict__ GX0,  // [B*T][3H]
                                                  const float* __restrict__ bh0,
                                                  float* __restrict__ H0,         // [B*T][H]
                                                  unsigned* __restrict__ bar,     // [16384] u32
                                                  float* __restrict__ hbuf) {     // [2][16384]
  __shared__ __align__(16) float w_lds[W_LDS_FLOATS];
  __shared__ __align__(16) float h_lds[H_LDS_FLOATS];
  const int w = blockIdx.x;
  const int jbase = w << 2;
  const int tid = threadIdx.x;

  // one-time W staging: rows 0..3 = r (jj 0..3), 4..7 = z, 8..11 = n
  for (int i = tid; i < 12 * 256; i += 256) {
    const int rr = i >> 8, kq = i & 255;
    const int q = kq >> 6, k4 = kq & 63;
    const int wrow = (rr >> 2) * H_ + jbase + (rr & 3);
    const float4 v = ((const float4*)(WhT + (size_t)wrow * H_))[kq];
    *(float4*)&w_lds[rr * WROW_STRIDE + q * QSTRIDE + (k4 << 2)] = v;
  }

  const int out = tid >> 2;   // 0..63
  const int q   = tid & 3;    // k-quarter
  const int b   = out >> 2;   // 0..15
  const int jj  = out & 3;
  const int j   = jbase + jj;

  const float bhr = bh0[j];
  const float bhz = bh0[H_ + j];
  const float bhn = bh0[2 * H_ + j];

  const float* __restrict__ wr = w_lds + (0 + jj) * WROW_STRIDE + q * QSTRIDE;
  const float* __restrict__ wz = w_lds + (4 + jj) * WROW_STRIDE + q * QSTRIDE;
  const float* __restrict__ wn = w_lds + (8 + jj) * WROW_STRIDE + q * QSTRIDE;
  const float* __restrict__ hq = h_lds + b * WROW_STRIDE + q * QSTRIDE;

  // GX0 prefetch for t=0
  float xr = 0.f, xz = 0.f, xn = 0.f;
  if (q == 0) {
    const size_t grow = (size_t)(b * T_) * H3;
    xr = GX0[grow + j];
    xz = GX0[grow + H_ + j];
    xn = GX0[grow + 2 * H_ + j];
  }

  for (int t = 0; t < T_; ++t) {
    // stage h_{t-1} into skewed LDS
    if (t == 0) {
      for (int i = tid; i < H_LDS_FLOATS; i += 256) h_lds[i] = 0.f;
    } else {
      float* hprev = hbuf + ((t - 1) & 1) * 16384;
      for (int i = tid; i < 16384; i += 256) {
        const int bb = i >> 10, k = i & 1023;
        const int qq = k >> 8, k4 = k & 255;
        h_lds[bb * WROW_STRIDE + qq * QSTRIDE + k4] = AGENT_LD(&hprev[i]);
      }
    }
    __syncthreads();

    float pr = 0.f, pz = 0.f, pn = 0.f;
    #pragma unroll 4
    for (int k = 0; k < 256; k += 4) {
      const float4 h4 = *(const float4*)(hq + k);
      const float4 r4 = *(const float4*)(wr + k);
      const float4 z4 = *(const float4*)(wz + k);
      const float4 n4 = *(const float4*)(wn + k);
      pr += h4.x * r4.x + h4.y * r4.y + h4.z * r4.z + h4.w * r4.w;
      pz += h4.x * z4.x + h4.y * z4.y + h4.z * z4.z + h4.w * z4.w;
      pn += h4.x * n4.x + h4.y * n4.y + h4.z * n4.z + h4.w * n4.w;
    }
    pr += __shfl_xor(pr, 1); pr += __shfl_xor(pr, 2);
    pz += __shfl_xor(pz, 1); pz += __shfl_xor(pz, 2);
    pn += __shfl_xor(pn, 1); pn += __shfl_xor(pn, 2);

    if (q == 0) {
      const float r = 1.f / (1.f + expf(-(xr + pr + bhr)));
      const float z = 1.f / (1.f + expf(-(xz + pz + bhz)));
      const float n = tanhf(xn + r * (pn + bhn));
      const float hp = h_lds[b * WROW_STRIDE + ((j >> 8) * QSTRIDE) + (j & 255)];
      const float hnew = (1.f - z) * n + z * hp;
      H0[((size_t)(b * T_ + t) << 10) + j] = hnew;            // plain (read by later kernels)
      if (t + 1 < T_) {
        AGENT_ST(&hbuf[(t & 1) * 16384 + (b << 10) + j], hnew);
        // prefetch next step's GX0 before the barrier
        const size_t grow = (size_t)(b * T_ + t + 1) * H3;
        xr = GX0[grow + j];
        xz = GX0[grow + H_ + j];
        xn = GX0[grow + 2 * H_ + j];
      }
    }

    if (t < T_ - 1) {
      const unsigned p = (unsigned)(t + 1);
      __syncthreads();                 // drains all waves' hbuf stores (vmcnt 0 before barrier)
      if (w == 0) {
        if (tid == 0) AGENT_ST(&bar[0], p);       // own arrival
        if (tid < 64) {
          for (;;) {
            const unsigned v0 = AGENT_LD(&bar[(tid      ) * 32]);
            const unsigned v1 = AGENT_LD(&bar[(tid +  64) * 32]);
            const unsigned v2 = AGENT_LD(&bar[(tid + 128) * 32]);
            const unsigned v3 = AGENT_LD(&bar[(tid + 192) * 32]);
            if (__all(v0 >= p && v1 >= p && v2 >= p && v3 >= p)) break;
            __builtin_amdgcn_s_sleep(1);
          }
          // broadcast release to 256 per-WG lines
          AGENT_ST(&bar[8192 + (tid      ) * 32], p);
          AGENT_ST(&bar[8192 + (tid +  64) * 32], p);
          AGENT_ST(&bar[8192 + (tid + 128) * 32], p);
          AGENT_ST(&bar[8192 + (tid + 192) * 32], p);
        }
      } else if (tid == 0) {
        AGENT_ST(&bar[w * 32], p);                // own arrival line
        while (AGENT_LD(&bar[8192 + w * 32]) < p) // spin on own release line
          __builtin_amdgcn_s_sleep(1);
      }
      __syncthreads();
    }
  }
}

// ---------------- layer-1 elementwise ----------------
__global__ __launch_bounds__(256) void k_gru1(const float* __restrict__ G1,
                                              const float* __restrict__ H0,
                                              float* __restrict__ H1, int row0) {
  const int lrow = blockIdx.x;
  const size_t row = (size_t)row0 + lrow;
  const float* g = G1 + (size_t)lrow * 6144;
  for (int j = threadIdx.x; j < H_; j += 256) {
    const float xr = g[j], xz = g[1024 + j], xn = g[2048 + j];
    const float hr = g[3072 + j], hz = g[4096 + j], hn = g[5120 + j];
    const float h = H0[(row << 10) + j];
    const float r = 1.f / (1.f + expf(-(xr + hr)));
    const float z = 1.f / (1.f + expf(-(xz + hz)));
    const float n = tanhf(xn + r * hn);
    H1[(row << 10) + j] = (1.f - z) * n + z * h;
  }
}

// ---------------- final hidden: out[2][B][H] ----------------
__global__ __launch_bounds__(256) void k_hidden(const float* __restrict__ H0,
                                                const float* __restrict__ H1,
                                                float* __restrict__ out) {
  const int i = blockIdx.x * 256 + threadIdx.x;
  const int l = i >> 14;
  const int b = (i >> 10) & 15;
  const int j = i & 1023;
  const float* src = l ? H1 : H0;
  out[i] = src[((size_t)(b * T_ + T_ - 1) << 10) + j];
}

extern "C" void kernel_launch(void* const* d_in, const int* in_sizes, int n_in,
                              void* d_out, int out_size, void* d_ws, size_t ws_size,
                              hipStream_t stream) {
  const int*   x   = (const int*)d_in[0];
  const float* emb = (const float*)d_in[1];
  const float* Wx0 = (const float*)d_in[2];
  const float* Wh0 = (const float*)d_in[3];
  const float* bx0 = (const float*)d_in[4];
  const float* bh0 = (const float*)d_in[5];
  const float* Wx1 = (const float*)d_in[6];
  const float* Wh1 = (const float*)d_in[7];
  const float* bx1 = (const float*)d_in[8];
  const float* bh1 = (const float*)d_in[9];
  const float* fcW = (const float*)d_in[10];
  const float* fcb = (const float*)d_in[11];
  float* out = (float*)d_out;

  char* ws = (char*)d_ws;
  float*    WhT  = (float*)(ws + 0);          // 12 MiB   [3072][1024]
  float*    H0   = (float*)(ws + 12582912);   // 16 MiB   [4096][1024]
  float*    H1   = (float*)(ws + 29360128);   // 16 MiB   [4096][1024]
  float*    EmbG = (float*)(ws + 46137344);   // 8 MiB    (dead after GX0)
  float*    GX0  = (float*)(ws + 54525952);   // 48 MiB   (dead after recur)
  float*    G1   = (float*)(ws + 46137344);   // 48 MiB   reuses EmbG+GX0
  unsigned* bar  = (unsigned*)(ws + 46137344);        // 64 KiB (EmbG region, dead in recur)
  float*    hbuf = (float*)(ws + 46137344 + 65536);   // 128 KiB compact h double buffer

  k_embed<<<dim3(B_ * T_), dim3(128), 0, stream>>>(x, emb, EmbG);
  k_transpose<<<dim3(H3 / 32, H_ / 32), dim3(256), 0, stream>>>(Wh0, WhT, H_, H3);
  k_gemm<<<dim3(H3 / 64, (B_ * T_) / 128), dim3(256), 0, stream>>>(
      EmbG, Wx0, bx0, GX0, B_ * T_, H3, E_, H3);

  hipMemsetAsync(bar, 0, 65536, stream);      // zero barrier flags every launch
  {
    void* args[] = {(void*)&WhT, (void*)&GX0, (void*)&bh0, (void*)&H0,
                    (void*)&bar, (void*)&hbuf};
    hipLaunchCooperativeKernel((const void*)k_recur, dim3(256), dim3(256), args, 0, stream);
  }

  for (int chunk = 0; chunk < 2; ++chunk) {
    const float* Ac = H0 + (size_t)chunk * 2048 * H_;
    k_gemm<<<dim3(H3 / 64, 2048 / 128), dim3(256), 0, stream>>>(
        Ac, Wx1, bx1, G1, 2048, H3, H_, 6144);
    k_gemm<<<dim3(H3 / 64, 2048 / 128), dim3(256), 0, stream>>>(
        Ac, Wh1, bh1, G1 + 3072, 2048, H3, H_, 6144);
    k_gru1<<<dim3(2048), dim3(256), 0, stream>>>(G1, H0, H1, chunk * 2048);
  }
  k_gemm<<<dim3(V_ / 64, (B_ * T_) / 128), dim3(256), 0, stream>>>(
      H1, fcW, fcb, out, B_ * T_, V_, H_, V_);
  k_hidden<<<dim3(32768 / 256), dim3(256), 0, stream>>>(H0, H1, out + (size_t)B_ * T_ * V_);
}

// Round 5
// 9171.968 us; speedup vs baseline: 2.7488x; 1.1718x over previous
//
#include <hip/hip_runtime.h>
#include <hip/hip_bf16.h>

#define V_  32000
#define E_  512
#define H_  1024
#define B_  16
#define T_  256
#define H3  3072

#define NWG   128
#define NTHR  512
#define WSTR  513                 // w_lds row stride in u32 pairs (odd => 2-way max)

#define AGENT_LD(p)    __hip_atomic_load((p),  __ATOMIC_RELAXED, __HIP_MEMORY_SCOPE_AGENT)
#define AGENT_ST(p, v) __hip_atomic_store((p), (v), __ATOMIC_RELAXED, __HIP_MEMORY_SCOPE_AGENT)

// ---------------- embedding gather ----------------
__global__ __launch_bounds__(128) void k_embed(const int* __restrict__ x,
                                               const float* __restrict__ emb,
                                               float* __restrict__ EmbG) {
  const int row = blockIdx.x;
  const int idx = x[row];
  const float4* src = (const float4*)(emb + (size_t)idx * E_);
  float4* dst = (float4*)(EmbG + (size_t)row * E_);
  dst[threadIdx.x] = src[threadIdx.x];
}

// ---------------- transpose Wh0 [1024][3072] -> WhTb [3072][1024] bf16 ----------------
__global__ __launch_bounds__(256) void k_transpose_b16(const float* __restrict__ W,
                                                       unsigned short* __restrict__ WTb) {
  __shared__ float tile[32][33];
  const int c0 = blockIdx.x * 32, r0 = blockIdx.y * 32;
  const int tx = threadIdx.x & 31, ty = threadIdx.x >> 5;
  #pragma unroll
  for (int i = ty; i < 32; i += 8)
    tile[i][tx] = W[(size_t)(r0 + i) * H3 + c0 + tx];
  __syncthreads();
  #pragma unroll
  for (int i = ty; i < 32; i += 8) {
    const __hip_bfloat16 v = __float2bfloat16(tile[tx][i]);
    WTb[(size_t)(c0 + i) * H_ + r0 + tx] = *(const unsigned short*)&v;
  }
}

// ---------------- f32 GEMM: BM=128 BN=64 BK=16, 8x4/thread ----------------
__global__ __launch_bounds__(256) void k_gemm(const float* __restrict__ A,
                                              const float* __restrict__ B,
                                              const float* __restrict__ bias,
                                              float* __restrict__ C,
                                              int M, int N, int K, int ldc) {
  __shared__ float As[16][128];
  __shared__ float Bs[16][64];
  const int bn = blockIdx.x * 64;
  const int bm = blockIdx.y * 128;
  const int tid = threadIdx.x;
  const int tr = (tid >> 4) << 3;
  const int tc = (tid & 15) << 2;
  const int lr = tid >> 2;
  const int lc = (tid & 3) << 2;
  const int br = tid >> 4;
  const int bc = (tid & 15) << 2;
  float acc[8][4] = {};
  for (int k0 = 0; k0 < K; k0 += 16) {
    const float4 a0 = *(const float4*)(A + (size_t)(bm + lr) * K + k0 + lc);
    const float4 a1 = *(const float4*)(A + (size_t)(bm + lr + 64) * K + k0 + lc);
    const float4 b0 = *(const float4*)(B + (size_t)(k0 + br) * N + bn + bc);
    __syncthreads();
    As[lc + 0][lr] = a0.x; As[lc + 1][lr] = a0.y; As[lc + 2][lr] = a0.z; As[lc + 3][lr] = a0.w;
    As[lc + 0][lr + 64] = a1.x; As[lc + 1][lr + 64] = a1.y; As[lc + 2][lr + 64] = a1.z; As[lc + 3][lr + 64] = a1.w;
    *(float4*)&Bs[br][bc] = b0;
    __syncthreads();
    #pragma unroll
    for (int kk = 0; kk < 16; ++kk) {
      const float4 av0 = *(const float4*)&As[kk][tr];
      const float4 av1 = *(const float4*)&As[kk][tr + 4];
      const float4 bv  = *(const float4*)&Bs[kk][tc];
      const float a[8] = {av0.x, av0.y, av0.z, av0.w, av1.x, av1.y, av1.z, av1.w};
      #pragma unroll
      for (int i = 0; i < 8; ++i) {
        acc[i][0] += a[i] * bv.x;
        acc[i][1] += a[i] * bv.y;
        acc[i][2] += a[i] * bv.z;
        acc[i][3] += a[i] * bv.w;
      }
    }
  }
  float4 b4;
  b4.x = bias[bn + tc + 0]; b4.y = bias[bn + tc + 1];
  b4.z = bias[bn + tc + 2]; b4.w = bias[bn + tc + 3];
  #pragma unroll
  for (int i = 0; i < 8; ++i) {
    const size_t row = bm + tr + i;
    float4 o;
    o.x = acc[i][0] + b4.x; o.y = acc[i][1] + b4.y;
    o.z = acc[i][2] + b4.z; o.w = acc[i][3] + b4.w;
    *(float4*)(C + row * (size_t)ldc + bn + tc) = o;
  }
}

// ---------------- layer-0 recurrence: 128 WG x 512 thr, bf16 W in LDS ----------------
// Thread (c=tid&7, q=tid>>3): columns wg*8+c, k-chunk [16q,16q+16). acc[16 b][3 gates].
// All-to-all flag barrier: each WG stores its own arrival line; wave 0 of EVERY WG
// polls all 128 lines (2 per lane) -> single-hop release after last arrival.
__global__ __launch_bounds__(NTHR, 1) void k_recur(const unsigned short* __restrict__ WhTb, // [3H][H] bf16
                                                   const float* __restrict__ GX0,  // [B*T][3H]
                                                   const float* __restrict__ bh0,
                                                   float* __restrict__ H0,         // [B*T][H]
                                                   unsigned* __restrict__ bar,     // 128 lines *32 u32
                                                   float* __restrict__ hbuf) {     // [2][16384] f32
  __shared__ unsigned w_u32[24 * WSTR];   // 48.1 KB: row (g*8+cc), 512 bf16-pairs + skew
  __shared__ float h_lds[16 * 1024];      // 64 KB: h_{t-1} [b][k]
  __shared__ float red[8 * 416];          // 13 KB: per-wave partials [wave][c*52 + b*3+g]
  const int wgid = blockIdx.x;
  const int tid = threadIdx.x;
  const int c = tid & 7, q = tid >> 3;    // q in [0,64)
  const int lane = tid & 63, wv = tid >> 6;

  // one-time W staging: 24 rows x 512 u32 (bf16 pairs), coalesced global reads
  for (int i = tid; i < 24 * 512; i += NTHR) {
    const int rr = i >> 9, pidx = i & 511;
    const int g = rr >> 3, cc = rr & 7;
    const int grow = g * H_ + (wgid << 3) + cc;
    w_u32[rr * WSTR + pidx] = ((const unsigned*)WhTb)[(size_t)grow * 512 + pidx];
  }

  // per-thread bias preload (gate-math threads only)
  float bhr = 0.f, bhz = 0.f, bhn = 0.f;
  if (tid < 128) {
    const int col = (wgid << 3) + (tid & 7);
    bhr = bh0[col]; bhz = bh0[H_ + col]; bhn = bh0[2 * H_ + col];
  }

  const unsigned* __restrict__ w0 = w_u32 + (0 + c) * WSTR + (q << 3);
  const unsigned* __restrict__ w1 = w_u32 + (8 + c) * WSTR + (q << 3);
  const unsigned* __restrict__ w2 = w_u32 + (16 + c) * WSTR + (q << 3);
  const int koffbase = q << 4;

  for (int t = 0; t < T_; ++t) {
    // ---- stage h_{t-1} into LDS ----
    if (t == 0) {
      #pragma unroll
      for (int r2 = 0; r2 < 32; ++r2) h_lds[(r2 << 9) + tid] = 0.f;
    } else {
      const float* __restrict__ hprev = hbuf + ((t - 1) & 1) * 16384;
      #pragma unroll
      for (int r2 = 0; r2 < 32; ++r2) {
        const int idx = (r2 << 9) + tid;
        h_lds[idx] = AGENT_LD(&hprev[idx]);
      }
    }
    __syncthreads();

    // GX0 loads for this step (scheduled early, consumed after reduce)
    float xr = 0.f, xz = 0.f, xn = 0.f;
    if (tid < 128) {
      const int b0 = tid >> 3, c7 = tid & 7;
      const size_t row3 = (size_t)(b0 * T_ + t) * H3;
      const int col = (wgid << 3) + c7;
      xr = GX0[row3 + col]; xz = GX0[row3 + H_ + col]; xn = GX0[row3 + 2 * H_ + col];
    }

    // ---- dot: acc[b][g] += h[b][k] * w[g][c][k] over this thread's 16 k ----
    float acc[16][3] = {};
    #pragma unroll
    for (int i = 0; i < 8; ++i) {
      const int ir = (i + q) & 7;                    // rotation: bank spread
      const unsigned pr_ = w0[ir], pz_ = w1[ir], pn_ = w2[ir];
      const float wr0 = __uint_as_float(pr_ << 16), wr1 = __uint_as_float(pr_ & 0xffff0000u);
      const float wz0 = __uint_as_float(pz_ << 16), wz1 = __uint_as_float(pz_ & 0xffff0000u);
      const float wn0 = __uint_as_float(pn_ << 16), wn1 = __uint_as_float(pn_ & 0xffff0000u);
      const float* hp = h_lds + koffbase + (ir << 1);
      #pragma unroll
      for (int b = 0; b < 16; ++b) {
        const float2 h2 = *(const float2*)(hp + (b << 10));
        acc[b][0] = fmaf(h2.y, wr1, fmaf(h2.x, wr0, acc[b][0]));
        acc[b][1] = fmaf(h2.y, wz1, fmaf(h2.x, wz0, acc[b][1]));
        acc[b][2] = fmaf(h2.y, wn1, fmaf(h2.x, wn0, acc[b][2]));
      }
    }

    // ---- reduce across q: in-wave shfl (q stride 8 in lane id) ----
    #pragma unroll
    for (int b = 0; b < 16; ++b)
      #pragma unroll
      for (int g = 0; g < 3; ++g) {
        float v = acc[b][g];
        v += __shfl_xor(v, 8);
        v += __shfl_xor(v, 16);
        v += __shfl_xor(v, 32);
        acc[b][g] = v;
      }
    if (lane < 8) {                                  // c = lane, q%8 == 0
      const int base = wv * 416 + lane * 52;
      #pragma unroll
      for (int b = 0; b < 16; ++b)
        #pragma unroll
        for (int g = 0; g < 3; ++g) red[base + b * 3 + g] = acc[b][g];
    }
    __syncthreads();

    // ---- combine 8 wave-partials + gates (128 threads) ----
    if (tid < 128) {
      const int b0 = tid >> 3, c7 = tid & 7;
      float pr = 0.f, pz = 0.f, pn = 0.f;
      #pragma unroll
      for (int w8 = 0; w8 < 8; ++w8) {
        const int base = w8 * 416 + c7 * 52 + b0 * 3;
        pr += red[base]; pz += red[base + 1]; pn += red[base + 2];
      }
      const float r = 1.f / (1.f + expf(-(xr + pr + bhr)));
      const float z = 1.f / (1.f + expf(-(xz + pz + bhz)));
      const float n = tanhf(xn + r * (pn + bhn));
      const int col = (wgid << 3) + c7;
      const float hp = h_lds[(b0 << 10) + col];
      const float hnew = (1.f - z) * n + z * hp;
      H0[((size_t)(b0 * T_ + t) << 10) + col] = hnew;
      if (t + 1 < T_) AGENT_ST(&hbuf[(t & 1) * 16384 + (b0 << 10) + col], hnew);
    }

    // ---- all-to-all flag barrier ----
    if (t < T_ - 1) {
      __syncthreads();                               // drains vmcnt => stores complete
      const unsigned p = (unsigned)(t + 1);
      if (tid == 0) AGENT_ST(&bar[wgid * 32], p);
      if (tid < 64) {
        for (;;) {
          const unsigned a0 = AGENT_LD(&bar[tid * 32]);
          const unsigned a1 = AGENT_LD(&bar[(tid + 64) * 32]);
          if (__all(a0 >= p && a1 >= p)) break;
          __builtin_amdgcn_s_sleep(1);
        }
      }
      __syncthreads();
    }
  }
}

// ---------------- layer-1 elementwise ----------------
__global__ __launch_bounds__(256) void k_gru1(const float* __restrict__ G1,
                                              const float* __restrict__ H0,
                                              float* __restrict__ H1, int row0) {
  const int lrow = blockIdx.x;
  const size_t row = (size_t)row0 + lrow;
  const float* g = G1 + (size_t)lrow * 6144;
  for (int j = threadIdx.x; j < H_; j += 256) {
    const float xr = g[j], xz = g[1024 + j], xn = g[2048 + j];
    const float hr = g[3072 + j], hz = g[4096 + j], hn = g[5120 + j];
    const float h = H0[(row << 10) + j];
    const float r = 1.f / (1.f + expf(-(xr + hr)));
    const float z = 1.f / (1.f + expf(-(xz + hz)));
    const float n = tanhf(xn + r * hn);
    H1[(row << 10) + j] = (1.f - z) * n + z * h;
  }
}

// ---------------- final hidden: out[2][B][H] ----------------
__global__ __launch_bounds__(256) void k_hidden(const float* __restrict__ H0,
                                                const float* __restrict__ H1,
                                                float* __restrict__ out) {
  const int i = blockIdx.x * 256 + threadIdx.x;
  const int l = i >> 14;
  const int b = (i >> 10) & 15;
  const int j = i & 1023;
  const float* src = l ? H1 : H0;
  out[i] = src[((size_t)(b * T_ + T_ - 1) << 10) + j];
}

extern "C" void kernel_launch(void* const* d_in, const int* in_sizes, int n_in,
                              void* d_out, int out_size, void* d_ws, size_t ws_size,
                              hipStream_t stream) {
  const int*   x   = (const int*)d_in[0];
  const float* emb = (const float*)d_in[1];
  const float* Wx0 = (const float*)d_in[2];
  const float* Wh0 = (const float*)d_in[3];
  const float* bx0 = (const float*)d_in[4];
  const float* bh0 = (const float*)d_in[5];
  const float* Wx1 = (const float*)d_in[6];
  const float* Wh1 = (const float*)d_in[7];
  const float* bx1 = (const float*)d_in[8];
  const float* bh1 = (const float*)d_in[9];
  const float* fcW = (const float*)d_in[10];
  const float* fcb = (const float*)d_in[11];
  float* out = (float*)d_out;

  char* ws = (char*)d_ws;
  unsigned short* WhTb = (unsigned short*)(ws + 0);   // 6 MiB  [3072][1024] bf16
  float*    H0   = (float*)(ws + 12582912);   // 16 MiB   [4096][1024]
  float*    H1   = (float*)(ws + 29360128);   // 16 MiB   [4096][1024]
  float*    EmbG = (float*)(ws + 46137344);   // 8 MiB    (dead after GX0)
  float*    GX0  = (float*)(ws + 54525952);   // 48 MiB   (dead after recur)
  float*    G1   = (float*)(ws + 46137344);   // 48 MiB   reuses EmbG+GX0
  unsigned* bar  = (unsigned*)(ws + 46137344);        // 16 KiB (EmbG region, dead in recur)
  float*    hbuf = (float*)(ws + 46137344 + 65536);   // 128 KiB f32 h ping-pong

  k_embed<<<dim3(B_ * T_), dim3(128), 0, stream>>>(x, emb, EmbG);
  k_transpose_b16<<<dim3(H3 / 32, H_ / 32), dim3(256), 0, stream>>>(Wh0, WhTb);
  k_gemm<<<dim3(H3 / 64, (B_ * T_) / 128), dim3(256), 0, stream>>>(
      EmbG, Wx0, bx0, GX0, B_ * T_, H3, E_, H3);

  hipMemsetAsync(bar, 0, 65536, stream);
  {
    void* args[] = {(void*)&WhTb, (void*)&GX0, (void*)&bh0, (void*)&H0,
                    (void*)&bar, (void*)&hbuf};
    hipLaunchCooperativeKernel((const void*)k_recur, dim3(NWG), dim3(NTHR), args, 0, stream);
  }

  for (int chunk = 0; chunk < 2; ++chunk) {
    const float* Ac = H0 + (size_t)chunk * 2048 * H_;
    k_gemm<<<dim3(H3 / 64, 2048 / 128), dim3(256), 0, stream>>>(
        Ac, Wx1, bx1, G1, 2048, H3, H_, 6144);
    k_gemm<<<dim3(H3 / 64, 2048 / 128), dim3(256), 0, stream>>>(
        Ac, Wh1, bh1, G1 + 3072, 2048, H3, H_, 6144);
    k_gru1<<<dim3(2048), dim3(256), 0, stream>>>(G1, H0, H1, chunk * 2048);
  }
  k_gemm<<<dim3(V_ / 64, (B_ * T_) / 128), dim3(256), 0, stream>>>(
      H1, fcW, fcb, out, B_ * T_, V_, H_, V_);
  k_hidden<<<dim3(32768 / 256), dim3(256), 0, stream>>>(H0, H1, out + (size_t)B_ * T_ * V_);
}

// Round 6
// 5267.955 us; speedup vs baseline: 4.7859x; 1.7411x over previous
//
#include <hip/hip_runtime.h>
#include <hip/hip_bf16.h>

#define V_  32000
#define E_  512
#define H_  1024
#define B_  16
#define T_  256
#define H3  3072

#define NWG   128
#define NTHR  512
#define WSTR  513                 // recur w_lds row stride in u32 pairs

#define AGENT_LD(p)    __hip_atomic_load((p),  __ATOMIC_RELAXED, __HIP_MEMORY_SCOPE_AGENT)
#define AGENT_ST(p, v) __hip_atomic_store((p), (v), __ATOMIC_RELAXED, __HIP_MEMORY_SCOPE_AGENT)

typedef __attribute__((ext_vector_type(8))) short bf16x8;
typedef __attribute__((ext_vector_type(4))) float f32x4;

#define GLDS16(gp, lp) __builtin_amdgcn_global_load_lds( \
    (const __attribute__((address_space(1))) unsigned int*)(gp), \
    (__attribute__((address_space(3))) unsigned int*)(lp), 16, 0, 0)

// ---------------- embedding gather ----------------
__global__ __launch_bounds__(128) void k_embed(const int* __restrict__ x,
                                               const float* __restrict__ emb,
                                               float* __restrict__ EmbG) {
  const int row = blockIdx.x;
  const int idx = x[row];
  const float4* src = (const float4*)(emb + (size_t)idx * E_);
  float4* dst = (float4*)(EmbG + (size_t)row * E_);
  dst[threadIdx.x] = src[threadIdx.x];
}

// ---------------- transpose Wh0 [1024][3072] -> WhTb [3072][1024] bf16 ----------------
__global__ __launch_bounds__(256) void k_transpose_b16(const float* __restrict__ W,
                                                       unsigned short* __restrict__ WTb) {
  __shared__ float tile[32][33];
  const int c0 = blockIdx.x * 32, r0 = blockIdx.y * 32;
  const int tx = threadIdx.x & 31, ty = threadIdx.x >> 5;
  #pragma unroll
  for (int i = ty; i < 32; i += 8)
    tile[i][tx] = W[(size_t)(r0 + i) * H3 + c0 + tx];
  __syncthreads();
  #pragma unroll
  for (int i = ty; i < 32; i += 8) {
    const __hip_bfloat16 v = __float2bfloat16(tile[tx][i]);
    WTb[(size_t)(c0 + i) * H_ + r0 + tx] = *(const unsigned short*)&v;
  }
}

// ---------------- transpose + hi/lo split: W [R][ldw] f32 -> WT hi/lo [C][R] bf16 ----------------
__global__ __launch_bounds__(256) void k_transpose_split(const float* __restrict__ W, int ldw,
                                                         unsigned short* __restrict__ WThi,
                                                         unsigned short* __restrict__ WTlo,
                                                         int R) {
  __shared__ float tile[32][33];
  const int c0 = blockIdx.x * 32, r0 = blockIdx.y * 32;
  const int tx = threadIdx.x & 31, ty = threadIdx.x >> 5;
  #pragma unroll
  for (int i = ty; i < 32; i += 8)
    tile[i][tx] = W[(size_t)(r0 + i) * ldw + c0 + tx];
  __syncthreads();
  #pragma unroll
  for (int i = ty; i < 32; i += 8) {
    const float v = tile[tx][i];
    const __hip_bfloat16 hb = __float2bfloat16(v);
    const float rr = v - __bfloat162float(hb);
    const __hip_bfloat16 lb = __float2bfloat16(rr);
    WThi[(size_t)(c0 + i) * R + r0 + tx] = *(const unsigned short*)&hb;
    WTlo[(size_t)(c0 + i) * R + r0 + tx] = *(const unsigned short*)&lb;
  }
}

// ---------------- elementwise hi/lo split (A operands) ----------------
__global__ __launch_bounds__(256) void k_split(const float* __restrict__ x,
                                               unsigned short* __restrict__ hi,
                                               unsigned short* __restrict__ lo, int n4) {
  const int i = blockIdx.x * 256 + threadIdx.x;
  if (i >= n4) return;
  const float4 v = ((const float4*)x)[i];
  const float f[4] = {v.x, v.y, v.z, v.w};
  unsigned short hh[4], ll[4];
  #pragma unroll
  for (int k = 0; k < 4; ++k) {
    const __hip_bfloat16 hb = __float2bfloat16(f[k]);
    hh[k] = *(const unsigned short*)&hb;
    const __hip_bfloat16 lb = __float2bfloat16(f[k] - __bfloat162float(hb));
    ll[k] = *(const unsigned short*)&lb;
  }
  ushort4 h4; h4.x = hh[0]; h4.y = hh[1]; h4.z = hh[2]; h4.w = hh[3];
  ushort4 l4; l4.x = ll[0]; l4.y = ll[1]; l4.z = ll[2]; l4.w = ll[3];
  ((ushort4*)hi)[i] = h4;
  ((ushort4*)lo)[i] = l4;
}

// ---------------- f32 GEMM (kept for GX0): BM=128 BN=64 BK=16 ----------------
__global__ __launch_bounds__(256) void k_gemm(const float* __restrict__ A,
                                              const float* __restrict__ B,
                                              const float* __restrict__ bias,
                                              float* __restrict__ C,
                                              int M, int N, int K, int ldc) {
  __shared__ float As[16][128];
  __shared__ float Bs[16][64];
  const int bn = blockIdx.x * 64;
  const int bm = blockIdx.y * 128;
  const int tid = threadIdx.x;
  const int tr = (tid >> 4) << 3;
  const int tc = (tid & 15) << 2;
  const int lr = tid >> 2;
  const int lc = (tid & 3) << 2;
  const int br = tid >> 4;
  const int bc = (tid & 15) << 2;
  float acc[8][4] = {};
  for (int k0 = 0; k0 < K; k0 += 16) {
    const float4 a0 = *(const float4*)(A + (size_t)(bm + lr) * K + k0 + lc);
    const float4 a1 = *(const float4*)(A + (size_t)(bm + lr + 64) * K + k0 + lc);
    const float4 b0 = *(const float4*)(B + (size_t)(k0 + br) * N + bn + bc);
    __syncthreads();
    As[lc + 0][lr] = a0.x; As[lc + 1][lr] = a0.y; As[lc + 2][lr] = a0.z; As[lc + 3][lr] = a0.w;
    As[lc + 0][lr + 64] = a1.x; As[lc + 1][lr + 64] = a1.y; As[lc + 2][lr + 64] = a1.z; As[lc + 3][lr + 64] = a1.w;
    *(float4*)&Bs[br][bc] = b0;
    __syncthreads();
    #pragma unroll
    for (int kk = 0; kk < 16; ++kk) {
      const float4 av0 = *(const float4*)&As[kk][tr];
      const float4 av1 = *(const float4*)&As[kk][tr + 4];
      const float4 bv  = *(const float4*)&Bs[kk][tc];
      const float a[8] = {av0.x, av0.y, av0.z, av0.w, av1.x, av1.y, av1.z, av1.w};
      #pragma unroll
      for (int i = 0; i < 8; ++i) {
        acc[i][0] += a[i] * bv.x;
        acc[i][1] += a[i] * bv.y;
        acc[i][2] += a[i] * bv.z;
        acc[i][3] += a[i] * bv.w;
      }
    }
  }
  float4 b4;
  b4.x = bias[bn + tc + 0]; b4.y = bias[bn + tc + 1];
  b4.z = bias[bn + tc + 2]; b4.w = bias[bn + tc + 3];
  #pragma unroll
  for (int i = 0; i < 8; ++i) {
    const size_t row = bm + tr + i;
    float4 o;
    o.x = acc[i][0] + b4.x; o.y = acc[i][1] + b4.y;
    o.z = acc[i][2] + b4.z; o.w = acc[i][3] + b4.w;
    *(float4*)(C + row * (size_t)ldc + bn + tc) = o;
  }
}

// ---------------- split-bf16 MFMA GEMM ----------------
// C[m][n] = sum_k A[m][k]*B[k][n] + bias[n], via Ahi*Bhi + Ahi*Blo + Alo*Bhi.
// A [M][K] f32-split bf16 (row-major, lda=K); BT [N][K] (B transposed, same layout).
// 128x128 tile, BK=64, 256 thr = 4 waves (2x2), wave = 4x4 frags of 16x16x32.
// LDS tiles linear [128][64] bf16 with 16B-slot XOR swizzle (slot ^= row&7),
// staged by global_load_lds(16B) from pre-swizzled global addresses.
__global__ __launch_bounds__(256, 2) void k_gemm_mfma(
    const unsigned short* __restrict__ Ahi, const unsigned short* __restrict__ Alo,
    const unsigned short* __restrict__ BThi, const unsigned short* __restrict__ BTlo,
    const float* __restrict__ bias, float* __restrict__ C,
    int MT, int NT, int K, int ldc) {
  __shared__ unsigned short sAhi[128 * 64], sAlo[128 * 64];
  __shared__ unsigned short sBhi[128 * 64], sBlo[128 * 64];

  // grouped grid swizzle (GROUP_M=8 supertiles for L2 reuse)
  const int bid = blockIdx.x;
  const int GROUPM = 8;
  const int group = bid / (GROUPM * NT);
  const int first = group * GROUPM;
  const int gsm = (MT - first < GROUPM) ? (MT - first) : GROUPM;
  const int rem = bid % (GROUPM * NT);
  const int pm = first + rem % gsm;
  const int pn = rem / gsm;
  const int bm = pm * 128, bn = pn * 128;

  const int tid = threadIdx.x;
  const int wv = tid >> 6, l = tid & 63;
  const int wr = wv >> 1, wc = wv & 1;
  const int frow = l & 15;          // frag row (A) / col (B)
  const int ksl  = l >> 4;          // k sub-slot 0..3

  f32x4 acc[4][4];
  #pragma unroll
  for (int a = 0; a < 4; ++a)
    #pragma unroll
    for (int b = 0; b < 4; ++b) acc[a][b] = (f32x4){0.f, 0.f, 0.f, 0.f};

  for (int k0 = 0; k0 < K; k0 += 64) {
    __syncthreads();                 // previous iteration's readers done
    #pragma unroll
    for (int p = 0; p < 4; ++p) {
      const int obase = ((p << 2) + wv) << 10;            // wave-uniform byte base
      const int row = ((obase >> 7)) + (l >> 3);          // 0..127
      const int slot = l & 7;
      const int gcol = k0 + ((slot ^ (row & 7)) << 3);    // pre-swizzled source col
      const size_t ga = (size_t)(bm + row) * K + gcol;
      const size_t gb = (size_t)(bn + row) * K + gcol;
      GLDS16(Ahi + ga, (char*)sAhi + obase);
      GLDS16(Alo + ga, (char*)sAlo + obase);
      GLDS16(BThi + gb, (char*)sBhi + obase);
      GLDS16(BTlo + gb, (char*)sBlo + obase);
    }
    __syncthreads();                 // vmcnt(0) drain: staged data visible
    #pragma unroll
    for (int kk = 0; kk < 2; ++kk) {
      bf16x8 ah[4], al[4], bh[4], bl[4];
      #pragma unroll
      for (int f = 0; f < 4; ++f) {
        const int ar = wr * 64 + f * 16 + frow;
        const int aoff = ar * 128 + ((((kk << 2) + ksl) ^ (ar & 7)) << 4);
        ah[f] = *(const bf16x8*)((const char*)sAhi + aoff);
        al[f] = *(const bf16x8*)((const char*)sAlo + aoff);
        const int br_ = wc * 64 + f * 16 + frow;
        const int boff = br_ * 128 + ((((kk << 2) + ksl) ^ (br_ & 7)) << 4);
        bh[f] = *(const bf16x8*)((const char*)sBhi + boff);
        bl[f] = *(const bf16x8*)((const char*)sBlo + boff);
      }
      #pragma unroll
      for (int fm = 0; fm < 4; ++fm)
        #pragma unroll
        for (int fn = 0; fn < 4; ++fn) {
          acc[fm][fn] = __builtin_amdgcn_mfma_f32_16x16x32_bf16(ah[fm], bh[fn], acc[fm][fn], 0, 0, 0);
          acc[fm][fn] = __builtin_amdgcn_mfma_f32_16x16x32_bf16(ah[fm], bl[fn], acc[fm][fn], 0, 0, 0);
          acc[fm][fn] = __builtin_amdgcn_mfma_f32_16x16x32_bf16(al[fm], bh[fn], acc[fm][fn], 0, 0, 0);
        }
    }
  }

  // epilogue: C/D layout col = l&15, row = (l>>4)*4 + i
  const int crow0 = bm + wr * 64 + (l >> 4) * 4;
  const int ccol0 = bn + wc * 64 + (l & 15);
  #pragma unroll
  for (int fn = 0; fn < 4; ++fn) {
    const int col = ccol0 + fn * 16;
    const float bv = bias[col];
    #pragma unroll
    for (int fm = 0; fm < 4; ++fm) {
      const int r0 = crow0 + fm * 16;
      #pragma unroll
      for (int i = 0; i < 4; ++i)
        C[(size_t)(r0 + i) * ldc + col] = acc[fm][fn][i] + bv;
    }
  }
}

// ---------------- layer-0 recurrence (unchanged from round 5) ----------------
__global__ __launch_bounds__(NTHR, 1) void k_recur(const unsigned short* __restrict__ WhTb,
                                                   const float* __restrict__ GX0,
                                                   const float* __restrict__ bh0,
                                                   float* __restrict__ H0,
                                                   unsigned* __restrict__ bar,
                                                   float* __restrict__ hbuf) {
  __shared__ unsigned w_u32[24 * WSTR];
  __shared__ float h_lds[16 * 1024];
  __shared__ float red[8 * 416];
  const int wgid = blockIdx.x;
  const int tid = threadIdx.x;
  const int c = tid & 7, q = tid >> 3;
  const int lane = tid & 63, wv = tid >> 6;

  for (int i = tid; i < 24 * 512; i += NTHR) {
    const int rr = i >> 9, pidx = i & 511;
    const int g = rr >> 3, cc = rr & 7;
    const int grow = g * H_ + (wgid << 3) + cc;
    w_u32[rr * WSTR + pidx] = ((const unsigned*)WhTb)[(size_t)grow * 512 + pidx];
  }

  float bhr = 0.f, bhz = 0.f, bhn = 0.f;
  if (tid < 128) {
    const int col = (wgid << 3) + (tid & 7);
    bhr = bh0[col]; bhz = bh0[H_ + col]; bhn = bh0[2 * H_ + col];
  }

  const unsigned* __restrict__ w0 = w_u32 + (0 + c) * WSTR + (q << 3);
  const unsigned* __restrict__ w1 = w_u32 + (8 + c) * WSTR + (q << 3);
  const unsigned* __restrict__ w2 = w_u32 + (16 + c) * WSTR + (q << 3);
  const int koffbase = q << 4;

  for (int t = 0; t < T_; ++t) {
    if (t == 0) {
      #pragma unroll
      for (int r2 = 0; r2 < 32; ++r2) h_lds[(r2 << 9) + tid] = 0.f;
    } else {
      const float* __restrict__ hprev = hbuf + ((t - 1) & 1) * 16384;
      #pragma unroll
      for (int r2 = 0; r2 < 32; ++r2) {
        const int idx = (r2 << 9) + tid;
        h_lds[idx] = AGENT_LD(&hprev[idx]);
      }
    }
    __syncthreads();

    float xr = 0.f, xz = 0.f, xn = 0.f;
    if (tid < 128) {
      const int b0 = tid >> 3, c7 = tid & 7;
      const size_t row3 = (size_t)(b0 * T_ + t) * H3;
      const int col = (wgid << 3) + c7;
      xr = GX0[row3 + col]; xz = GX0[row3 + H_ + col]; xn = GX0[row3 + 2 * H_ + col];
    }

    float acc[16][3] = {};
    #pragma unroll
    for (int i = 0; i < 8; ++i) {
      const int ir = (i + q) & 7;
      const unsigned pr_ = w0[ir], pz_ = w1[ir], pn_ = w2[ir];
      const float wr0 = __uint_as_float(pr_ << 16), wr1 = __uint_as_float(pr_ & 0xffff0000u);
      const float wz0 = __uint_as_float(pz_ << 16), wz1 = __uint_as_float(pz_ & 0xffff0000u);
      const float wn0 = __uint_as_float(pn_ << 16), wn1 = __uint_as_float(pn_ & 0xffff0000u);
      const float* hp = h_lds + koffbase + (ir << 1);
      #pragma unroll
      for (int b = 0; b < 16; ++b) {
        const float2 h2 = *(const float2*)(hp + (b << 10));
        acc[b][0] = fmaf(h2.y, wr1, fmaf(h2.x, wr0, acc[b][0]));
        acc[b][1] = fmaf(h2.y, wz1, fmaf(h2.x, wz0, acc[b][1]));
        acc[b][2] = fmaf(h2.y, wn1, fmaf(h2.x, wn0, acc[b][2]));
      }
    }

    #pragma unroll
    for (int b = 0; b < 16; ++b)
      #pragma unroll
      for (int g = 0; g < 3; ++g) {
        float v = acc[b][g];
        v += __shfl_xor(v, 8);
        v += __shfl_xor(v, 16);
        v += __shfl_xor(v, 32);
        acc[b][g] = v;
      }
    if (lane < 8) {
      const int base = wv * 416 + lane * 52;
      #pragma unroll
      for (int b = 0; b < 16; ++b)
        #pragma unroll
        for (int g = 0; g < 3; ++g) red[base + b * 3 + g] = acc[b][g];
    }
    __syncthreads();

    if (tid < 128) {
      const int b0 = tid >> 3, c7 = tid & 7;
      float pr = 0.f, pz = 0.f, pn = 0.f;
      #pragma unroll
      for (int w8 = 0; w8 < 8; ++w8) {
        const int base = w8 * 416 + c7 * 52 + b0 * 3;
        pr += red[base]; pz += red[base + 1]; pn += red[base + 2];
      }
      const float r = 1.f / (1.f + expf(-(xr + pr + bhr)));
      const float z = 1.f / (1.f + expf(-(xz + pz + bhz)));
      const float n = tanhf(xn + r * (pn + bhn));
      const int col = (wgid << 3) + c7;
      const float hp = h_lds[(b0 << 10) + col];
      const float hnew = (1.f - z) * n + z * hp;
      H0[((size_t)(b0 * T_ + t) << 10) + col] = hnew;
      if (t + 1 < T_) AGENT_ST(&hbuf[(t & 1) * 16384 + (b0 << 10) + col], hnew);
    }

    if (t < T_ - 1) {
      __syncthreads();
      const unsigned p = (unsigned)(t + 1);
      if (tid == 0) AGENT_ST(&bar[wgid * 32], p);
      if (tid < 64) {
        for (;;) {
          const unsigned a0 = AGENT_LD(&bar[tid * 32]);
          const unsigned a1 = AGENT_LD(&bar[(tid + 64) * 32]);
          if (__all(a0 >= p && a1 >= p)) break;
          __builtin_amdgcn_s_sleep(1);
        }
      }
      __syncthreads();
    }
  }
}

// ---------------- layer-1 elementwise (separate gx/gh buffers) ----------------
__global__ __launch_bounds__(256) void k_gru1(const float* __restrict__ GX1,
                                              const float* __restrict__ GH1,
                                              const float* __restrict__ H0,
                                              float* __restrict__ H1, int row0) {
  const int lrow = blockIdx.x;
  const size_t row = (size_t)row0 + lrow;
  const float* gx = GX1 + (size_t)lrow * H3;
  const float* gh = GH1 + (size_t)lrow * H3;
  for (int j = threadIdx.x; j < H_; j += 256) {
    const float xr = gx[j], xz = gx[1024 + j], xn = gx[2048 + j];
    const float hr = gh[j], hz = gh[1024 + j], hn = gh[2048 + j];
    const float h = H0[(row << 10) + j];
    const float r = 1.f / (1.f + expf(-(xr + hr)));
    const float z = 1.f / (1.f + expf(-(xz + hz)));
    const float n = tanhf(xn + r * hn);
    H1[(row << 10) + j] = (1.f - z) * n + z * h;
  }
}

// ---------------- final hidden: out[2][B][H] ----------------
__global__ __launch_bounds__(256) void k_hidden(const float* __restrict__ H0,
                                                const float* __restrict__ H1,
                                                float* __restrict__ out) {
  const int i = blockIdx.x * 256 + threadIdx.x;
  const int l = i >> 14;
  const int b = (i >> 10) & 15;
  const int j = i & 1023;
  const float* src = l ? H1 : H0;
  out[i] = src[((size_t)(b * T_ + T_ - 1) << 10) + j];
}

extern "C" void kernel_launch(void* const* d_in, const int* in_sizes, int n_in,
                              void* d_out, int out_size, void* d_ws, size_t ws_size,
                              hipStream_t stream) {
  const int*   x   = (const int*)d_in[0];
  const float* emb = (const float*)d_in[1];
  const float* Wx0 = (const float*)d_in[2];
  const float* Wh0 = (const float*)d_in[3];
  const float* bx0 = (const float*)d_in[4];
  const float* bh0 = (const float*)d_in[5];
  const float* Wx1 = (const float*)d_in[6];
  const float* Wh1 = (const float*)d_in[7];
  const float* bx1 = (const float*)d_in[8];
  const float* bh1 = (const float*)d_in[9];
  const float* fcW = (const float*)d_in[10];
  const float* fcb = (const float*)d_in[11];
  float* out = (float*)d_out;

  char* ws = (char*)d_ws;
  const size_t MB = 1024 * 1024;
  // persistent
  float* H0 = (float*)(ws + 0);                 // 16 MB
  float* H1 = (float*)(ws + 16 * MB);           // 16 MB
  char*  S  = ws + 32 * MB;                     // scratch base
  // phase A/B
  unsigned short* WhTb = (unsigned short*)(S);            // 6 MB
  float*    GX0  = (float*)(S + 8 * MB);                  // 48 MB
  float*    EmbG = (float*)(S + 56 * MB);                 // 8 MB
  unsigned* bar  = (unsigned*)(S + 64 * MB);              // 64 KB
  float*    hbuf = (float*)(S + 64 * MB + 65536);         // 128 KB
  // phase C (layer 1)
  unsigned short* AHi  = (unsigned short*)(S);            // 8 MB  (H0 / later H1 hi)
  unsigned short* ALo  = (unsigned short*)(S + 8 * MB);   // 8 MB
  unsigned short* WxThi = (unsigned short*)(S + 16 * MB); // 6 MB
  unsigned short* WxTlo = (unsigned short*)(S + 22 * MB); // 6 MB
  unsigned short* WhThi = (unsigned short*)(S + 28 * MB); // 6 MB
  unsigned short* WhTlo = (unsigned short*)(S + 34 * MB); // 6 MB
  float* GX1 = (float*)(S + 40 * MB);                     // 24 MB (2048 rows)
  float* GH1 = (float*)(S + 64 * MB);                     // 24 MB
  // phase D (FC)
  unsigned short* fcThi = (unsigned short*)(S + 16 * MB); // 31.25 MB (16000x1024)
  unsigned short* fcTlo = (unsigned short*)(S + 48 * MB); // 31.25 MB

  // ---- phase A: embeddings, recur-W, GX0 ----
  k_embed<<<dim3(B_ * T_), dim3(128), 0, stream>>>(x, emb, EmbG);
  k_transpose_b16<<<dim3(H3 / 32, H_ / 32), dim3(256), 0, stream>>>(Wh0, WhTb);
  k_gemm<<<dim3(H3 / 64, (B_ * T_) / 128), dim3(256), 0, stream>>>(
      EmbG, Wx0, bx0, GX0, B_ * T_, H3, E_, H3);

  // ---- phase B: recurrence ----
  hipMemsetAsync(bar, 0, 65536, stream);
  {
    void* args[] = {(void*)&WhTb, (void*)&GX0, (void*)&bh0, (void*)&H0,
                    (void*)&bar, (void*)&hbuf};
    hipLaunchCooperativeKernel((const void*)k_recur, dim3(NWG), dim3(NTHR), args, 0, stream);
  }

  // ---- phase C: layer 1 via split-bf16 MFMA ----
  k_split<<<dim3(4096), dim3(256), 0, stream>>>(H0, AHi, ALo, (B_ * T_ * H_) / 4);
  k_transpose_split<<<dim3(H3 / 32, H_ / 32), dim3(256), 0, stream>>>(Wx1, H3, WxThi, WxTlo, H_);
  k_transpose_split<<<dim3(H3 / 32, H_ / 32), dim3(256), 0, stream>>>(Wh1, H3, WhThi, WhTlo, H_);
  for (int chunk = 0; chunk < 2; ++chunk) {
    const unsigned short* Ah = AHi + (size_t)chunk * 2048 * H_;
    const unsigned short* Al = ALo + (size_t)chunk * 2048 * H_;
    k_gemm_mfma<<<dim3(16 * 24), dim3(256), 0, stream>>>(
        Ah, Al, WxThi, WxTlo, bx1, GX1, 16, 24, H_, H3);
    k_gemm_mfma<<<dim3(16 * 24), dim3(256), 0, stream>>>(
        Ah, Al, WhThi, WhTlo, bh1, GH1, 16, 24, H_, H3);
    k_gru1<<<dim3(2048), dim3(256), 0, stream>>>(GX1, GH1, H0, H1, chunk * 2048);
  }

  // ---- phase D: FC via split-bf16 MFMA, 2 N-chunks of 16000 ----
  k_split<<<dim3(4096), dim3(256), 0, stream>>>(H1, AHi, ALo, (B_ * T_ * H_) / 4);
  for (int chunk = 0; chunk < 2; ++chunk) {
    const float* Wc = fcW + (size_t)chunk * 16000;
    k_transpose_split<<<dim3(16000 / 32, H_ / 32), dim3(256), 0, stream>>>(
        Wc, V_, fcThi, fcTlo, H_);
    k_gemm_mfma<<<dim3(32 * 125), dim3(256), 0, stream>>>(
        AHi, ALo, fcThi, fcTlo, fcb + (size_t)chunk * 16000,
        out + (size_t)chunk * 16000, 32, 125, H_, V_);
  }

  // ---- final hidden ----
  k_hidden<<<dim3(32768 / 256), dim3(256), 0, stream>>>(H0, H1, out + (size_t)B_ * T_ * V_);
}

// Round 7
// 4000.368 us; speedup vs baseline: 6.3024x; 1.3169x over previous
//
#include <hip/hip_runtime.h>
#include <hip/hip_bf16.h>

#define V_  32000
#define E_  512
#define H_  1024
#define B_  16
#define T_  256
#define H3  3072

#define NWG   128
#define NTHR  512
#define WSTR  513                 // recur w_lds row stride in u32 pairs

#define AGENT_LD(p)    __hip_atomic_load((p),  __ATOMIC_RELAXED, __HIP_MEMORY_SCOPE_AGENT)
#define AGENT_ST(p, v) __hip_atomic_store((p), (v), __ATOMIC_RELAXED, __HIP_MEMORY_SCOPE_AGENT)

typedef __attribute__((ext_vector_type(8))) short bf16x8;
typedef __attribute__((ext_vector_type(4))) float f32x4;

#define GLDS16(gp, lp) __builtin_amdgcn_global_load_lds( \
    (const __attribute__((address_space(1))) unsigned int*)(gp), \
    (__attribute__((address_space(3))) unsigned int*)(lp), 16, 0, 0)

// ---------------- embedding gather + hi/lo split ----------------
__global__ __launch_bounds__(128) void k_embed_split(const int* __restrict__ x,
                                                     const float* __restrict__ emb,
                                                     unsigned short* __restrict__ hi,
                                                     unsigned short* __restrict__ lo) {
  const int row = blockIdx.x;
  const int idx = x[row];
  const float4 v = ((const float4*)(emb + (size_t)idx * E_))[threadIdx.x];
  const float f[4] = {v.x, v.y, v.z, v.w};
  unsigned short hh[4], ll[4];
  #pragma unroll
  for (int k = 0; k < 4; ++k) {
    const __hip_bfloat16 hb = __float2bfloat16(f[k]);
    hh[k] = *(const unsigned short*)&hb;
    const __hip_bfloat16 lb = __float2bfloat16(f[k] - __bfloat162float(hb));
    ll[k] = *(const unsigned short*)&lb;
  }
  ushort4 h4; h4.x = hh[0]; h4.y = hh[1]; h4.z = hh[2]; h4.w = hh[3];
  ushort4 l4; l4.x = ll[0]; l4.y = ll[1]; l4.z = ll[2]; l4.w = ll[3];
  ((ushort4*)(hi + (size_t)row * E_))[threadIdx.x] = h4;
  ((ushort4*)(lo + (size_t)row * E_))[threadIdx.x] = l4;
}

// ---------------- transpose Wh0 [1024][3072] -> WhTb [3072][1024] bf16 ----------------
__global__ __launch_bounds__(256) void k_transpose_b16(const float* __restrict__ W,
                                                       unsigned short* __restrict__ WTb) {
  __shared__ float tile[32][33];
  const int c0 = blockIdx.x * 32, r0 = blockIdx.y * 32;
  const int tx = threadIdx.x & 31, ty = threadIdx.x >> 5;
  #pragma unroll
  for (int i = ty; i < 32; i += 8)
    tile[i][tx] = W[(size_t)(r0 + i) * H3 + c0 + tx];
  __syncthreads();
  #pragma unroll
  for (int i = ty; i < 32; i += 8) {
    const __hip_bfloat16 v = __float2bfloat16(tile[tx][i]);
    WTb[(size_t)(c0 + i) * H_ + r0 + tx] = *(const unsigned short*)&v;
  }
}

// ---------------- transpose + hi/lo split: W [R][ldw] f32 -> WT hi/lo [C][R] bf16 ----------------
__global__ __launch_bounds__(256) void k_transpose_split(const float* __restrict__ W, int ldw,
                                                         unsigned short* __restrict__ WThi,
                                                         unsigned short* __restrict__ WTlo,
                                                         int R) {
  __shared__ float tile[32][33];
  const int c0 = blockIdx.x * 32, r0 = blockIdx.y * 32;
  const int tx = threadIdx.x & 31, ty = threadIdx.x >> 5;
  #pragma unroll
  for (int i = ty; i < 32; i += 8)
    tile[i][tx] = W[(size_t)(r0 + i) * ldw + c0 + tx];
  __syncthreads();
  #pragma unroll
  for (int i = ty; i < 32; i += 8) {
    const float v = tile[tx][i];
    const __hip_bfloat16 hb = __float2bfloat16(v);
    const float rr = v - __bfloat162float(hb);
    const __hip_bfloat16 lb = __float2bfloat16(rr);
    WThi[(size_t)(c0 + i) * R + r0 + tx] = *(const unsigned short*)&hb;
    WTlo[(size_t)(c0 + i) * R + r0 + tx] = *(const unsigned short*)&lb;
  }
}

// ---------------- elementwise hi/lo split ----------------
__global__ __launch_bounds__(256) void k_split(const float* __restrict__ x,
                                               unsigned short* __restrict__ hi,
                                               unsigned short* __restrict__ lo, int n4) {
  const int i = blockIdx.x * 256 + threadIdx.x;
  if (i >= n4) return;
  const float4 v = ((const float4*)x)[i];
  const float f[4] = {v.x, v.y, v.z, v.w};
  unsigned short hh[4], ll[4];
  #pragma unroll
  for (int k = 0; k < 4; ++k) {
    const __hip_bfloat16 hb = __float2bfloat16(f[k]);
    hh[k] = *(const unsigned short*)&hb;
    const __hip_bfloat16 lb = __float2bfloat16(f[k] - __bfloat162float(hb));
    ll[k] = *(const unsigned short*)&lb;
  }
  ushort4 h4; h4.x = hh[0]; h4.y = hh[1]; h4.z = hh[2]; h4.w = hh[3];
  ushort4 l4; l4.x = ll[0]; l4.y = ll[1]; l4.z = ll[2]; l4.w = ll[3];
  ((ushort4*)hi)[i] = h4;
  ((ushort4*)lo)[i] = l4;
}

// ---------------- split-bf16 MFMA GEMM (unchanged from round 6) ----------------
__global__ __launch_bounds__(256, 2) void k_gemm_mfma(
    const unsigned short* __restrict__ Ahi, const unsigned short* __restrict__ Alo,
    const unsigned short* __restrict__ BThi, const unsigned short* __restrict__ BTlo,
    const float* __restrict__ bias, float* __restrict__ C,
    int MT, int NT, int K, int ldc) {
  __shared__ unsigned short sAhi[128 * 64], sAlo[128 * 64];
  __shared__ unsigned short sBhi[128 * 64], sBlo[128 * 64];

  const int bid = blockIdx.x;
  const int GROUPM = 8;
  const int group = bid / (GROUPM * NT);
  const int first = group * GROUPM;
  const int gsm = (MT - first < GROUPM) ? (MT - first) : GROUPM;
  const int rem = bid % (GROUPM * NT);
  const int pm = first + rem % gsm;
  const int pn = rem / gsm;
  const int bm = pm * 128, bn = pn * 128;

  const int tid = threadIdx.x;
  const int wv = tid >> 6, l = tid & 63;
  const int wr = wv >> 1, wc = wv & 1;
  const int frow = l & 15;
  const int ksl  = l >> 4;

  f32x4 acc[4][4];
  #pragma unroll
  for (int a = 0; a < 4; ++a)
    #pragma unroll
    for (int b = 0; b < 4; ++b) acc[a][b] = (f32x4){0.f, 0.f, 0.f, 0.f};

  for (int k0 = 0; k0 < K; k0 += 64) {
    __syncthreads();
    #pragma unroll
    for (int p = 0; p < 4; ++p) {
      const int obase = ((p << 2) + wv) << 10;
      const int row = ((obase >> 7)) + (l >> 3);
      const int slot = l & 7;
      const int gcol = k0 + ((slot ^ (row & 7)) << 3);
      const size_t ga = (size_t)(bm + row) * K + gcol;
      const size_t gb = (size_t)(bn + row) * K + gcol;
      GLDS16(Ahi + ga, (char*)sAhi + obase);
      GLDS16(Alo + ga, (char*)sAlo + obase);
      GLDS16(BThi + gb, (char*)sBhi + obase);
      GLDS16(BTlo + gb, (char*)sBlo + obase);
    }
    __syncthreads();
    #pragma unroll
    for (int kk = 0; kk < 2; ++kk) {
      bf16x8 ah[4], al[4], bh[4], bl[4];
      #pragma unroll
      for (int f = 0; f < 4; ++f) {
        const int ar = wr * 64 + f * 16 + frow;
        const int aoff = ar * 128 + ((((kk << 2) + ksl) ^ (ar & 7)) << 4);
        ah[f] = *(const bf16x8*)((const char*)sAhi + aoff);
        al[f] = *(const bf16x8*)((const char*)sAlo + aoff);
        const int br_ = wc * 64 + f * 16 + frow;
        const int boff = br_ * 128 + ((((kk << 2) + ksl) ^ (br_ & 7)) << 4);
        bh[f] = *(const bf16x8*)((const char*)sBhi + boff);
        bl[f] = *(const bf16x8*)((const char*)sBlo + boff);
      }
      #pragma unroll
      for (int fm = 0; fm < 4; ++fm)
        #pragma unroll
        for (int fn = 0; fn < 4; ++fn) {
          acc[fm][fn] = __builtin_amdgcn_mfma_f32_16x16x32_bf16(ah[fm], bh[fn], acc[fm][fn], 0, 0, 0);
          acc[fm][fn] = __builtin_amdgcn_mfma_f32_16x16x32_bf16(ah[fm], bl[fn], acc[fm][fn], 0, 0, 0);
          acc[fm][fn] = __builtin_amdgcn_mfma_f32_16x16x32_bf16(al[fm], bh[fn], acc[fm][fn], 0, 0, 0);
        }
    }
  }

  const int crow0 = bm + wr * 64 + (l >> 4) * 4;
  const int ccol0 = bn + wc * 64 + (l & 15);
  #pragma unroll
  for (int fn = 0; fn < 4; ++fn) {
    const int col = ccol0 + fn * 16;
    const float bv = bias[col];
    #pragma unroll
    for (int fm = 0; fm < 4; ++fm) {
      const int r0 = crow0 + fm * 16;
      #pragma unroll
      for (int i = 0; i < 4; ++i)
        C[(size_t)(r0 + i) * ldc + col] = acc[fm][fn][i] + bv;
    }
  }
}

// ---------------- layer-0 recurrence: wide coherent staging + packed flags ----------------
__global__ __launch_bounds__(NTHR, 1) void k_recur(const unsigned short* __restrict__ WhTb,
                                                   const float* __restrict__ GX0,
                                                   const float* __restrict__ bh0,
                                                   float* __restrict__ H0,
                                                   unsigned* __restrict__ bar,   // flags packed 4B stride
                                                   float* __restrict__ hbuf) {   // [2][16384] f32
  __shared__ unsigned w_u32[24 * WSTR];
  __shared__ float h_lds[16 * 1024];
  __shared__ float red[8 * 416];
  const int wgid = blockIdx.x;
  const int tid = threadIdx.x;
  const int c = tid & 7, q = tid >> 3;
  const int lane = tid & 63, wv = tid >> 6;

  for (int i = tid; i < 24 * 512; i += NTHR) {
    const int rr = i >> 9, pidx = i & 511;
    const int g = rr >> 3, cc = rr & 7;
    const int grow = g * H_ + (wgid << 3) + cc;
    w_u32[rr * WSTR + pidx] = ((const unsigned*)WhTb)[(size_t)grow * 512 + pidx];
  }

  float bhr = 0.f, bhz = 0.f, bhn = 0.f;
  if (tid < 128) {
    const int col = (wgid << 3) + (tid & 7);
    bhr = bh0[col]; bhz = bh0[H_ + col]; bhn = bh0[2 * H_ + col];
  }

  const unsigned* __restrict__ w0 = w_u32 + (0 + c) * WSTR + (q << 3);
  const unsigned* __restrict__ w1 = w_u32 + (8 + c) * WSTR + (q << 3);
  const unsigned* __restrict__ w2 = w_u32 + (16 + c) * WSTR + (q << 3);
  const int koffbase = q << 4;

  for (int t = 0; t < T_; ++t) {
    // ---- stage h_{t-1}: 8x dwordx4 coherent loads per thread (data immutable now) ----
    if (t == 0) {
      #pragma unroll
      for (int r2 = 0; r2 < 32; ++r2) h_lds[(r2 << 9) + tid] = 0.f;
    } else {
      const char* hsrc = (const char*)(hbuf + ((t - 1) & 1) * 16384) + (tid << 4);
      f32x4 hv[8];
      #pragma unroll
      for (int r = 0; r < 8; ++r)
        asm volatile("global_load_dwordx4 %0, %1, off sc0 sc1"
                     : "=v"(hv[r]) : "v"(hsrc + (r << 13)));
      asm volatile("s_waitcnt vmcnt(0)" ::: "memory");
      #pragma unroll
      for (int r = 0; r < 8; ++r)
        *(f32x4*)&h_lds[(r << 11) + (tid << 2)] = hv[r];
    }
    __syncthreads();

    float xr = 0.f, xz = 0.f, xn = 0.f;
    if (tid < 128) {
      const int b0 = tid >> 3, c7 = tid & 7;
      const size_t row3 = (size_t)(b0 * T_ + t) * H3;
      const int col = (wgid << 3) + c7;
      xr = GX0[row3 + col]; xz = GX0[row3 + H_ + col]; xn = GX0[row3 + 2 * H_ + col];
    }

    float acc[16][3] = {};
    #pragma unroll
    for (int i = 0; i < 8; ++i) {
      const int ir = (i + q) & 7;
      const unsigned pr_ = w0[ir], pz_ = w1[ir], pn_ = w2[ir];
      const float wr0 = __uint_as_float(pr_ << 16), wr1 = __uint_as_float(pr_ & 0xffff0000u);
      const float wz0 = __uint_as_float(pz_ << 16), wz1 = __uint_as_float(pz_ & 0xffff0000u);
      const float wn0 = __uint_as_float(pn_ << 16), wn1 = __uint_as_float(pn_ & 0xffff0000u);
      const float* hp = h_lds + koffbase + (ir << 1);
      #pragma unroll
      for (int b = 0; b < 16; ++b) {
        const float2 h2 = *(const float2*)(hp + (b << 10));
        acc[b][0] = fmaf(h2.y, wr1, fmaf(h2.x, wr0, acc[b][0]));
        acc[b][1] = fmaf(h2.y, wz1, fmaf(h2.x, wz0, acc[b][1]));
        acc[b][2] = fmaf(h2.y, wn1, fmaf(h2.x, wn0, acc[b][2]));
      }
    }

    #pragma unroll
    for (int b = 0; b < 16; ++b)
      #pragma unroll
      for (int g = 0; g < 3; ++g) {
        float v = acc[b][g];
        v += __shfl_xor(v, 8);
        v += __shfl_xor(v, 16);
        v += __shfl_xor(v, 32);
        acc[b][g] = v;
      }
    if (lane < 8) {
      const int base = wv * 416 + lane * 52;
      #pragma unroll
      for (int b = 0; b < 16; ++b)
        #pragma unroll
        for (int g = 0; g < 3; ++g) red[base + b * 3 + g] = acc[b][g];
    }
    __syncthreads();

    if (tid < 128) {
      const int b0 = tid >> 3, c7 = tid & 7;
      float pr = 0.f, pz = 0.f, pn = 0.f;
      #pragma unroll
      for (int w8 = 0; w8 < 8; ++w8) {
        const int base = w8 * 416 + c7 * 52 + b0 * 3;
        pr += red[base]; pz += red[base + 1]; pn += red[base + 2];
      }
      const float r = 1.f / (1.f + expf(-(xr + pr + bhr)));
      const float z = 1.f / (1.f + expf(-(xz + pz + bhz)));
      const float n = tanhf(xn + r * (pn + bhn));
      const int col = (wgid << 3) + c7;
      const float hp = h_lds[(b0 << 10) + col];
      const float hnew = (1.f - z) * n + z * hp;
      H0[((size_t)(b0 * T_ + t) << 10) + col] = hnew;
      if (t + 1 < T_) AGENT_ST(&hbuf[(t & 1) * 16384 + (b0 << 10) + col], hnew);
    }

    if (t < T_ - 1) {
      __syncthreads();                      // vmcnt(0): h stores globally visible
      const unsigned p = (unsigned)(t + 1);
      if (tid == 0) AGENT_ST(&bar[wgid], p);
      if (tid < 64) {
        for (;;) {
          const unsigned a0 = AGENT_LD(&bar[tid]);
          const unsigned a1 = AGENT_LD(&bar[tid + 64]);
          if (__all(a0 >= p && a1 >= p)) break;
          __builtin_amdgcn_s_sleep(1);
        }
      }
      __syncthreads();
    }
  }
}

// ---------------- layer-1 elementwise ----------------
__global__ __launch_bounds__(256) void k_gru1(const float* __restrict__ GX1,
                                              const float* __restrict__ GH1,
                                              const float* __restrict__ H0,
                                              float* __restrict__ H1, int row0) {
  const int lrow = blockIdx.x;
  const size_t row = (size_t)row0 + lrow;
  const float* gx = GX1 + (size_t)lrow * H3;
  const float* gh = GH1 + (size_t)lrow * H3;
  for (int j = threadIdx.x; j < H_; j += 256) {
    const float xr = gx[j], xz = gx[1024 + j], xn = gx[2048 + j];
    const float hr = gh[j], hz = gh[1024 + j], hn = gh[2048 + j];
    const float h = H0[(row << 10) + j];
    const float r = 1.f / (1.f + expf(-(xr + hr)));
    const float z = 1.f / (1.f + expf(-(xz + hz)));
    const float n = tanhf(xn + r * hn);
    H1[(row << 10) + j] = (1.f - z) * n + z * h;
  }
}

// ---------------- final hidden: out[2][B][H] ----------------
__global__ __launch_bounds__(256) void k_hidden(const float* __restrict__ H0,
                                                const float* __restrict__ H1,
                                                float* __restrict__ out) {
  const int i = blockIdx.x * 256 + threadIdx.x;
  const int l = i >> 14;
  const int b = (i >> 10) & 15;
  const int j = i & 1023;
  const float* src = l ? H1 : H0;
  out[i] = src[((size_t)(b * T_ + T_ - 1) << 10) + j];
}

extern "C" void kernel_launch(void* const* d_in, const int* in_sizes, int n_in,
                              void* d_out, int out_size, void* d_ws, size_t ws_size,
                              hipStream_t stream) {
  const int*   x   = (const int*)d_in[0];
  const float* emb = (const float*)d_in[1];
  const float* Wx0 = (const float*)d_in[2];
  const float* Wh0 = (const float*)d_in[3];
  const float* bx0 = (const float*)d_in[4];
  const float* bh0 = (const float*)d_in[5];
  const float* Wx1 = (const float*)d_in[6];
  const float* Wh1 = (const float*)d_in[7];
  const float* bx1 = (const float*)d_in[8];
  const float* bh1 = (const float*)d_in[9];
  const float* fcW = (const float*)d_in[10];
  const float* fcb = (const float*)d_in[11];
  float* out = (float*)d_out;

  char* ws = (char*)d_ws;
  const size_t MB = 1024 * 1024;
  // persistent
  float* H0 = (float*)(ws + 0);                 // 16 MB
  float* H1 = (float*)(ws + 16 * MB);           // 16 MB
  char*  S  = ws + 32 * MB;
  // phase A/B
  unsigned short* WhTb  = (unsigned short*)(S);           // 6 MB
  float*          GX0   = (float*)(S + 8 * MB);           // 48 MB
  unsigned short* EmbHi = (unsigned short*)(S + 56 * MB); // 4 MB
  unsigned short* EmbLo = (unsigned short*)(S + 60 * MB); // 4 MB
  unsigned short* Wx0Thi= (unsigned short*)(S + 64 * MB); // 3 MB
  unsigned short* Wx0Tlo= (unsigned short*)(S + 67 * MB); // 3 MB
  unsigned*       bar   = (unsigned*)(S + 72 * MB);       // 64 KB
  float*          hbuf  = (float*)(S + 72 * MB + 65536);  // 128 KB
  // phase C (layer 1)
  unsigned short* AHi   = (unsigned short*)(S);           // 8 MB
  unsigned short* ALo   = (unsigned short*)(S + 8 * MB);  // 8 MB
  unsigned short* WxThi = (unsigned short*)(S + 16 * MB); // 6 MB
  unsigned short* WxTlo = (unsigned short*)(S + 22 * MB); // 6 MB
  unsigned short* WhThi = (unsigned short*)(S + 28 * MB); // 6 MB
  unsigned short* WhTlo = (unsigned short*)(S + 34 * MB); // 6 MB
  float* GX1 = (float*)(S + 40 * MB);                     // 24 MB
  float* GH1 = (float*)(S + 64 * MB);                     // 24 MB
  // phase D (FC)
  unsigned short* fcThi = (unsigned short*)(S + 16 * MB); // 31.25 MB
  unsigned short* fcTlo = (unsigned short*)(S + 48 * MB); // 31.25 MB

  // ---- phase A: embeddings (split), recur-W, GX0 via MFMA ----
  k_embed_split<<<dim3(B_ * T_), dim3(128), 0, stream>>>(x, emb, EmbHi, EmbLo);
  k_transpose_b16<<<dim3(H3 / 32, H_ / 32), dim3(256), 0, stream>>>(Wh0, WhTb);
  k_transpose_split<<<dim3(H3 / 32, E_ / 32), dim3(256), 0, stream>>>(Wx0, H3, Wx0Thi, Wx0Tlo, E_);
  k_gemm_mfma<<<dim3(32 * 24), dim3(256), 0, stream>>>(
      EmbHi, EmbLo, Wx0Thi, Wx0Tlo, bx0, GX0, 32, 24, E_, H3);

  // ---- phase B: recurrence ----
  hipMemsetAsync(bar, 0, 65536, stream);
  {
    void* args[] = {(void*)&WhTb, (void*)&GX0, (void*)&bh0, (void*)&H0,
                    (void*)&bar, (void*)&hbuf};
    hipLaunchCooperativeKernel((const void*)k_recur, dim3(NWG), dim3(NTHR), args, 0, stream);
  }

  // ---- phase C: layer 1 via split-bf16 MFMA ----
  k_split<<<dim3(4096), dim3(256), 0, stream>>>(H0, AHi, ALo, (B_ * T_ * H_) / 4);
  k_transpose_split<<<dim3(H3 / 32, H_ / 32), dim3(256), 0, stream>>>(Wx1, H3, WxThi, WxTlo, H_);
  k_transpose_split<<<dim3(H3 / 32, H_ / 32), dim3(256), 0, stream>>>(Wh1, H3, WhThi, WhTlo, H_);
  for (int chunk = 0; chunk < 2; ++chunk) {
    const unsigned short* Ah = AHi + (size_t)chunk * 2048 * H_;
    const unsigned short* Al = ALo + (size_t)chunk * 2048 * H_;
    k_gemm_mfma<<<dim3(16 * 24), dim3(256), 0, stream>>>(
        Ah, Al, WxThi, WxTlo, bx1, GX1, 16, 24, H_, H3);
    k_gemm_mfma<<<dim3(16 * 24), dim3(256), 0, stream>>>(
        Ah, Al, WhThi, WhTlo, bh1, GH1, 16, 24, H_, H3);
    k_gru1<<<dim3(2048), dim3(256), 0, stream>>>(GX1, GH1, H0, H1, chunk * 2048);
  }

  // ---- phase D: FC via split-bf16 MFMA, 2 N-chunks of 16000 ----
  k_split<<<dim3(4096), dim3(256), 0, stream>>>(H1, AHi, ALo, (B_ * T_ * H_) / 4);
  for (int chunk = 0; chunk < 2; ++chunk) {
    const float* Wc = fcW + (size_t)chunk * 16000;
    k_transpose_split<<<dim3(16000 / 32, H_ / 32), dim3(256), 0, stream>>>(
        Wc, V_, fcThi, fcTlo, H_);
    k_gemm_mfma<<<dim3(32 * 125), dim3(256), 0, stream>>>(
        AHi, ALo, fcThi, fcTlo, fcb + (size_t)chunk * 16000,
        out + (size_t)chunk * 16000, 32, 125, H_, V_);
  }

  // ---- final hidden ----
  k_hidden<<<dim3(32768 / 256), dim3(256), 0, stream>>>(H0, H1, out + (size_t)B_ * T_ * V_);
}

// Round 8
// 3448.532 us; speedup vs baseline: 7.3110x; 1.1600x over previous
//
#include <hip/hip_runtime.h>
#include <hip/hip_bf16.h>

#define V_  32000
#define E_  512
#define H_  1024
#define B_  16
#define T_  256
#define H3  3072

#define NWG   128
#define NTHR  512
#define WSTR  513                 // recur w_lds row stride in u32 pairs

#define AGENT_LD(p)    __hip_atomic_load((p),  __ATOMIC_RELAXED, __HIP_MEMORY_SCOPE_AGENT)
#define AGENT_ST(p, v) __hip_atomic_store((p), (v), __ATOMIC_RELAXED, __HIP_MEMORY_SCOPE_AGENT)

typedef __attribute__((ext_vector_type(8))) short bf16x8;
typedef __attribute__((ext_vector_type(4))) float f32x4;

#define GLDS16(gp, lp) __builtin_amdgcn_global_load_lds( \
    (const __attribute__((address_space(1))) unsigned int*)(gp), \
    (__attribute__((address_space(3))) unsigned int*)(lp), 16, 0, 0)

// ---------------- embedding gather + hi/lo split ----------------
__global__ __launch_bounds__(128) void k_embed_split(const int* __restrict__ x,
                                                     const float* __restrict__ emb,
                                                     unsigned short* __restrict__ hi,
                                                     unsigned short* __restrict__ lo) {
  const int row = blockIdx.x;
  const int idx = x[row];
  const float4 v = ((const float4*)(emb + (size_t)idx * E_))[threadIdx.x];
  const float f[4] = {v.x, v.y, v.z, v.w};
  unsigned short hh[4], ll[4];
  #pragma unroll
  for (int k = 0; k < 4; ++k) {
    const __hip_bfloat16 hb = __float2bfloat16(f[k]);
    hh[k] = *(const unsigned short*)&hb;
    const __hip_bfloat16 lb = __float2bfloat16(f[k] - __bfloat162float(hb));
    ll[k] = *(const unsigned short*)&lb;
  }
  ushort4 h4; h4.x = hh[0]; h4.y = hh[1]; h4.z = hh[2]; h4.w = hh[3];
  ushort4 l4; l4.x = ll[0]; l4.y = ll[1]; l4.z = ll[2]; l4.w = ll[3];
  ((ushort4*)(hi + (size_t)row * E_))[threadIdx.x] = h4;
  ((ushort4*)(lo + (size_t)row * E_))[threadIdx.x] = l4;
}

// ---------------- transpose Wh0 [1024][3072] -> WhTb [3072][1024] bf16 ----------------
__global__ __launch_bounds__(256) void k_transpose_b16(const float* __restrict__ W,
                                                       unsigned short* __restrict__ WTb) {
  __shared__ float tile[32][33];
  const int c0 = blockIdx.x * 32, r0 = blockIdx.y * 32;
  const int tx = threadIdx.x & 31, ty = threadIdx.x >> 5;
  #pragma unroll
  for (int i = ty; i < 32; i += 8)
    tile[i][tx] = W[(size_t)(r0 + i) * H3 + c0 + tx];
  __syncthreads();
  #pragma unroll
  for (int i = ty; i < 32; i += 8) {
    const __hip_bfloat16 v = __float2bfloat16(tile[tx][i]);
    WTb[(size_t)(c0 + i) * H_ + r0 + tx] = *(const unsigned short*)&v;
  }
}

// ---------------- transpose + hi/lo split: W [R][ldw] f32 -> WT hi/lo [C][R] bf16 ----------------
__global__ __launch_bounds__(256) void k_transpose_split(const float* __restrict__ W, int ldw,
                                                         unsigned short* __restrict__ WThi,
                                                         unsigned short* __restrict__ WTlo,
                                                         int R) {
  __shared__ float tile[32][33];
  const int c0 = blockIdx.x * 32, r0 = blockIdx.y * 32;
  const int tx = threadIdx.x & 31, ty = threadIdx.x >> 5;
  #pragma unroll
  for (int i = ty; i < 32; i += 8)
    tile[i][tx] = W[(size_t)(r0 + i) * ldw + c0 + tx];
  __syncthreads();
  #pragma unroll
  for (int i = ty; i < 32; i += 8) {
    const float v = tile[tx][i];
    const __hip_bfloat16 hb = __float2bfloat16(v);
    const float rr = v - __bfloat162float(hb);
    const __hip_bfloat16 lb = __float2bfloat16(rr);
    WThi[(size_t)(c0 + i) * R + r0 + tx] = *(const unsigned short*)&hb;
    WTlo[(size_t)(c0 + i) * R + r0 + tx] = *(const unsigned short*)&lb;
  }
}

// ---------------- elementwise hi/lo split ----------------
__global__ __launch_bounds__(256) void k_split(const float* __restrict__ x,
                                               unsigned short* __restrict__ hi,
                                               unsigned short* __restrict__ lo, int n4) {
  const int i = blockIdx.x * 256 + threadIdx.x;
  if (i >= n4) return;
  const float4 v = ((const float4*)x)[i];
  const float f[4] = {v.x, v.y, v.z, v.w};
  unsigned short hh[4], ll[4];
  #pragma unroll
  for (int k = 0; k < 4; ++k) {
    const __hip_bfloat16 hb = __float2bfloat16(f[k]);
    hh[k] = *(const unsigned short*)&hb;
    const __hip_bfloat16 lb = __float2bfloat16(f[k] - __bfloat162float(hb));
    ll[k] = *(const unsigned short*)&lb;
  }
  ushort4 h4; h4.x = hh[0]; h4.y = hh[1]; h4.z = hh[2]; h4.w = hh[3];
  ushort4 l4; l4.x = ll[0]; l4.y = ll[1]; l4.z = ll[2]; l4.w = ll[3];
  ((ushort4*)hi)[i] = h4;
  ((ushort4*)lo)[i] = l4;
}

// ---------------- split-bf16 MFMA GEMM (unchanged) ----------------
__global__ __launch_bounds__(256, 2) void k_gemm_mfma(
    const unsigned short* __restrict__ Ahi, const unsigned short* __restrict__ Alo,
    const unsigned short* __restrict__ BThi, const unsigned short* __restrict__ BTlo,
    const float* __restrict__ bias, float* __restrict__ C,
    int MT, int NT, int K, int ldc) {
  __shared__ unsigned short sAhi[128 * 64], sAlo[128 * 64];
  __shared__ unsigned short sBhi[128 * 64], sBlo[128 * 64];

  const int bid = blockIdx.x;
  const int GROUPM = 8;
  const int group = bid / (GROUPM * NT);
  const int first = group * GROUPM;
  const int gsm = (MT - first < GROUPM) ? (MT - first) : GROUPM;
  const int rem = bid % (GROUPM * NT);
  const int pm = first + rem % gsm;
  const int pn = rem / gsm;
  const int bm = pm * 128, bn = pn * 128;

  const int tid = threadIdx.x;
  const int wv = tid >> 6, l = tid & 63;
  const int wr = wv >> 1, wc = wv & 1;
  const int frow = l & 15;
  const int ksl  = l >> 4;

  f32x4 acc[4][4];
  #pragma unroll
  for (int a = 0; a < 4; ++a)
    #pragma unroll
    for (int b = 0; b < 4; ++b) acc[a][b] = (f32x4){0.f, 0.f, 0.f, 0.f};

  for (int k0 = 0; k0 < K; k0 += 64) {
    __syncthreads();
    #pragma unroll
    for (int p = 0; p < 4; ++p) {
      const int obase = ((p << 2) + wv) << 10;
      const int row = ((obase >> 7)) + (l >> 3);
      const int slot = l & 7;
      const int gcol = k0 + ((slot ^ (row & 7)) << 3);
      const size_t ga = (size_t)(bm + row) * K + gcol;
      const size_t gb = (size_t)(bn + row) * K + gcol;
      GLDS16(Ahi + ga, (char*)sAhi + obase);
      GLDS16(Alo + ga, (char*)sAlo + obase);
      GLDS16(BThi + gb, (char*)sBhi + obase);
      GLDS16(BTlo + gb, (char*)sBlo + obase);
    }
    __syncthreads();
    #pragma unroll
    for (int kk = 0; kk < 2; ++kk) {
      bf16x8 ah[4], al[4], bh[4], bl[4];
      #pragma unroll
      for (int f = 0; f < 4; ++f) {
        const int ar = wr * 64 + f * 16 + frow;
        const int aoff = ar * 128 + ((((kk << 2) + ksl) ^ (ar & 7)) << 4);
        ah[f] = *(const bf16x8*)((const char*)sAhi + aoff);
        al[f] = *(const bf16x8*)((const char*)sAlo + aoff);
        const int br_ = wc * 64 + f * 16 + frow;
        const int boff = br_ * 128 + ((((kk << 2) + ksl) ^ (br_ & 7)) << 4);
        bh[f] = *(const bf16x8*)((const char*)sBhi + boff);
        bl[f] = *(const bf16x8*)((const char*)sBlo + boff);
      }
      #pragma unroll
      for (int fm = 0; fm < 4; ++fm)
        #pragma unroll
        for (int fn = 0; fn < 4; ++fn) {
          acc[fm][fn] = __builtin_amdgcn_mfma_f32_16x16x32_bf16(ah[fm], bh[fn], acc[fm][fn], 0, 0, 0);
          acc[fm][fn] = __builtin_amdgcn_mfma_f32_16x16x32_bf16(ah[fm], bl[fn], acc[fm][fn], 0, 0, 0);
          acc[fm][fn] = __builtin_amdgcn_mfma_f32_16x16x32_bf16(al[fm], bh[fn], acc[fm][fn], 0, 0, 0);
        }
    }
  }

  const int crow0 = bm + wr * 64 + (l >> 4) * 4;
  const int ccol0 = bn + wc * 64 + (l & 15);
  #pragma unroll
  for (int fn = 0; fn < 4; ++fn) {
    const int col = ccol0 + fn * 16;
    const float bv = bias[col];
    #pragma unroll
    for (int fm = 0; fm < 4; ++fm) {
      const int r0 = crow0 + fm * 16;
      #pragma unroll
      for (int i = 0; i < 4; ++i)
        C[(size_t)(r0 + i) * ldc + col] = acc[fm][fn][i] + bv;
    }
  }
}

// ---------------- layer-0 recurrence: w in VGPRs + delegated-detect barrier ----------------
// Barrier topology: arrival[w] (1W/1R, WG0 reads) -> WG0 wave0 detects ->
// WG0 wave0 stores 128 per-WG release lines (1W/1R each) -> WG w spins on own line.
// No cache line anywhere has more than one reader or one writer spinning on it.
__global__ __launch_bounds__(NTHR, 1) void k_recur(const unsigned short* __restrict__ WhTb,
                                                   const float* __restrict__ GX0,
                                                   const float* __restrict__ bh0,
                                                   float* __restrict__ H0,
                                                   unsigned* __restrict__ bar,
                                                   float* __restrict__ hbuf) {   // [2][16384] f32
  __shared__ unsigned w_u32[24 * WSTR];
  __shared__ float h_lds[16 * 1024];
  __shared__ float red[8 * 416];
  const int wgid = blockIdx.x;
  const int tid = threadIdx.x;
  const int c = tid & 7, q = tid >> 3;
  const int lane = tid & 63, wv = tid >> 6;

  for (int i = tid; i < 24 * 512; i += NTHR) {
    const int rr = i >> 9, pidx = i & 511;
    const int g = rr >> 3, cc = rr & 7;
    const int grow = g * H_ + (wgid << 3) + cc;
    w_u32[rr * WSTR + pidx] = ((const unsigned*)WhTb)[(size_t)grow * 512 + pidx];
  }

  float bhr = 0.f, bhz = 0.f, bhn = 0.f;
  if (tid < 128) {
    const int col = (wgid << 3) + (tid & 7);
    bhr = bh0[col]; bhz = bh0[H_ + col]; bhn = bh0[2 * H_ + col];
  }

  const unsigned* __restrict__ w0 = w_u32 + (0 + c) * WSTR + (q << 3);
  const unsigned* __restrict__ w1 = w_u32 + (8 + c) * WSTR + (q << 3);
  const unsigned* __restrict__ w2 = w_u32 + (16 + c) * WSTR + (q << 3);
  const int koffbase = q << 4;

  // ---- preload this thread's 24 time-invariant w words into registers,
  //      stored in rotated order so all inner-loop register indices are static ----
  __syncthreads();
  float wv_[8][6];
  #pragma unroll
  for (int i = 0; i < 8; ++i) {
    const int ir = (i + q) & 7;
    const unsigned pr_ = w0[ir], pz_ = w1[ir], pn_ = w2[ir];
    wv_[i][0] = __uint_as_float(pr_ << 16); wv_[i][1] = __uint_as_float(pr_ & 0xffff0000u);
    wv_[i][2] = __uint_as_float(pz_ << 16); wv_[i][3] = __uint_as_float(pz_ & 0xffff0000u);
    wv_[i][4] = __uint_as_float(pn_ << 16); wv_[i][5] = __uint_as_float(pn_ & 0xffff0000u);
  }

  for (int t = 0; t < T_; ++t) {
    // ---- stage h_{t-1}: 8x dwordx4 coherent loads per thread ----
    if (t == 0) {
      #pragma unroll
      for (int r2 = 0; r2 < 32; ++r2) h_lds[(r2 << 9) + tid] = 0.f;
    } else {
      const char* hsrc = (const char*)(hbuf + ((t - 1) & 1) * 16384) + (tid << 4);
      f32x4 hv[8];
      #pragma unroll
      for (int r = 0; r < 8; ++r)
        asm volatile("global_load_dwordx4 %0, %1, off sc0 sc1"
                     : "=v"(hv[r]) : "v"(hsrc + (r << 13)));
      asm volatile("s_waitcnt vmcnt(0)" ::: "memory");
      #pragma unroll
      for (int r = 0; r < 8; ++r)
        *(f32x4*)&h_lds[(r << 11) + (tid << 2)] = hv[r];
    }
    __syncthreads();

    float xr = 0.f, xz = 0.f, xn = 0.f;
    if (tid < 128) {
      const int b0 = tid >> 3, c7 = tid & 7;
      const size_t row3 = (size_t)(b0 * T_ + t) * H3;
      const int col = (wgid << 3) + c7;
      xr = GX0[row3 + col]; xz = GX0[row3 + H_ + col]; xn = GX0[row3 + 2 * H_ + col];
    }

    float acc[16][3] = {};
    #pragma unroll
    for (int i = 0; i < 8; ++i) {
      const int ir = (i + q) & 7;
      const float* hp = h_lds + koffbase + (ir << 1);
      #pragma unroll
      for (int b = 0; b < 16; ++b) {
        const float2 h2 = *(const float2*)(hp + (b << 10));
        acc[b][0] = fmaf(h2.y, wv_[i][1], fmaf(h2.x, wv_[i][0], acc[b][0]));
        acc[b][1] = fmaf(h2.y, wv_[i][3], fmaf(h2.x, wv_[i][2], acc[b][1]));
        acc[b][2] = fmaf(h2.y, wv_[i][5], fmaf(h2.x, wv_[i][4], acc[b][2]));
      }
    }

    #pragma unroll
    for (int b = 0; b < 16; ++b)
      #pragma unroll
      for (int g = 0; g < 3; ++g) {
        float v = acc[b][g];
        v += __shfl_xor(v, 8);
        v += __shfl_xor(v, 16);
        v += __shfl_xor(v, 32);
        acc[b][g] = v;
      }
    if (lane < 8) {
      const int base = wv * 416 + lane * 52;
      #pragma unroll
      for (int b = 0; b < 16; ++b)
        #pragma unroll
        for (int g = 0; g < 3; ++g) red[base + b * 3 + g] = acc[b][g];
    }
    __syncthreads();

    if (tid < 128) {
      const int b0 = tid >> 3, c7 = tid & 7;
      float pr = 0.f, pz = 0.f, pn = 0.f;
      #pragma unroll
      for (int w8 = 0; w8 < 8; ++w8) {
        const int base = w8 * 416 + c7 * 52 + b0 * 3;
        pr += red[base]; pz += red[base + 1]; pn += red[base + 2];
      }
      const float r = 1.f / (1.f + expf(-(xr + pr + bhr)));
      const float z = 1.f / (1.f + expf(-(xz + pz + bhz)));
      const float n = tanhf(xn + r * (pn + bhn));
      const int col = (wgid << 3) + c7;
      const float hp = h_lds[(b0 << 10) + col];
      const float hnew = (1.f - z) * n + z * hp;
      H0[((size_t)(b0 * T_ + t) << 10) + col] = hnew;
      if (t + 1 < T_) AGENT_ST(&hbuf[(t & 1) * 16384 + (b0 << 10) + col], hnew);
    }

    if (t < T_ - 1) {
      __syncthreads();                      // vmcnt(0): h stores globally visible
      const unsigned p = (unsigned)(t + 1);
      if (wgid == 0) {
        if (tid == 0) AGENT_ST(&bar[0], p);
        if (tid < 64) {
          for (;;) {
            const unsigned a0 = AGENT_LD(&bar[tid * 32]);
            const unsigned a1 = AGENT_LD(&bar[(tid + 64) * 32]);
            if (__all(a0 >= p && a1 >= p)) break;
            __builtin_amdgcn_s_sleep(1);
          }
          AGENT_ST(&bar[8192 + tid * 32], p);          // fan-out: 128 private
          AGENT_ST(&bar[8192 + (tid + 64) * 32], p);   // release lines
        }
      } else if (tid == 0) {
        AGENT_ST(&bar[wgid * 32], p);                  // own arrival line
        while (AGENT_LD(&bar[8192 + wgid * 32]) < p)   // spin on own release line
          __builtin_amdgcn_s_sleep(1);
      }
      __syncthreads();
    }
  }
}

// ---------------- layer-1 elementwise ----------------
__global__ __launch_bounds__(256) void k_gru1(const float* __restrict__ GX1,
                                              const float* __restrict__ GH1,
                                              const float* __restrict__ H0,
                                              float* __restrict__ H1, int row0) {
  const int lrow = blockIdx.x;
  const size_t row = (size_t)row0 + lrow;
  const float* gx = GX1 + (size_t)lrow * H3;
  const float* gh = GH1 + (size_t)lrow * H3;
  for (int j = threadIdx.x; j < H_; j += 256) {
    const float xr = gx[j], xz = gx[1024 + j], xn = gx[2048 + j];
    const float hr = gh[j], hz = gh[1024 + j], hn = gh[2048 + j];
    const float h = H0[(row << 10) + j];
    const float r = 1.f / (1.f + expf(-(xr + hr)));
    const float z = 1.f / (1.f + expf(-(xz + hz)));
    const float n = tanhf(xn + r * hn);
    H1[(row << 10) + j] = (1.f - z) * n + z * h;
  }
}

// ---------------- final hidden: out[2][B][H] ----------------
__global__ __launch_bounds__(256) void k_hidden(const float* __restrict__ H0,
                                                const float* __restrict__ H1,
                                                float* __restrict__ out) {
  const int i = blockIdx.x * 256 + threadIdx.x;
  const int l = i >> 14;
  const int b = (i >> 10) & 15;
  const int j = i & 1023;
  const float* src = l ? H1 : H0;
  out[i] = src[((size_t)(b * T_ + T_ - 1) << 10) + j];
}

extern "C" void kernel_launch(void* const* d_in, const int* in_sizes, int n_in,
                              void* d_out, int out_size, void* d_ws, size_t ws_size,
                              hipStream_t stream) {
  const int*   x   = (const int*)d_in[0];
  const float* emb = (const float*)d_in[1];
  const float* Wx0 = (const float*)d_in[2];
  const float* Wh0 = (const float*)d_in[3];
  const float* bx0 = (const float*)d_in[4];
  const float* bh0 = (const float*)d_in[5];
  const float* Wx1 = (const float*)d_in[6];
  const float* Wh1 = (const float*)d_in[7];
  const float* bx1 = (const float*)d_in[8];
  const float* bh1 = (const float*)d_in[9];
  const float* fcW = (const float*)d_in[10];
  const float* fcb = (const float*)d_in[11];
  float* out = (float*)d_out;

  char* ws = (char*)d_ws;
  const size_t MB = 1024 * 1024;
  // persistent
  float* H0 = (float*)(ws + 0);                 // 16 MB
  float* H1 = (float*)(ws + 16 * MB);           // 16 MB
  char*  S  = ws + 32 * MB;
  // phase A/B
  unsigned short* WhTb  = (unsigned short*)(S);           // 6 MB
  float*          GX0   = (float*)(S + 8 * MB);           // 48 MB
  unsigned short* EmbHi = (unsigned short*)(S + 56 * MB); // 4 MB
  unsigned short* EmbLo = (unsigned short*)(S + 60 * MB); // 4 MB
  unsigned short* Wx0Thi= (unsigned short*)(S + 64 * MB); // 3 MB
  unsigned short* Wx0Tlo= (unsigned short*)(S + 67 * MB); // 3 MB
  unsigned*       bar   = (unsigned*)(S + 72 * MB);       // 64 KB
  float*          hbuf  = (float*)(S + 72 * MB + 65536);  // 128 KB
  // phase C (layer 1)
  unsigned short* AHi   = (unsigned short*)(S);           // 8 MB
  unsigned short* ALo   = (unsigned short*)(S + 8 * MB);  // 8 MB
  unsigned short* WxThi = (unsigned short*)(S + 16 * MB); // 6 MB
  unsigned short* WxTlo = (unsigned short*)(S + 22 * MB); // 6 MB
  unsigned short* WhThi = (unsigned short*)(S + 28 * MB); // 6 MB
  unsigned short* WhTlo = (unsigned short*)(S + 34 * MB); // 6 MB
  float* GX1 = (float*)(S + 40 * MB);                     // 24 MB
  float* GH1 = (float*)(S + 64 * MB);                     // 24 MB
  // phase D (FC)
  unsigned short* fcThi = (unsigned short*)(S + 16 * MB); // 31.25 MB
  unsigned short* fcTlo = (unsigned short*)(S + 48 * MB); // 31.25 MB

  // ---- phase A: embeddings (split), recur-W, GX0 via MFMA ----
  k_embed_split<<<dim3(B_ * T_), dim3(128), 0, stream>>>(x, emb, EmbHi, EmbLo);
  k_transpose_b16<<<dim3(H3 / 32, H_ / 32), dim3(256), 0, stream>>>(Wh0, WhTb);
  k_transpose_split<<<dim3(H3 / 32, E_ / 32), dim3(256), 0, stream>>>(Wx0, H3, Wx0Thi, Wx0Tlo, E_);
  k_gemm_mfma<<<dim3(32 * 24), dim3(256), 0, stream>>>(
      EmbHi, EmbLo, Wx0Thi, Wx0Tlo, bx0, GX0, 32, 24, E_, H3);

  // ---- phase B: recurrence ----
  hipMemsetAsync(bar, 0, 65536, stream);
  {
    void* args[] = {(void*)&WhTb, (void*)&GX0, (void*)&bh0, (void*)&H0,
                    (void*)&bar, (void*)&hbuf};
    hipLaunchCooperativeKernel((const void*)k_recur, dim3(NWG), dim3(NTHR), args, 0, stream);
  }

  // ---- phase C: layer 1 via split-bf16 MFMA ----
  k_split<<<dim3(4096), dim3(256), 0, stream>>>(H0, AHi, ALo, (B_ * T_ * H_) / 4);
  k_transpose_split<<<dim3(H3 / 32, H_ / 32), dim3(256), 0, stream>>>(Wx1, H3, WxThi, WxTlo, H_);
  k_transpose_split<<<dim3(H3 / 32, H_ / 32), dim3(256), 0, stream>>>(Wh1, H3, WhThi, WhTlo, H_);
  for (int chunk = 0; chunk < 2; ++chunk) {
    const unsigned short* Ah = AHi + (size_t)chunk * 2048 * H_;
    const unsigned short* Al = ALo + (size_t)chunk * 2048 * H_;
    k_gemm_mfma<<<dim3(16 * 24), dim3(256), 0, stream>>>(
        Ah, Al, WxThi, WxTlo, bx1, GX1, 16, 24, H_, H3);
    k_gemm_mfma<<<dim3(16 * 24), dim3(256), 0, stream>>>(
        Ah, Al, WhThi, WhTlo, bh1, GH1, 16, 24, H_, H3);
    k_gru1<<<dim3(2048), dim3(256), 0, stream>>>(GX1, GH1, H0, H1, chunk * 2048);
  }

  // ---- phase D: FC via split-bf16 MFMA, 2 N-chunks of 16000 ----
  k_split<<<dim3(4096), dim3(256), 0, stream>>>(H1, AHi, ALo, (B_ * T_ * H_) / 4);
  for (int chunk = 0; chunk < 2; ++chunk) {
    const float* Wc = fcW + (size_t)chunk * 16000;
    k_transpose_split<<<dim3(16000 / 32, H_ / 32), dim3(256), 0, stream>>>(
        Wc, V_, fcThi, fcTlo, H_);
    k_gemm_mfma<<<dim3(32 * 125), dim3(256), 0, stream>>>(
        AHi, ALo, fcThi, fcTlo, fcb + (size_t)chunk * 16000,
        out + (size_t)chunk * 16000, 32, 125, H_, V_);
  }

  // ---- final hidden ----
  k_hidden<<<dim3(32768 / 256), dim3(256), 0, stream>>>(H0, H1, out + (size_t)B_ * T_ * V_);
}

// Round 9
// 3323.926 us; speedup vs baseline: 7.5850x; 1.0375x over previous
//
#include <hip/hip_runtime.h>
#include <hip/hip_bf16.h>

#define V_  32000
#define E_  512
#define H_  1024
#define B_  16
#define T_  256
#define H3  3072

#define NWG   128
#define NTHR  512
#define WSTR  513                 // recur w_lds row stride in u32 pairs

#define AGENT_LD(p)    __hip_atomic_load((p),  __ATOMIC_RELAXED, __HIP_MEMORY_SCOPE_AGENT)
#define AGENT_ST(p, v) __hip_atomic_store((p), (v), __ATOMIC_RELAXED, __HIP_MEMORY_SCOPE_AGENT)

typedef __attribute__((ext_vector_type(8))) short bf16x8;
typedef __attribute__((ext_vector_type(4))) float f32x4;

#define GLDS16(gp, lp) __builtin_amdgcn_global_load_lds( \
    (const __attribute__((address_space(1))) unsigned int*)(gp), \
    (__attribute__((address_space(3))) unsigned int*)(lp), 16, 0, 0)

__device__ __forceinline__ void split_f32(float v, unsigned short& hi, unsigned short& lo) {
  const __hip_bfloat16 hb = __float2bfloat16(v);
  hi = *(const unsigned short*)&hb;
  const __hip_bfloat16 lb = __float2bfloat16(v - __bfloat162float(hb));
  lo = *(const unsigned short*)&lb;
}
__device__ __forceinline__ float join_bf(unsigned short hi, unsigned short lo) {
  return __uint_as_float((unsigned)hi << 16) + __uint_as_float((unsigned)lo << 16);
}

// ---------------- embedding gather + hi/lo split ----------------
__global__ __launch_bounds__(128) void k_embed_split(const int* __restrict__ x,
                                                     const float* __restrict__ emb,
                                                     unsigned short* __restrict__ hi,
                                                     unsigned short* __restrict__ lo) {
  const int row = blockIdx.x;
  const int idx = x[row];
  const float4 v = ((const float4*)(emb + (size_t)idx * E_))[threadIdx.x];
  const float f[4] = {v.x, v.y, v.z, v.w};
  unsigned short hh[4], ll[4];
  #pragma unroll
  for (int k = 0; k < 4; ++k) split_f32(f[k], hh[k], ll[k]);
  ushort4 h4; h4.x = hh[0]; h4.y = hh[1]; h4.z = hh[2]; h4.w = hh[3];
  ushort4 l4; l4.x = ll[0]; l4.y = ll[1]; l4.z = ll[2]; l4.w = ll[3];
  ((ushort4*)(hi + (size_t)row * E_))[threadIdx.x] = h4;
  ((ushort4*)(lo + (size_t)row * E_))[threadIdx.x] = l4;
}

// ---------------- transpose Wh0 [1024][3072] -> WhTb [3072][1024] bf16 ----------------
__global__ __launch_bounds__(256) void k_transpose_b16(const float* __restrict__ W,
                                                       unsigned short* __restrict__ WTb) {
  __shared__ float tile[32][33];
  const int c0 = blockIdx.x * 32, r0 = blockIdx.y * 32;
  const int tx = threadIdx.x & 31, ty = threadIdx.x >> 5;
  #pragma unroll
  for (int i = ty; i < 32; i += 8)
    tile[i][tx] = W[(size_t)(r0 + i) * H3 + c0 + tx];
  __syncthreads();
  #pragma unroll
  for (int i = ty; i < 32; i += 8) {
    const __hip_bfloat16 v = __float2bfloat16(tile[tx][i]);
    WTb[(size_t)(c0 + i) * H_ + r0 + tx] = *(const unsigned short*)&v;
  }
}

// ---------------- transpose + hi/lo split: W [R][ldw] f32 -> WT hi/lo [C][R] bf16 ----------------
__global__ __launch_bounds__(256) void k_transpose_split(const float* __restrict__ W, int ldw,
                                                         unsigned short* __restrict__ WThi,
                                                         unsigned short* __restrict__ WTlo,
                                                         int R) {
  __shared__ float tile[32][33];
  const int c0 = blockIdx.x * 32, r0 = blockIdx.y * 32;
  const int tx = threadIdx.x & 31, ty = threadIdx.x >> 5;
  #pragma unroll
  for (int i = ty; i < 32; i += 8)
    tile[i][tx] = W[(size_t)(r0 + i) * ldw + c0 + tx];
  __syncthreads();
  #pragma unroll
  for (int i = ty; i < 32; i += 8) {
    unsigned short h, l;
    split_f32(tile[tx][i], h, l);
    WThi[(size_t)(c0 + i) * R + r0 + tx] = h;
    WTlo[(size_t)(c0 + i) * R + r0 + tx] = l;
  }
}

// ---------------- split-bf16 MFMA GEMM (unchanged) ----------------
__global__ __launch_bounds__(256, 2) void k_gemm_mfma(
    const unsigned short* __restrict__ Ahi, const unsigned short* __restrict__ Alo,
    const unsigned short* __restrict__ BThi, const unsigned short* __restrict__ BTlo,
    const float* __restrict__ bias, float* __restrict__ C,
    int MT, int NT, int K, int ldc) {
  __shared__ unsigned short sAhi[128 * 64], sAlo[128 * 64];
  __shared__ unsigned short sBhi[128 * 64], sBlo[128 * 64];

  const int bid = blockIdx.x;
  const int GROUPM = 8;
  const int group = bid / (GROUPM * NT);
  const int first = group * GROUPM;
  const int gsm = (MT - first < GROUPM) ? (MT - first) : GROUPM;
  const int rem = bid % (GROUPM * NT);
  const int pm = first + rem % gsm;
  const int pn = rem / gsm;
  const int bm = pm * 128, bn = pn * 128;

  const int tid = threadIdx.x;
  const int wv = tid >> 6, l = tid & 63;
  const int wr = wv >> 1, wc = wv & 1;
  const int frow = l & 15;
  const int ksl  = l >> 4;

  f32x4 acc[4][4];
  #pragma unroll
  for (int a = 0; a < 4; ++a)
    #pragma unroll
    for (int b = 0; b < 4; ++b) acc[a][b] = (f32x4){0.f, 0.f, 0.f, 0.f};

  for (int k0 = 0; k0 < K; k0 += 64) {
    __syncthreads();
    #pragma unroll
    for (int p = 0; p < 4; ++p) {
      const int obase = ((p << 2) + wv) << 10;
      const int row = ((obase >> 7)) + (l >> 3);
      const int slot = l & 7;
      const int gcol = k0 + ((slot ^ (row & 7)) << 3);
      const size_t ga = (size_t)(bm + row) * K + gcol;
      const size_t gb = (size_t)(bn + row) * K + gcol;
      GLDS16(Ahi + ga, (char*)sAhi + obase);
      GLDS16(Alo + ga, (char*)sAlo + obase);
      GLDS16(BThi + gb, (char*)sBhi + obase);
      GLDS16(BTlo + gb, (char*)sBlo + obase);
    }
    __syncthreads();
    #pragma unroll
    for (int kk = 0; kk < 2; ++kk) {
      bf16x8 ah[4], al[4], bh[4], bl[4];
      #pragma unroll
      for (int f = 0; f < 4; ++f) {
        const int ar = wr * 64 + f * 16 + frow;
        const int aoff = ar * 128 + ((((kk << 2) + ksl) ^ (ar & 7)) << 4);
        ah[f] = *(const bf16x8*)((const char*)sAhi + aoff);
        al[f] = *(const bf16x8*)((const char*)sAlo + aoff);
        const int br_ = wc * 64 + f * 16 + frow;
        const int boff = br_ * 128 + ((((kk << 2) + ksl) ^ (br_ & 7)) << 4);
        bh[f] = *(const bf16x8*)((const char*)sBhi + boff);
        bl[f] = *(const bf16x8*)((const char*)sBlo + boff);
      }
      #pragma unroll
      for (int fm = 0; fm < 4; ++fm)
        #pragma unroll
        for (int fn = 0; fn < 4; ++fn) {
          acc[fm][fn] = __builtin_amdgcn_mfma_f32_16x16x32_bf16(ah[fm], bh[fn], acc[fm][fn], 0, 0, 0);
          acc[fm][fn] = __builtin_amdgcn_mfma_f32_16x16x32_bf16(ah[fm], bl[fn], acc[fm][fn], 0, 0, 0);
          acc[fm][fn] = __builtin_amdgcn_mfma_f32_16x16x32_bf16(al[fm], bh[fn], acc[fm][fn], 0, 0, 0);
        }
    }
  }

  const int crow0 = bm + wr * 64 + (l >> 4) * 4;
  const int ccol0 = bn + wc * 64 + (l & 15);
  #pragma unroll
  for (int fn = 0; fn < 4; ++fn) {
    const int col = ccol0 + fn * 16;
    const float bv = bias[col];
    #pragma unroll
    for (int fm = 0; fm < 4; ++fm) {
      const int r0 = crow0 + fm * 16;
      #pragma unroll
      for (int i = 0; i < 4; ++i)
        C[(size_t)(r0 + i) * ldc + col] = acc[fm][fn][i] + bv;
    }
  }
}

// ---------------- layer-0 recurrence: GX0 prefetch in barrier window, hi/lo out ----------------
__global__ __launch_bounds__(NTHR, 1) void k_recur(const unsigned short* __restrict__ WhTb,
                                                   const float* __restrict__ GX0,
                                                   const float* __restrict__ bh0,
                                                   unsigned short* __restrict__ H0hi,
                                                   unsigned short* __restrict__ H0lo,
                                                   unsigned* __restrict__ bar,
                                                   float* __restrict__ hbuf) {   // [2][16384] f32
  __shared__ unsigned w_u32[24 * WSTR];
  __shared__ float h_lds[16 * 1024];
  __shared__ float red[8 * 416];
  const int wgid = blockIdx.x;
  const int tid = threadIdx.x;
  const int c = tid & 7, q = tid >> 3;
  const int lane = tid & 63, wv = tid >> 6;

  for (int i = tid; i < 24 * 512; i += NTHR) {
    const int rr = i >> 9, pidx = i & 511;
    const int g = rr >> 3, cc = rr & 7;
    const int grow = g * H_ + (wgid << 3) + cc;
    w_u32[rr * WSTR + pidx] = ((const unsigned*)WhTb)[(size_t)grow * 512 + pidx];
  }

  const int b0 = tid >> 3, c7 = tid & 7;            // valid for tid<128
  const int mycol = (wgid << 3) + c7;
  float bhr = 0.f, bhz = 0.f, bhn = 0.f;
  float xr = 0.f, xz = 0.f, xn = 0.f;
  if (tid < 128) {
    bhr = bh0[mycol]; bhz = bh0[H_ + mycol]; bhn = bh0[2 * H_ + mycol];
    const size_t row3 = (size_t)(b0 * T_) * H3;     // prefetch t=0
    xr = GX0[row3 + mycol]; xz = GX0[row3 + H_ + mycol]; xn = GX0[row3 + 2 * H_ + mycol];
  }

  const unsigned* __restrict__ w0 = w_u32 + (0 + c) * WSTR + (q << 3);
  const unsigned* __restrict__ w1 = w_u32 + (8 + c) * WSTR + (q << 3);
  const unsigned* __restrict__ w2 = w_u32 + (16 + c) * WSTR + (q << 3);
  const int koffbase = q << 4;

  // preload this thread's 24 time-invariant w words into regs (rotated order)
  __syncthreads();
  float wv_[8][6];
  #pragma unroll
  for (int i = 0; i < 8; ++i) {
    const int ir = (i + q) & 7;
    const unsigned pr_ = w0[ir], pz_ = w1[ir], pn_ = w2[ir];
    wv_[i][0] = __uint_as_float(pr_ << 16); wv_[i][1] = __uint_as_float(pr_ & 0xffff0000u);
    wv_[i][2] = __uint_as_float(pz_ << 16); wv_[i][3] = __uint_as_float(pz_ & 0xffff0000u);
    wv_[i][4] = __uint_as_float(pn_ << 16); wv_[i][5] = __uint_as_float(pn_ & 0xffff0000u);
  }

  for (int t = 0; t < T_; ++t) {
    // ---- stage h_{t-1}: 8x dwordx4 coherent loads per thread ----
    if (t == 0) {
      #pragma unroll
      for (int r2 = 0; r2 < 32; ++r2) h_lds[(r2 << 9) + tid] = 0.f;
    } else {
      const char* hsrc = (const char*)(hbuf + ((t - 1) & 1) * 16384) + (tid << 4);
      f32x4 hv[8];
      #pragma unroll
      for (int r = 0; r < 8; ++r)
        asm volatile("global_load_dwordx4 %0, %1, off sc0 sc1"
                     : "=v"(hv[r]) : "v"(hsrc + (r << 13)));
      asm volatile("s_waitcnt vmcnt(0)" ::: "memory");
      #pragma unroll
      for (int r = 0; r < 8; ++r)
        *(f32x4*)&h_lds[(r << 11) + (tid << 2)] = hv[r];
    }
    __syncthreads();

    float acc[16][3] = {};
    #pragma unroll
    for (int i = 0; i < 8; ++i) {
      const int ir = (i + q) & 7;
      const float* hp = h_lds + koffbase + (ir << 1);
      #pragma unroll
      for (int b = 0; b < 16; ++b) {
        const float2 h2 = *(const float2*)(hp + (b << 10));
        acc[b][0] = fmaf(h2.y, wv_[i][1], fmaf(h2.x, wv_[i][0], acc[b][0]));
        acc[b][1] = fmaf(h2.y, wv_[i][3], fmaf(h2.x, wv_[i][2], acc[b][1]));
        acc[b][2] = fmaf(h2.y, wv_[i][5], fmaf(h2.x, wv_[i][4], acc[b][2]));
      }
    }

    #pragma unroll
    for (int b = 0; b < 16; ++b)
      #pragma unroll
      for (int g = 0; g < 3; ++g) {
        float v = acc[b][g];
        v += __shfl_xor(v, 8);
        v += __shfl_xor(v, 16);
        v += __shfl_xor(v, 32);
        acc[b][g] = v;
      }
    if (lane < 8) {
      const int base = wv * 416 + lane * 52;
      #pragma unroll
      for (int b = 0; b < 16; ++b)
        #pragma unroll
        for (int g = 0; g < 3; ++g) red[base + b * 3 + g] = acc[b][g];
    }
    __syncthreads();

    if (tid < 128) {
      float pr = 0.f, pz = 0.f, pn = 0.f;
      #pragma unroll
      for (int w8 = 0; w8 < 8; ++w8) {
        const int base = w8 * 416 + c7 * 52 + b0 * 3;
        pr += red[base]; pz += red[base + 1]; pn += red[base + 2];
      }
      const float r = 1.f / (1.f + expf(-(xr + pr + bhr)));
      const float z = 1.f / (1.f + expf(-(xz + pz + bhz)));
      const float n = tanhf(xn + r * (pn + bhn));
      const float hp = h_lds[(b0 << 10) + mycol];
      const float hnew = (1.f - z) * n + z * hp;
      const size_t oidx = ((size_t)(b0 * T_ + t) << 10) + mycol;
      unsigned short hh, hl;
      split_f32(hnew, hh, hl);
      H0hi[oidx] = hh;
      H0lo[oidx] = hl;
      if (t + 1 < T_) AGENT_ST(&hbuf[(t & 1) * 16384 + (b0 << 10) + mycol], hnew);
    }

    if (t < T_ - 1) {
      __syncthreads();                      // vmcnt(0) drain: hbuf stores visible
      const unsigned p = (unsigned)(t + 1);
      if (tid == 0) AGENT_ST(&bar[wgid * 32], p);
      // prefetch next step's GX0 inside the barrier window (hides LLC latency)
      if (tid < 128) {
        const size_t row3 = (size_t)(b0 * T_ + t + 1) * H3;
        xr = GX0[row3 + mycol];
        xz = GX0[row3 + H_ + mycol];
        xn = GX0[row3 + 2 * H_ + mycol];
      }
      if (wgid == 0) {
        if (tid < 64) {
          for (;;) {
            const unsigned a0 = AGENT_LD(&bar[tid * 32]);
            const unsigned a1 = AGENT_LD(&bar[(tid + 64) * 32]);
            if (__all(a0 >= p && a1 >= p)) break;
          }
          AGENT_ST(&bar[8192 + tid * 32], p);          // fan-out to 128 private
          AGENT_ST(&bar[8192 + (tid + 64) * 32], p);   // release lines
        }
      } else if (tid == 0) {
        while (AGENT_LD(&bar[8192 + wgid * 32]) < p) {}
      }
      __syncthreads();
    }
  }
}

// ---------------- layer-1 elementwise: hi/lo in, hi/lo out ----------------
__global__ __launch_bounds__(256) void k_gru1(const float* __restrict__ GX1,
                                              const float* __restrict__ GH1,
                                              const unsigned short* __restrict__ H0hi,
                                              const unsigned short* __restrict__ H0lo,
                                              unsigned short* __restrict__ H1hi,
                                              unsigned short* __restrict__ H1lo, int row0) {
  const int lrow = blockIdx.x;
  const size_t row = (size_t)row0 + lrow;
  const float* gx = GX1 + (size_t)lrow * H3;
  const float* gh = GH1 + (size_t)lrow * H3;
  for (int j = threadIdx.x; j < H_; j += 256) {
    const float xr = gx[j], xz = gx[1024 + j], xn = gx[2048 + j];
    const float hr = gh[j], hz = gh[1024 + j], hn = gh[2048 + j];
    const size_t idx = (row << 10) + j;
    const float h = join_bf(H0hi[idx], H0lo[idx]);
    const float r = 1.f / (1.f + expf(-(xr + hr)));
    const float z = 1.f / (1.f + expf(-(xz + hz)));
    const float n = tanhf(xn + r * hn);
    const float hnew = (1.f - z) * n + z * h;
    unsigned short hh, hl;
    split_f32(hnew, hh, hl);
    H1hi[idx] = hh;
    H1lo[idx] = hl;
  }
}

// ---------------- final hidden: out[2][B][H] from hi/lo ----------------
__global__ __launch_bounds__(256) void k_hidden(const unsigned short* __restrict__ H0hi,
                                                const unsigned short* __restrict__ H0lo,
                                                const unsigned short* __restrict__ H1hi,
                                                const unsigned short* __restrict__ H1lo,
                                                float* __restrict__ out) {
  const int i = blockIdx.x * 256 + threadIdx.x;
  const int l = i >> 14;
  const int b = (i >> 10) & 15;
  const int j = i & 1023;
  const size_t idx = ((size_t)(b * T_ + T_ - 1) << 10) + j;
  out[i] = l ? join_bf(H1hi[idx], H1lo[idx]) : join_bf(H0hi[idx], H0lo[idx]);
}

extern "C" void kernel_launch(void* const* d_in, const int* in_sizes, int n_in,
                              void* d_out, int out_size, void* d_ws, size_t ws_size,
                              hipStream_t stream) {
  const int*   x   = (const int*)d_in[0];
  const float* emb = (const float*)d_in[1];
  const float* Wx0 = (const float*)d_in[2];
  const float* Wh0 = (const float*)d_in[3];
  const float* bx0 = (const float*)d_in[4];
  const float* bh0 = (const float*)d_in[5];
  const float* Wx1 = (const float*)d_in[6];
  const float* Wh1 = (const float*)d_in[7];
  const float* bx1 = (const float*)d_in[8];
  const float* bh1 = (const float*)d_in[9];
  const float* fcW = (const float*)d_in[10];
  const float* fcb = (const float*)d_in[11];
  float* out = (float*)d_out;

  char* ws = (char*)d_ws;
  const size_t MB = 1024 * 1024;
  // persistent hi/lo hidden states (bf16 pairs)
  unsigned short* H0hi = (unsigned short*)(ws + 0);        // 8 MB [4096][1024]
  unsigned short* H0lo = (unsigned short*)(ws + 8 * MB);   // 8 MB
  unsigned short* H1hi = (unsigned short*)(ws + 16 * MB);  // 8 MB
  unsigned short* H1lo = (unsigned short*)(ws + 24 * MB);  // 8 MB
  char* S = ws + 32 * MB;
  // phase A/B
  unsigned short* WhTb  = (unsigned short*)(S);            // 6 MB
  float*          GX0   = (float*)(S + 8 * MB);            // 48 MB
  unsigned short* EmbHi = (unsigned short*)(S + 56 * MB);  // 4 MB
  unsigned short* EmbLo = (unsigned short*)(S + 60 * MB);  // 4 MB
  unsigned short* Wx0Thi= (unsigned short*)(S + 64 * MB);  // 3 MB
  unsigned short* Wx0Tlo= (unsigned short*)(S + 67 * MB);  // 3 MB
  unsigned*       bar   = (unsigned*)(S + 72 * MB);        // 64 KB
  float*          hbuf  = (float*)(S + 72 * MB + 65536);   // 128 KB
  // phase C (layer 1)
  unsigned short* WxThi = (unsigned short*)(S);            // 6 MB
  unsigned short* WxTlo = (unsigned short*)(S + 6 * MB);   // 6 MB
  unsigned short* WhThi = (unsigned short*)(S + 12 * MB);  // 6 MB
  unsigned short* WhTlo = (unsigned short*)(S + 18 * MB);  // 6 MB
  float* GX1 = (float*)(S + 24 * MB);                      // 24 MB (2048 rows)
  float* GH1 = (float*)(S + 48 * MB);                      // 24 MB
  // phase D (FC)
  unsigned short* fcThi = (unsigned short*)(S);            // 31.25 MB (16000x1024)
  unsigned short* fcTlo = (unsigned short*)(S + 32 * MB);  // 31.25 MB

  // ---- phase A: embeddings (split), recur-W, GX0 via MFMA ----
  k_embed_split<<<dim3(B_ * T_), dim3(128), 0, stream>>>(x, emb, EmbHi, EmbLo);
  k_transpose_b16<<<dim3(H3 / 32, H_ / 32), dim3(256), 0, stream>>>(Wh0, WhTb);
  k_transpose_split<<<dim3(H3 / 32, E_ / 32), dim3(256), 0, stream>>>(Wx0, H3, Wx0Thi, Wx0Tlo, E_);
  k_gemm_mfma<<<dim3(32 * 24), dim3(256), 0, stream>>>(
      EmbHi, EmbLo, Wx0Thi, Wx0Tlo, bx0, GX0, 32, 24, E_, H3);

  // ---- phase B: recurrence ----
  hipMemsetAsync(bar, 0, 65536, stream);
  {
    void* args[] = {(void*)&WhTb, (void*)&GX0, (void*)&bh0, (void*)&H0hi, (void*)&H0lo,
                    (void*)&bar, (void*)&hbuf};
    hipLaunchCooperativeKernel((const void*)k_recur, dim3(NWG), dim3(NTHR), args, 0, stream);
  }

  // ---- phase C: layer 1 via split-bf16 MFMA (H0 already split) ----
  k_transpose_split<<<dim3(H3 / 32, H_ / 32), dim3(256), 0, stream>>>(Wx1, H3, WxThi, WxTlo, H_);
  k_transpose_split<<<dim3(H3 / 32, H_ / 32), dim3(256), 0, stream>>>(Wh1, H3, WhThi, WhTlo, H_);
  for (int chunk = 0; chunk < 2; ++chunk) {
    const unsigned short* Ah = H0hi + (size_t)chunk * 2048 * H_;
    const unsigned short* Al = H0lo + (size_t)chunk * 2048 * H_;
    k_gemm_mfma<<<dim3(16 * 24), dim3(256), 0, stream>>>(
        Ah, Al, WxThi, WxTlo, bx1, GX1, 16, 24, H_, H3);
    k_gemm_mfma<<<dim3(16 * 24), dim3(256), 0, stream>>>(
        Ah, Al, WhThi, WhTlo, bh1, GH1, 16, 24, H_, H3);
    k_gru1<<<dim3(2048), dim3(256), 0, stream>>>(GX1, GH1, H0hi, H0lo, H1hi, H1lo, chunk * 2048);
  }

  // ---- phase D: FC via split-bf16 MFMA, 2 N-chunks of 16000 ----
  for (int chunk = 0; chunk < 2; ++chunk) {
    const float* Wc = fcW + (size_t)chunk * 16000;
    k_transpose_split<<<dim3(16000 / 32, H_ / 32), dim3(256), 0, stream>>>(
        Wc, V_, fcThi, fcTlo, H_);
    k_gemm_mfma<<<dim3(32 * 125), dim3(256), 0, stream>>>(
        H1hi, H1lo, fcThi, fcTlo, fcb + (size_t)chunk * 16000,
        out + (size_t)chunk * 16000, 32, 125, H_, V_);
  }

  // ---- final hidden ----
  k_hidden<<<dim3(32768 / 256), dim3(256), 0, stream>>>(H0hi, H0lo, H1hi, H1lo,
                                                        out + (size_t)B_ * T_ * V_);
}

// Round 12
// 3305.914 us; speedup vs baseline: 7.6264x; 1.0054x over previous
//
#include <hip/hip_runtime.h>
#include <hip/hip_bf16.h>

#define V_  32000
#define E_  512
#define H_  1024
#define B_  16
#define T_  256
#define H3  3072

#define NWG   128
#define NTHR  512
#define WSTR  513                 // recur w_lds row stride in u32 pairs

#define AGENT_LD(p)    __hip_atomic_load((p),  __ATOMIC_RELAXED, __HIP_MEMORY_SCOPE_AGENT)
#define AGENT_ST(p, v) __hip_atomic_store((p), (v), __ATOMIC_RELAXED, __HIP_MEMORY_SCOPE_AGENT)

typedef __attribute__((ext_vector_type(8))) short bf16x8;
typedef __attribute__((ext_vector_type(4))) float f32x4;

#define GLDS16(gp, lp) __builtin_amdgcn_global_load_lds( \
    (const __attribute__((address_space(1))) unsigned int*)(gp), \
    (__attribute__((address_space(3))) unsigned int*)(lp), 16, 0, 0)

__device__ __forceinline__ void split_f32(float v, unsigned short& hi, unsigned short& lo) {
  const __hip_bfloat16 hb = __float2bfloat16(v);
  hi = *(const unsigned short*)&hb;
  const __hip_bfloat16 lb = __float2bfloat16(v - __bfloat162float(hb));
  lo = *(const unsigned short*)&lb;
}
__device__ __forceinline__ float join_bf(unsigned short hi, unsigned short lo) {
  return __uint_as_float((unsigned)hi << 16) + __uint_as_float((unsigned)lo << 16);
}

// ---------------- embedding gather + hi/lo split ----------------
__global__ __launch_bounds__(128) void k_embed_split(const int* __restrict__ x,
                                                     const float* __restrict__ emb,
                                                     unsigned short* __restrict__ hi,
                                                     unsigned short* __restrict__ lo) {
  const int row = blockIdx.x;
  const int idx = x[row];
  const float4 v = ((const float4*)(emb + (size_t)idx * E_))[threadIdx.x];
  const float f[4] = {v.x, v.y, v.z, v.w};
  unsigned short hh[4], ll[4];
  #pragma unroll
  for (int k = 0; k < 4; ++k) split_f32(f[k], hh[k], ll[k]);
  ushort4 h4; h4.x = hh[0]; h4.y = hh[1]; h4.z = hh[2]; h4.w = hh[3];
  ushort4 l4; l4.x = ll[0]; l4.y = ll[1]; l4.z = ll[2]; l4.w = ll[3];
  ((ushort4*)(hi + (size_t)row * E_))[threadIdx.x] = h4;
  ((ushort4*)(lo + (size_t)row * E_))[threadIdx.x] = l4;
}

// ---------------- transpose Wh0 [1024][3072] -> WhTb [3072][1024] bf16 ----------------
__global__ __launch_bounds__(256) void k_transpose_b16(const float* __restrict__ W,
                                                       unsigned short* __restrict__ WTb) {
  __shared__ float tile[32][33];
  const int c0 = blockIdx.x * 32, r0 = blockIdx.y * 32;
  const int tx = threadIdx.x & 31, ty = threadIdx.x >> 5;
  #pragma unroll
  for (int i = ty; i < 32; i += 8)
    tile[i][tx] = W[(size_t)(r0 + i) * H3 + c0 + tx];
  __syncthreads();
  #pragma unroll
  for (int i = ty; i < 32; i += 8) {
    const __hip_bfloat16 v = __float2bfloat16(tile[tx][i]);
    WTb[(size_t)(c0 + i) * H_ + r0 + tx] = *(const unsigned short*)&v;
  }
}

// ---------------- transpose + hi/lo split ----------------
__global__ __launch_bounds__(256) void k_transpose_split(const float* __restrict__ W, int ldw,
                                                         unsigned short* __restrict__ WThi,
                                                         unsigned short* __restrict__ WTlo,
                                                         int R) {
  __shared__ float tile[32][33];
  const int c0 = blockIdx.x * 32, r0 = blockIdx.y * 32;
  const int tx = threadIdx.x & 31, ty = threadIdx.x >> 5;
  #pragma unroll
  for (int i = ty; i < 32; i += 8)
    tile[i][tx] = W[(size_t)(r0 + i) * ldw + c0 + tx];
  __syncthreads();
  #pragma unroll
  for (int i = ty; i < 32; i += 8) {
    unsigned short h, l;
    split_f32(tile[tx][i], h, l);
    WThi[(size_t)(c0 + i) * R + r0 + tx] = h;
    WTlo[(size_t)(c0 + i) * R + r0 + tx] = l;
  }
}

// ---------------- bias concat: out[0..3071]=a, out[3072..6143]=b ----------------
__global__ __launch_bounds__(512) void k_catbias(const float* __restrict__ a,
                                                 const float* __restrict__ b,
                                                 float* __restrict__ o) {
  const int i = blockIdx.x * 512 + threadIdx.x;
  o[i] = (i < H3) ? a[i] : b[i - H3];
}

// ---------------- split-bf16 MFMA GEMM (proven) ----------------
__global__ __launch_bounds__(256, 2) void k_gemm_mfma(
    const unsigned short* __restrict__ Ahi, const unsigned short* __restrict__ Alo,
    const unsigned short* __restrict__ BThi, const unsigned short* __restrict__ BTlo,
    const float* __restrict__ bias, float* __restrict__ C,
    int MT, int NT, int K, int ldc) {
  __shared__ unsigned short sAhi[128 * 64], sAlo[128 * 64];
  __shared__ unsigned short sBhi[128 * 64], sBlo[128 * 64];

  const int bid = blockIdx.x;
  const int GROUPM = 8;
  const int group = bid / (GROUPM * NT);
  const int first = group * GROUPM;
  const int gsm = (MT - first < GROUPM) ? (MT - first) : GROUPM;
  const int rem = bid % (GROUPM * NT);
  const int pm = first + rem % gsm;
  const int pn = rem / gsm;
  const int bm = pm * 128, bn = pn * 128;

  const int tid = threadIdx.x;
  const int wv = tid >> 6, l = tid & 63;
  const int wr = wv >> 1, wc = wv & 1;
  const int frow = l & 15;
  const int ksl  = l >> 4;

  f32x4 acc[4][4];
  #pragma unroll
  for (int a = 0; a < 4; ++a)
    #pragma unroll
    for (int b = 0; b < 4; ++b) acc[a][b] = (f32x4){0.f, 0.f, 0.f, 0.f};

  for (int k0 = 0; k0 < K; k0 += 64) {
    __syncthreads();
    #pragma unroll
    for (int p = 0; p < 4; ++p) {
      const int obase = ((p << 2) + wv) << 10;
      const int row = ((obase >> 7)) + (l >> 3);
      const int slot = l & 7;
      const int gcol = k0 + ((slot ^ (row & 7)) << 3);
      const size_t ga = (size_t)(bm + row) * K + gcol;
      const size_t gb = (size_t)(bn + row) * K + gcol;
      GLDS16(Ahi + ga, (char*)sAhi + obase);
      GLDS16(Alo + ga, (char*)sAlo + obase);
      GLDS16(BThi + gb, (char*)sBhi + obase);
      GLDS16(BTlo + gb, (char*)sBlo + obase);
    }
    __syncthreads();
    #pragma unroll
    for (int kk = 0; kk < 2; ++kk) {
      bf16x8 ah[4], al[4], bh[4], bl[4];
      #pragma unroll
      for (int f = 0; f < 4; ++f) {
        const int ar = wr * 64 + f * 16 + frow;
        const int aoff = ar * 128 + ((((kk << 2) + ksl) ^ (ar & 7)) << 4);
        ah[f] = *(const bf16x8*)((const char*)sAhi + aoff);
        al[f] = *(const bf16x8*)((const char*)sAlo + aoff);
        const int br_ = wc * 64 + f * 16 + frow;
        const int boff = br_ * 128 + ((((kk << 2) + ksl) ^ (br_ & 7)) << 4);
        bh[f] = *(const bf16x8*)((const char*)sBhi + boff);
        bl[f] = *(const bf16x8*)((const char*)sBlo + boff);
      }
      #pragma unroll
      for (int fm = 0; fm < 4; ++fm)
        #pragma unroll
        for (int fn = 0; fn < 4; ++fn) {
          acc[fm][fn] = __builtin_amdgcn_mfma_f32_16x16x32_bf16(ah[fm], bh[fn], acc[fm][fn], 0, 0, 0);
          acc[fm][fn] = __builtin_amdgcn_mfma_f32_16x16x32_bf16(ah[fm], bl[fn], acc[fm][fn], 0, 0, 0);
          acc[fm][fn] = __builtin_amdgcn_mfma_f32_16x16x32_bf16(al[fm], bh[fn], acc[fm][fn], 0, 0, 0);
        }
    }
  }

  const int crow0 = bm + wr * 64 + (l >> 4) * 4;
  const int ccol0 = bn + wc * 64 + (l & 15);
  #pragma unroll
  for (int fn = 0; fn < 4; ++fn) {
    const int col = ccol0 + fn * 16;
    const float bv = bias[col];
    #pragma unroll
    for (int fm = 0; fm < 4; ++fm) {
      const int r0 = crow0 + fm * 16;
      #pragma unroll
      for (int i = 0; i < 4; ++i)
        C[(size_t)(r0 + i) * ldc + col] = acc[fm][fn][i] + bv;
    }
  }
}

// ---------------- layer-0 recurrence (round-9 proven) + helper WGs for Wx1/Wh1 T ----------------
// WGs 0..127: exact round-9 recurrence (w in VGPRs, coherent dwordx4 staging,
// delegated-detect flag barrier). WGs 128..255: transpose+split Wx1/Wh1 into
// BThi/BTlo ([6144][1024], rows 0-3071 = Wx1T, 3072-6143 = Wh1T). Disjoint memory.
__global__ __launch_bounds__(NTHR, 1) void k_recur(const unsigned short* __restrict__ WhTb,
                                                   const float* __restrict__ GX0,
                                                   const float* __restrict__ bh0,
                                                   unsigned short* __restrict__ H0hi,
                                                   unsigned short* __restrict__ H0lo,
                                                   unsigned* __restrict__ bar,
                                                   float* __restrict__ hbuf,
                                                   const float* __restrict__ Wx1,
                                                   const float* __restrict__ Wh1,
                                                   unsigned short* __restrict__ BThi,
                                                   unsigned short* __restrict__ BTlo) {
  __shared__ unsigned w_u32[24 * WSTR];
  __shared__ float h_lds[16 * 1024];
  __shared__ float red[8 * 416];
  const int wgid = blockIdx.x;
  const int tid = threadIdx.x;

  if (wgid >= NWG) {
    // ---------- helper: static-striped Wx1/Wh1 transpose+split, then exit ----------
    float* tile = (float*)w_u32;                // [32][33] region reuse
    const int ty = tid >> 5, tx = tid & 31;     // ty in [0,16)
    for (int tix = wgid - NWG; tix < 6144; tix += 128) {
      const int job = tix >= 3072;
      const int tt = job ? tix - 3072 : tix;
      const int c0 = (tt % 96) * 32, r0 = (tt / 96) * 32;
      const float* W = job ? Wh1 : Wx1;
      unsigned short* Dhi = BThi + (job ? (size_t)H3 * H_ : 0);
      unsigned short* Dlo = BTlo + (job ? (size_t)H3 * H_ : 0);
      __syncthreads();
      tile[ty * 33 + tx]        = W[(size_t)(r0 + ty) * H3 + c0 + tx];
      tile[(ty + 16) * 33 + tx] = W[(size_t)(r0 + ty + 16) * H3 + c0 + tx];
      __syncthreads();
      #pragma unroll
      for (int s = 0; s < 2; ++s) {
        const int i = ty + s * 16;
        unsigned short h, l;
        split_f32(tile[tx * 33 + i], h, l);
        Dhi[(size_t)(c0 + i) * H_ + r0 + tx] = h;
        Dlo[(size_t)(c0 + i) * H_ + r0 + tx] = l;
      }
    }
    return;
  }

  const int c = tid & 7, q = tid >> 3;
  const int lane = tid & 63, wv = tid >> 6;

  for (int i = tid; i < 24 * 512; i += NTHR) {
    const int rr = i >> 9, pidx = i & 511;
    const int g = rr >> 3, cc = rr & 7;
    const int grow = g * H_ + (wgid << 3) + cc;
    w_u32[rr * WSTR + pidx] = ((const unsigned*)WhTb)[(size_t)grow * 512 + pidx];
  }

  const int b0 = tid >> 3, c7 = tid & 7;            // valid for tid<128
  const int mycol = (wgid << 3) + c7;
  float bhr = 0.f, bhz = 0.f, bhn = 0.f;
  float xr = 0.f, xz = 0.f, xn = 0.f;
  if (tid < 128) {
    bhr = bh0[mycol]; bhz = bh0[H_ + mycol]; bhn = bh0[2 * H_ + mycol];
    const size_t row3 = (size_t)(b0 * T_) * H3;     // prefetch t=0
    xr = GX0[row3 + mycol]; xz = GX0[row3 + H_ + mycol]; xn = GX0[row3 + 2 * H_ + mycol];
  }

  const unsigned* __restrict__ w0 = w_u32 + (0 + c) * WSTR + (q << 3);
  const unsigned* __restrict__ w1 = w_u32 + (8 + c) * WSTR + (q << 3);
  const unsigned* __restrict__ w2 = w_u32 + (16 + c) * WSTR + (q << 3);
  const int koffbase = q << 4;

  // preload this thread's 24 time-invariant w words into regs (rotated order)
  __syncthreads();
  float wv_[8][6];
  #pragma unroll
  for (int i = 0; i < 8; ++i) {
    const int ir = (i + q) & 7;
    const unsigned pr_ = w0[ir], pz_ = w1[ir], pn_ = w2[ir];
    wv_[i][0] = __uint_as_float(pr_ << 16); wv_[i][1] = __uint_as_float(pr_ & 0xffff0000u);
    wv_[i][2] = __uint_as_float(pz_ << 16); wv_[i][3] = __uint_as_float(pz_ & 0xffff0000u);
    wv_[i][4] = __uint_as_float(pn_ << 16); wv_[i][5] = __uint_as_float(pn_ & 0xffff0000u);
  }

  for (int t = 0; t < T_; ++t) {
    // ---- stage h_{t-1}: 8x dwordx4 coherent loads per thread ----
    if (t == 0) {
      #pragma unroll
      for (int r2 = 0; r2 < 32; ++r2) h_lds[(r2 << 9) + tid] = 0.f;
    } else {
      const char* hsrc = (const char*)(hbuf + ((t - 1) & 1) * 16384) + (tid << 4);
      f32x4 hv[8];
      #pragma unroll
      for (int r = 0; r < 8; ++r)
        asm volatile("global_load_dwordx4 %0, %1, off sc0 sc1"
                     : "=v"(hv[r]) : "v"(hsrc + (r << 13)));
      asm volatile("s_waitcnt vmcnt(0)" ::: "memory");
      #pragma unroll
      for (int r = 0; r < 8; ++r)
        *(f32x4*)&h_lds[(r << 11) + (tid << 2)] = hv[r];
    }
    __syncthreads();

    float acc[16][3] = {};
    #pragma unroll
    for (int i = 0; i < 8; ++i) {
      const int ir = (i + q) & 7;
      const float* hp = h_lds + koffbase + (ir << 1);
      #pragma unroll
      for (int b = 0; b < 16; ++b) {
        const float2 h2 = *(const float2*)(hp + (b << 10));
        acc[b][0] = fmaf(h2.y, wv_[i][1], fmaf(h2.x, wv_[i][0], acc[b][0]));
        acc[b][1] = fmaf(h2.y, wv_[i][3], fmaf(h2.x, wv_[i][2], acc[b][1]));
        acc[b][2] = fmaf(h2.y, wv_[i][5], fmaf(h2.x, wv_[i][4], acc[b][2]));
      }
    }

    #pragma unroll
    for (int b = 0; b < 16; ++b)
      #pragma unroll
      for (int g = 0; g < 3; ++g) {
        float v = acc[b][g];
        v += __shfl_xor(v, 8);
        v += __shfl_xor(v, 16);
        v += __shfl_xor(v, 32);
        acc[b][g] = v;
      }
    if (lane < 8) {
      const int base = wv * 416 + lane * 52;
      #pragma unroll
      for (int b = 0; b < 16; ++b)
        #pragma unroll
        for (int g = 0; g < 3; ++g) red[base + b * 3 + g] = acc[b][g];
    }
    __syncthreads();

    if (tid < 128) {
      float pr = 0.f, pz = 0.f, pn = 0.f;
      #pragma unroll
      for (int w8 = 0; w8 < 8; ++w8) {
        const int base = w8 * 416 + c7 * 52 + b0 * 3;
        pr += red[base]; pz += red[base + 1]; pn += red[base + 2];
      }
      const float r = 1.f / (1.f + expf(-(xr + pr + bhr)));
      const float z = 1.f / (1.f + expf(-(xz + pz + bhz)));
      const float n = tanhf(xn + r * (pn + bhn));
      const float hp = h_lds[(b0 << 10) + mycol];
      const float hnew = (1.f - z) * n + z * hp;
      const size_t oidx = ((size_t)(b0 * T_ + t) << 10) + mycol;
      unsigned short hh, hl;
      split_f32(hnew, hh, hl);
      H0hi[oidx] = hh;
      H0lo[oidx] = hl;
      if (t + 1 < T_) AGENT_ST(&hbuf[(t & 1) * 16384 + (b0 << 10) + mycol], hnew);
    }

    if (t < T_ - 1) {
      __syncthreads();                      // vmcnt(0) drain: hbuf stores visible
      const unsigned p = (unsigned)(t + 1);
      if (tid == 0) AGENT_ST(&bar[wgid * 32], p);
      // prefetch next step's GX0 inside the barrier window
      if (tid < 128) {
        const size_t row3 = (size_t)(b0 * T_ + t + 1) * H3;
        xr = GX0[row3 + mycol];
        xz = GX0[row3 + H_ + mycol];
        xn = GX0[row3 + 2 * H_ + mycol];
      }
      if (wgid == 0) {
        if (tid < 64) {
          for (;;) {
            const unsigned a0 = AGENT_LD(&bar[tid * 32]);
            const unsigned a1 = AGENT_LD(&bar[(tid + 64) * 32]);
            if (__all(a0 >= p && a1 >= p)) break;
          }
          AGENT_ST(&bar[8192 + tid * 32], p);          // fan-out to 128 private
          AGENT_ST(&bar[8192 + (tid + 64) * 32], p);   // release lines
        }
      } else if (tid == 0) {
        while (AGENT_LD(&bar[8192 + wgid * 32]) < p) {}
      }
      __syncthreads();
    }
  }
}

// ---------------- layer-1 elementwise: G1 [rows][6144], hi/lo H0 in, hi/lo H1 out ----------------
__global__ __launch_bounds__(256) void k_gru1(const float* __restrict__ G1,
                                              const unsigned short* __restrict__ H0hi,
                                              const unsigned short* __restrict__ H0lo,
                                              unsigned short* __restrict__ H1hi,
                                              unsigned short* __restrict__ H1lo, int row0) {
  const int lrow = blockIdx.x;
  const size_t row = (size_t)row0 + lrow;
  const float* g = G1 + (size_t)lrow * 6144;
  for (int j = threadIdx.x; j < H_; j += 256) {
    const float xr = g[j], xz = g[1024 + j], xn = g[2048 + j];
    const float hr = g[3072 + j], hz = g[4096 + j], hn = g[5120 + j];
    const size_t idx = (row << 10) + j;
    const float h = join_bf(H0hi[idx], H0lo[idx]);
    const float r = 1.f / (1.f + expf(-(xr + hr)));
    const float z = 1.f / (1.f + expf(-(xz + hz)));
    const float n = tanhf(xn + r * hn);
    const float hnew = (1.f - z) * n + z * h;
    unsigned short hh, hl;
    split_f32(hnew, hh, hl);
    H1hi[idx] = hh;
    H1lo[idx] = hl;
  }
}

// ---------------- final hidden: out[2][B][H] from hi/lo ----------------
__global__ __launch_bounds__(256) void k_hidden(const unsigned short* __restrict__ H0hi,
                                                const unsigned short* __restrict__ H0lo,
                                                const unsigned short* __restrict__ H1hi,
                                                const unsigned short* __restrict__ H1lo,
                                                float* __restrict__ out) {
  const int i = blockIdx.x * 256 + threadIdx.x;
  const int l = i >> 14;
  const int b = (i >> 10) & 15;
  const int j = i & 1023;
  const size_t idx = ((size_t)(b * T_ + T_ - 1) << 10) + j;
  out[i] = l ? join_bf(H1hi[idx], H1lo[idx]) : join_bf(H0hi[idx], H0lo[idx]);
}

extern "C" void kernel_launch(void* const* d_in, const int* in_sizes, int n_in,
                              void* d_out, int out_size, void* d_ws, size_t ws_size,
                              hipStream_t stream) {
  const int*   x   = (const int*)d_in[0];
  const float* emb = (const float*)d_in[1];
  const float* Wx0 = (const float*)d_in[2];
  const float* Wh0 = (const float*)d_in[3];
  const float* bx0 = (const float*)d_in[4];
  const float* bh0 = (const float*)d_in[5];
  const float* Wx1 = (const float*)d_in[6];
  const float* Wh1 = (const float*)d_in[7];
  const float* bx1 = (const float*)d_in[8];
  const float* bh1 = (const float*)d_in[9];
  const float* fcW = (const float*)d_in[10];
  const float* fcb = (const float*)d_in[11];
  float* out = (float*)d_out;

  char* ws = (char*)d_ws;
  const size_t MB = 1024 * 1024;
  // persistent hi/lo hidden states
  unsigned short* H0hi = (unsigned short*)(ws + 0);        // 8 MB [4096][1024]
  unsigned short* H0lo = (unsigned short*)(ws + 8 * MB);
  unsigned short* H1hi = (unsigned short*)(ws + 16 * MB);
  unsigned short* H1lo = (unsigned short*)(ws + 24 * MB);
  char* S = ws + 32 * MB;
  // phase A/B
  unsigned short* WhTb  = (unsigned short*)(S);            // 6 MB
  float*          GX0   = (float*)(S + 8 * MB);            // 48 MB
  unsigned short* EmbHi = (unsigned short*)(S + 56 * MB);  // 4 MB (dead after GX0 gemm)
  unsigned short* EmbLo = (unsigned short*)(S + 60 * MB);  // 4 MB
  unsigned short* Wx0Thi= (unsigned short*)(S + 64 * MB);  // 3 MB
  unsigned short* Wx0Tlo= (unsigned short*)(S + 67 * MB);  // 3 MB
  // written by helper WGs during k_recur (over the corpses above):
  unsigned short* BThi  = (unsigned short*)(S + 56 * MB);  // 12 MB [6144][1024] (Wx1T|Wh1T)
  unsigned short* BTlo  = (unsigned short*)(S + 68 * MB);  // 12 MB
  unsigned*       bar   = (unsigned*)(S + 80 * MB);        // 64 KB
  float*          hbuf  = (float*)(S + 80 * MB + 65536);   // 128 KB
  float*          b1cat = (float*)(S + 80 * MB + 65536 + 131072); // 24 KB
  // phase C (GX0 corpse)
  float* G1 = (float*)(S + 8 * MB);                        // 48 MB [2048][6144]
  // phase D
  unsigned short* fcThi = (unsigned short*)(S);            // 31.25 MB (16000x1024)
  unsigned short* fcTlo = (unsigned short*)(S + 32 * MB);  // 31.25 MB

  // ---- phase A: embeddings (split), Wh0->bf16, Wx0 split-T, GX0 via MFMA, bias cat ----
  k_embed_split<<<dim3(B_ * T_), dim3(128), 0, stream>>>(x, emb, EmbHi, EmbLo);
  k_transpose_b16<<<dim3(H3 / 32, H_ / 32), dim3(256), 0, stream>>>(Wh0, WhTb);
  k_transpose_split<<<dim3(H3 / 32, E_ / 32), dim3(256), 0, stream>>>(Wx0, H3, Wx0Thi, Wx0Tlo, E_);
  k_gemm_mfma<<<dim3(32 * 24), dim3(256), 0, stream>>>(
      EmbHi, EmbLo, Wx0Thi, Wx0Tlo, bx0, GX0, 32, 24, E_, H3);
  k_catbias<<<dim3(12), dim3(512), 0, stream>>>(bx1, bh1, b1cat);

  // ---- phase B: recurrence (WGs 0-127) + Wx1/Wh1 transposes (WGs 128-255) ----
  hipMemsetAsync(bar, 0, 65536, stream);
  {
    void* args[] = {(void*)&WhTb, (void*)&GX0, (void*)&bh0, (void*)&H0hi, (void*)&H0lo,
                    (void*)&bar, (void*)&hbuf, (void*)&Wx1, (void*)&Wh1,
                    (void*)&BThi, (void*)&BTlo};
    hipLaunchCooperativeKernel((const void*)k_recur, dim3(256), dim3(NTHR), args, 0, stream);
  }

  // ---- phase C: layer 1, one merged GEMM per chunk (N = 6144) ----
  for (int chunk = 0; chunk < 2; ++chunk) {
    const unsigned short* Ah = H0hi + (size_t)chunk * 2048 * H_;
    const unsigned short* Al = H0lo + (size_t)chunk * 2048 * H_;
    k_gemm_mfma<<<dim3(16 * 48), dim3(256), 0, stream>>>(
        Ah, Al, BThi, BTlo, b1cat, G1, 16, 48, H_, 6144);
    k_gru1<<<dim3(2048), dim3(256), 0, stream>>>(G1, H0hi, H0lo, H1hi, H1lo, chunk * 2048);
  }

  // ---- phase D: FC via split-bf16 MFMA, 2 N-chunks of 16000 ----
  for (int chunk = 0; chunk < 2; ++chunk) {
    const float* Wc = fcW + (size_t)chunk * 16000;
    k_transpose_split<<<dim3(16000 / 32, H_ / 32), dim3(256), 0, stream>>>(
        Wc, V_, fcThi, fcTlo, H_);
    k_gemm_mfma<<<dim3(32 * 125), dim3(256), 0, stream>>>(
        H1hi, H1lo, fcThi, fcTlo, fcb + (size_t)chunk * 16000,
        out + (size_t)chunk * 16000, 32, 125, H_, V_);
  }

  // ---- final hidden ----
  k_hidden<<<dim3(32768 / 256), dim3(256), 0, stream>>>(H0hi, H0lo, H1hi, H1lo,
                                                        out + (size_t)B_ * T_ * V_);
}

// Round 13
// 2159.107 us; speedup vs baseline: 11.6771x; 1.5311x over previous
//
#include <hip/hip_runtime.h>
#include <hip/hip_bf16.h>

#define V_  32000
#define E_  512
#define H_  1024
#define B_  16
#define T_  256
#define H3  3072

#define AGENT_LD(p)    __hip_atomic_load((p),  __ATOMIC_RELAXED, __HIP_MEMORY_SCOPE_AGENT)
#define AGENT_ST(p, v) __hip_atomic_store((p), (v), __ATOMIC_RELAXED, __HIP_MEMORY_SCOPE_AGENT)

typedef __attribute__((ext_vector_type(8))) short bf16x8;
typedef __attribute__((ext_vector_type(4))) float f32x4;

#define GLDS16(gp, lp) __builtin_amdgcn_global_load_lds( \
    (const __attribute__((address_space(1))) unsigned int*)(gp), \
    (__attribute__((address_space(3))) unsigned int*)(lp), 16, 0, 0)

__device__ __forceinline__ void split_f32(float v, unsigned short& hi, unsigned short& lo) {
  const __hip_bfloat16 hb = __float2bfloat16(v);
  hi = *(const unsigned short*)&hb;
  const __hip_bfloat16 lb = __float2bfloat16(v - __bfloat162float(hb));
  lo = *(const unsigned short*)&lb;
}
__device__ __forceinline__ float join_bf(unsigned short hi, unsigned short lo) {
  return __uint_as_float((unsigned)hi << 16) + __uint_as_float((unsigned)lo << 16);
}

// ---------------- embedding gather + hi/lo split ----------------
__global__ __launch_bounds__(128) void k_embed_split(const int* __restrict__ x,
                                                     const float* __restrict__ emb,
                                                     unsigned short* __restrict__ hi,
                                                     unsigned short* __restrict__ lo) {
  const int row = blockIdx.x;
  const int idx = x[row];
  const float4 v = ((const float4*)(emb + (size_t)idx * E_))[threadIdx.x];
  const float f[4] = {v.x, v.y, v.z, v.w};
  unsigned short hh[4], ll[4];
  #pragma unroll
  for (int k = 0; k < 4; ++k) split_f32(f[k], hh[k], ll[k]);
  ushort4 h4; h4.x = hh[0]; h4.y = hh[1]; h4.z = hh[2]; h4.w = hh[3];
  ushort4 l4; l4.x = ll[0]; l4.y = ll[1]; l4.z = ll[2]; l4.w = ll[3];
  ((ushort4*)(hi + (size_t)row * E_))[threadIdx.x] = h4;
  ((ushort4*)(lo + (size_t)row * E_))[threadIdx.x] = l4;
}

// ---------------- transpose Wh0 [1024][3072] -> WhTb [3072][1024] bf16 ----------------
__global__ __launch_bounds__(256) void k_transpose_b16(const float* __restrict__ W,
                                                       unsigned short* __restrict__ WTb) {
  __shared__ float tile[32][33];
  const int c0 = blockIdx.x * 32, r0 = blockIdx.y * 32;
  const int tx = threadIdx.x & 31, ty = threadIdx.x >> 5;
  #pragma unroll
  for (int i = ty; i < 32; i += 8)
    tile[i][tx] = W[(size_t)(r0 + i) * H3 + c0 + tx];
  __syncthreads();
  #pragma unroll
  for (int i = ty; i < 32; i += 8) {
    const __hip_bfloat16 v = __float2bfloat16(tile[tx][i]);
    WTb[(size_t)(c0 + i) * H_ + r0 + tx] = *(const unsigned short*)&v;
  }
}

// ---------------- transpose + hi/lo split ----------------
__global__ __launch_bounds__(256) void k_transpose_split(const float* __restrict__ W, int ldw,
                                                         unsigned short* __restrict__ WThi,
                                                         unsigned short* __restrict__ WTlo,
                                                         int R) {
  __shared__ float tile[32][33];
  const int c0 = blockIdx.x * 32, r0 = blockIdx.y * 32;
  const int tx = threadIdx.x & 31, ty = threadIdx.x >> 5;
  #pragma unroll
  for (int i = ty; i < 32; i += 8)
    tile[i][tx] = W[(size_t)(r0 + i) * ldw + c0 + tx];
  __syncthreads();
  #pragma unroll
  for (int i = ty; i < 32; i += 8) {
    unsigned short h, l;
    split_f32(tile[tx][i], h, l);
    WThi[(size_t)(c0 + i) * R + r0 + tx] = h;
    WTlo[(size_t)(c0 + i) * R + r0 + tx] = l;
  }
}

// ---------------- bias concat ----------------
__global__ __launch_bounds__(512) void k_catbias(const float* __restrict__ a,
                                                 const float* __restrict__ b,
                                                 float* __restrict__ o) {
  const int i = blockIdx.x * 512 + threadIdx.x;
  o[i] = (i < H3) ? a[i] : b[i - H3];
}

// ---------------- split-bf16 MFMA GEMM (proven) ----------------
__global__ __launch_bounds__(256, 2) void k_gemm_mfma(
    const unsigned short* __restrict__ Ahi, const unsigned short* __restrict__ Alo,
    const unsigned short* __restrict__ BThi, const unsigned short* __restrict__ BTlo,
    const float* __restrict__ bias, float* __restrict__ C,
    int MT, int NT, int K, int ldc) {
  __shared__ unsigned short sAhi[128 * 64], sAlo[128 * 64];
  __shared__ unsigned short sBhi[128 * 64], sBlo[128 * 64];

  const int bid = blockIdx.x;
  const int GROUPM = 8;
  const int group = bid / (GROUPM * NT);
  const int first = group * GROUPM;
  const int gsm = (MT - first < GROUPM) ? (MT - first) : GROUPM;
  const int rem = bid % (GROUPM * NT);
  const int pm = first + rem % gsm;
  const int pn = rem / gsm;
  const int bm = pm * 128, bn = pn * 128;

  const int tid = threadIdx.x;
  const int wv = tid >> 6, l = tid & 63;
  const int wr = wv >> 1, wc = wv & 1;
  const int frow = l & 15;
  const int ksl  = l >> 4;

  f32x4 acc[4][4];
  #pragma unroll
  for (int a = 0; a < 4; ++a)
    #pragma unroll
    for (int b = 0; b < 4; ++b) acc[a][b] = (f32x4){0.f, 0.f, 0.f, 0.f};

  for (int k0 = 0; k0 < K; k0 += 64) {
    __syncthreads();
    #pragma unroll
    for (int p = 0; p < 4; ++p) {
      const int obase = ((p << 2) + wv) << 10;
      const int row = ((obase >> 7)) + (l >> 3);
      const int slot = l & 7;
      const int gcol = k0 + ((slot ^ (row & 7)) << 3);
      const size_t ga = (size_t)(bm + row) * K + gcol;
      const size_t gb = (size_t)(bn + row) * K + gcol;
      GLDS16(Ahi + ga, (char*)sAhi + obase);
      GLDS16(Alo + ga, (char*)sAlo + obase);
      GLDS16(BThi + gb, (char*)sBhi + obase);
      GLDS16(BTlo + gb, (char*)sBlo + obase);
    }
    __syncthreads();
    #pragma unroll
    for (int kk = 0; kk < 2; ++kk) {
      bf16x8 ah[4], al[4], bh[4], bl[4];
      #pragma unroll
      for (int f = 0; f < 4; ++f) {
        const int ar = wr * 64 + f * 16 + frow;
        const int aoff = ar * 128 + ((((kk << 2) + ksl) ^ (ar & 7)) << 4);
        ah[f] = *(const bf16x8*)((const char*)sAhi + aoff);
        al[f] = *(const bf16x8*)((const char*)sAlo + aoff);
        const int br_ = wc * 64 + f * 16 + frow;
        const int boff = br_ * 128 + ((((kk << 2) + ksl) ^ (br_ & 7)) << 4);
        bh[f] = *(const bf16x8*)((const char*)sBhi + boff);
        bl[f] = *(const bf16x8*)((const char*)sBlo + boff);
      }
      #pragma unroll
      for (int fm = 0; fm < 4; ++fm)
        #pragma unroll
        for (int fn = 0; fn < 4; ++fn) {
          acc[fm][fn] = __builtin_amdgcn_mfma_f32_16x16x32_bf16(ah[fm], bh[fn], acc[fm][fn], 0, 0, 0);
          acc[fm][fn] = __builtin_amdgcn_mfma_f32_16x16x32_bf16(ah[fm], bl[fn], acc[fm][fn], 0, 0, 0);
          acc[fm][fn] = __builtin_amdgcn_mfma_f32_16x16x32_bf16(al[fm], bh[fn], acc[fm][fn], 0, 0, 0);
        }
    }
  }

  const int crow0 = bm + wr * 64 + (l >> 4) * 4;
  const int ccol0 = bn + wc * 64 + (l & 15);
  #pragma unroll
  for (int fn = 0; fn < 4; ++fn) {
    const int col = ccol0 + fn * 16;
    const float bv = bias[col];
    #pragma unroll
    for (int fm = 0; fm < 4; ++fm) {
      const int r0 = crow0 + fm * 16;
      #pragma unroll
      for (int i = 0; i < 4; ++i)
        C[(size_t)(r0 + i) * ldc + col] = acc[fm][fn][i] + bv;
    }
  }
}

// ---------------- layer-0 recurrence: 32 MFMA WGs + dataflow tags; 224 helper WGs ----------------
// tag[p][c] at byte p*4096 + c*128 (1 writer, 1 reading wave). RAW: tag t+1 published
// after stores+drain. WAR: tag[c]>=t implies c's step-(t-1) loads done (program order),
// and every producer verifies all 32 tags >= t (8 waves x 4 + syncthreads) before
// overwriting buf[t&1]. hbuf: [buf(2)][plane hi/lo(2)][b(16)][k(1024)] bf16.
// RULE #18: sched_barrier(0) after the inline-asm vmcnt(0) -- MFMA consumers are
// register-only and the "memory" clobber does NOT order them.
__global__ __launch_bounds__(512, 1) void k_recur3(
    const unsigned short* __restrict__ WhTb,   // [3072][1024] bf16
    const float* __restrict__ GX0,             // [4096][3072] f32
    const float* __restrict__ bh0,
    unsigned short* __restrict__ H0hi,
    unsigned short* __restrict__ H0lo,
    unsigned* __restrict__ bar,
    unsigned short* __restrict__ hbuf,
    const float* __restrict__ Wx1,
    const float* __restrict__ Wh1,
    unsigned short* __restrict__ BThi,
    unsigned short* __restrict__ BTlo) {
  __shared__ float red[12288];                 // 48 KB
  const int tid = threadIdx.x;
  const int wg = blockIdx.x;

  if (wg >= 32) {
    // ---------- helper: static-striped Wx1/Wh1 transpose+split into BT, then exit ----------
    float* tile = red;                          // [32][33]
    const int ty = tid >> 5, tx = tid & 31;     // ty in [0,16)
    for (int tix = wg - 32; tix < 6144; tix += 224) {
      const int job = tix >= 3072;
      const int tt = job ? tix - 3072 : tix;
      const int c0 = (tt % 96) * 32, r0 = (tt / 96) * 32;
      const float* W = job ? Wh1 : Wx1;
      unsigned short* Dhi = BThi + (job ? (size_t)H3 * H_ : 0);
      unsigned short* Dlo = BTlo + (job ? (size_t)H3 * H_ : 0);
      __syncthreads();
      tile[ty * 33 + tx]        = W[(size_t)(r0 + ty) * H3 + c0 + tx];
      tile[(ty + 16) * 33 + tx] = W[(size_t)(r0 + ty + 16) * H3 + c0 + tx];
      __syncthreads();
      #pragma unroll
      for (int s = 0; s < 2; ++s) {
        const int i = ty + s * 16;
        unsigned short h, l;
        split_f32(tile[tx * 33 + i], h, l);
        Dhi[(size_t)(c0 + i) * H_ + r0 + tx] = h;
        Dlo[(size_t)(c0 + i) * H_ + r0 + tx] = l;
      }
    }
    return;
  }

  // ---------- participant WG `rank` owns h-cols [32*rank, 32*rank+32) ----------
  const int rank = wg;
  const int wv = tid >> 6, l = tid & 63;
  const int b  = tid >> 5, jj = tid & 31;      // thread -> (batch b, col-offset jj)
  const int col = rank * 32 + jj;

  // one-time Wh B-frags into VGPRs (layouts identical to proven k_gemm_mfma)
  bf16x8 breg[6][4];
  #pragma unroll
  for (int nf = 0; nf < 6; ++nf) {
    const int g = nf >> 1, h2 = nf & 1;
    const int bcol = g * 1024 + rank * 32 + h2 * 16 + (l & 15);
    #pragma unroll
    for (int kf = 0; kf < 4; ++kf)
      breg[nf][kf] = *(const bf16x8*)(WhTb + (size_t)bcol * 1024 + wv * 128 + kf * 32 + ((l >> 4) << 3));
  }
  const float bhr = bh0[col], bhz = bh0[1024 + col], bhn = bh0[2048 + col];

  float xr, xz, xn;
  {
    const size_t g0 = (size_t)(b * T_) * H3;
    xr = GX0[g0 + col]; xz = GX0[g0 + 1024 + col]; xn = GX0[g0 + 2048 + col];
  }
  float hprev = 0.f;

  for (int t = 0; t < T_; ++t) {
    // ---- per-wave dataflow wait: this wave's 4 producers must have published t ----
    if (t > 0) {
      const unsigned* tp = &bar[(unsigned)((4 * wv + (l & 3)) * 32 + rank) * 32];
      int guard = 0;
      for (;;) {
        const unsigned v = AGENT_LD(tp);
        if (__all(v >= (unsigned)t)) break;
        if (++guard > 10000000) break;         // hang guard -> degrade to wrong answer
      }
    }

    // ---- A-frags (h_{t-1} hi/lo planes), coherent loads + RULE-18 fence ----
    const char* ab = (const char*)hbuf + ((t + 1) & 1) * 65536
                     + ((l & 15) * 2048) + (wv * 128 + ((l >> 4) << 3)) * 2;
    bf16x8 ahi[4], alo[4];
    #pragma unroll
    for (int kf = 0; kf < 4; ++kf) {
      asm volatile("global_load_dwordx4 %0, %1, off sc0 sc1" : "=v"(ahi[kf]) : "v"(ab + kf * 64));
      asm volatile("global_load_dwordx4 %0, %1, off sc0 sc1" : "=v"(alo[kf]) : "v"(ab + 32768 + kf * 64));
    }
    asm volatile("s_waitcnt vmcnt(0)" ::: "memory");
    __builtin_amdgcn_sched_barrier(0);         // MFMA must not hoist past the waitcnt

    #pragma unroll
    for (int nf = 0; nf < 6; ++nf) {
      f32x4 a4 = (f32x4){0.f, 0.f, 0.f, 0.f};
      #pragma unroll
      for (int kf = 0; kf < 4; ++kf) {
        a4 = __builtin_amdgcn_mfma_f32_16x16x32_bf16(ahi[kf], breg[nf][kf], a4, 0, 0, 0);
        a4 = __builtin_amdgcn_mfma_f32_16x16x32_bf16(alo[kf], breg[nf][kf], a4, 0, 0, 0);
      }
      *(f32x4*)&red[(((wv * 6 + nf) << 6) + l) << 2] = a4;
    }
    __syncthreads();   // also: all 8 waves passed tag-wait t => all 32 tags >= t (WAR gate)

    // ---- reduce 8 wave-partials + gates; thread = (b, jj) ----
    const int h2 = jj >> 4, f = jj & 15;
    const int lp = ((b >> 2) << 4) + f, ii = b & 3;
    float p3[3];
    #pragma unroll
    for (int g = 0; g < 3; ++g) {
      const int nf = g * 2 + h2;
      float s = 0.f;
      #pragma unroll
      for (int w8 = 0; w8 < 8; ++w8)
        s += red[((((w8 * 6 + nf) << 6) + lp) << 2) + ii];
      p3[g] = s;
    }
    const float r = 1.f / (1.f + expf(-(xr + p3[0] + bhr)));
    const float z = 1.f / (1.f + expf(-(xz + p3[1] + bhz)));
    const float n = tanhf(xn + r * (p3[2] + bhn));
    const float hnew = (1.f - z) * n + z * hprev;
    hprev = hnew;
    unsigned short hh, hl;
    split_f32(hnew, hh, hl);
    const size_t oidx = ((size_t)(b * T_ + t) << 10) + col;
    H0hi[oidx] = hh;
    H0lo[oidx] = hl;

    if (t + 1 < T_) {
      // ---- pack col-pairs, publish h to hbuf planes ----
      const unsigned tmp = (unsigned)hh | ((unsigned)hl << 16);
      const unsigned nb = __shfl_xor(tmp, 1);
      if ((jj & 1) == 0) {
        const unsigned hw = (tmp & 0xffffu) | ((nb & 0xffffu) << 16);
        const unsigned lw = (tmp >> 16) | (nb & 0xffff0000u);
        unsigned* basep = (unsigned*)((char*)hbuf + (t & 1) * 65536);
        const int u32i = ((b << 10) + col) >> 1;
        AGENT_ST(basep + u32i, hw);            // hi plane
        AGENT_ST(basep + 8192 + u32i, lw);     // lo plane (+32768 B)
      }
      __syncthreads();                         // vmcnt(0) drain: h stores at LLC
      if (tid < 32) AGENT_ST(&bar[(unsigned)(rank * 32 + tid) * 32], (unsigned)(t + 1));
      {                                        // GX0 prefetch for t+1 (off critical path)
        const size_t g0 = (size_t)(b * T_ + t + 1) * H3;
        xr = GX0[g0 + col]; xz = GX0[g0 + 1024 + col]; xn = GX0[g0 + 2048 + col];
      }
    }
  }
}

// ---------------- layer-1 elementwise: G1 [rows][6144], hi/lo in, hi/lo out ----------------
__global__ __launch_bounds__(256) void k_gru1(const float* __restrict__ G1,
                                              const unsigned short* __restrict__ H0hi,
                                              const unsigned short* __restrict__ H0lo,
                                              unsigned short* __restrict__ H1hi,
                                              unsigned short* __restrict__ H1lo, int row0) {
  const int lrow = blockIdx.x;
  const size_t row = (size_t)row0 + lrow;
  const float* g = G1 + (size_t)lrow * 6144;
  for (int j = threadIdx.x; j < H_; j += 256) {
    const float xr = g[j], xz = g[1024 + j], xn = g[2048 + j];
    const float hr = g[3072 + j], hz = g[4096 + j], hn = g[5120 + j];
    const size_t idx = (row << 10) + j;
    const float h = join_bf(H0hi[idx], H0lo[idx]);
    const float r = 1.f / (1.f + expf(-(xr + hr)));
    const float z = 1.f / (1.f + expf(-(xz + hz)));
    const float n = tanhf(xn + r * hn);
    const float hnew = (1.f - z) * n + z * h;
    unsigned short hh, hl;
    split_f32(hnew, hh, hl);
    H1hi[idx] = hh;
    H1lo[idx] = hl;
  }
}

// ---------------- final hidden: out[2][B][H] from hi/lo ----------------
__global__ __launch_bounds__(256) void k_hidden(const unsigned short* __restrict__ H0hi,
                                                const unsigned short* __restrict__ H0lo,
                                                const unsigned short* __restrict__ H1hi,
                                                const unsigned short* __restrict__ H1lo,
                                                float* __restrict__ out) {
  const int i = blockIdx.x * 256 + threadIdx.x;
  const int l = i >> 14;
  const int b = (i >> 10) & 15;
  const int j = i & 1023;
  const size_t idx = ((size_t)(b * T_ + T_ - 1) << 10) + j;
  out[i] = l ? join_bf(H1hi[idx], H1lo[idx]) : join_bf(H0hi[idx], H0lo[idx]);
}

extern "C" void kernel_launch(void* const* d_in, const int* in_sizes, int n_in,
                              void* d_out, int out_size, void* d_ws, size_t ws_size,
                              hipStream_t stream) {
  const int*   x   = (const int*)d_in[0];
  const float* emb = (const float*)d_in[1];
  const float* Wx0 = (const float*)d_in[2];
  const float* Wh0 = (const float*)d_in[3];
  const float* bx0 = (const float*)d_in[4];
  const float* bh0 = (const float*)d_in[5];
  const float* Wx1 = (const float*)d_in[6];
  const float* Wh1 = (const float*)d_in[7];
  const float* bx1 = (const float*)d_in[8];
  const float* bh1 = (const float*)d_in[9];
  const float* fcW = (const float*)d_in[10];
  const float* fcb = (const float*)d_in[11];
  float* out = (float*)d_out;

  char* ws = (char*)d_ws;
  const size_t MB = 1024 * 1024;
  // persistent hi/lo hidden states
  unsigned short* H0hi = (unsigned short*)(ws + 0);        // 8 MB [4096][1024]
  unsigned short* H0lo = (unsigned short*)(ws + 8 * MB);
  unsigned short* H1hi = (unsigned short*)(ws + 16 * MB);
  unsigned short* H1lo = (unsigned short*)(ws + 24 * MB);
  char* S = ws + 32 * MB;
  // phase A/B
  unsigned short* WhTb  = (unsigned short*)(S);            // 6 MB
  float*          GX0   = (float*)(S + 8 * MB);            // 48 MB
  unsigned short* EmbHi = (unsigned short*)(S + 56 * MB);  // 4 MB (dead after GX0 gemm)
  unsigned short* EmbLo = (unsigned short*)(S + 60 * MB);  // 4 MB
  unsigned short* Wx0Thi= (unsigned short*)(S + 64 * MB);  // 3 MB
  unsigned short* Wx0Tlo= (unsigned short*)(S + 67 * MB);  // 3 MB
  // written by helper WGs during k_recur3 (over the corpses above):
  unsigned short* BThi  = (unsigned short*)(S + 56 * MB);  // 12 MB [6144][1024] (Wx1T|Wh1T)
  unsigned short* BTlo  = (unsigned short*)(S + 68 * MB);  // 12 MB
  unsigned*       bar   = (unsigned*)(S + 80 * MB);        // 128 KB tag matrix
  unsigned short* hbuf  = (unsigned short*)(S + 80 * MB + 131072);  // 128 KB h planes
  float*          b1cat = (float*)(S + 80 * MB + 262144);  // 24 KB
  // phase C (GX0 corpse)
  float* G1 = (float*)(S + 8 * MB);                        // 48 MB [2048][6144]
  // phase D
  unsigned short* fcThi = (unsigned short*)(S);            // 31.25 MB (16000x1024)
  unsigned short* fcTlo = (unsigned short*)(S + 32 * MB);  // 31.25 MB

  // ---- phase A: embeddings (split), Wh0->bf16, Wx0 split-T, GX0 via MFMA, bias cat ----
  k_embed_split<<<dim3(B_ * T_), dim3(128), 0, stream>>>(x, emb, EmbHi, EmbLo);
  k_transpose_b16<<<dim3(H3 / 32, H_ / 32), dim3(256), 0, stream>>>(Wh0, WhTb);
  k_transpose_split<<<dim3(H3 / 32, E_ / 32), dim3(256), 0, stream>>>(Wx0, H3, Wx0Thi, Wx0Tlo, E_);
  k_gemm_mfma<<<dim3(32 * 24), dim3(256), 0, stream>>>(
      EmbHi, EmbLo, Wx0Thi, Wx0Tlo, bx0, GX0, 32, 24, E_, H3);
  k_catbias<<<dim3(12), dim3(512), 0, stream>>>(bx1, bh1, b1cat);

  // ---- phase B: recurrence (WGs 0-31) + Wx1/Wh1 transposes (WGs 32-255) ----
  hipMemsetAsync(bar, 0, 131072, stream);
  hipMemsetAsync(hbuf, 0, 131072, stream);
  {
    void* args[] = {(void*)&WhTb, (void*)&GX0, (void*)&bh0, (void*)&H0hi, (void*)&H0lo,
                    (void*)&bar, (void*)&hbuf, (void*)&Wx1, (void*)&Wh1,
                    (void*)&BThi, (void*)&BTlo};
    hipLaunchCooperativeKernel((const void*)k_recur3, dim3(256), dim3(512), args, 0, stream);
  }

  // ---- phase C: layer 1, one merged GEMM per chunk (N = 6144) ----
  for (int chunk = 0; chunk < 2; ++chunk) {
    const unsigned short* Ah = H0hi + (size_t)chunk * 2048 * H_;
    const unsigned short* Al = H0lo + (size_t)chunk * 2048 * H_;
    k_gemm_mfma<<<dim3(16 * 48), dim3(256), 0, stream>>>(
        Ah, Al, BThi, BTlo, b1cat, G1, 16, 48, H_, 6144);
    k_gru1<<<dim3(2048), dim3(256), 0, stream>>>(G1, H0hi, H0lo, H1hi, H1lo, chunk * 2048);
  }

  // ---- phase D: FC via split-bf16 MFMA, 2 N-chunks of 16000 ----
  for (int chunk = 0; chunk < 2; ++chunk) {
    const float* Wc = fcW + (size_t)chunk * 16000;
    k_transpose_split<<<dim3(16000 / 32, H_ / 32), dim3(256), 0, stream>>>(
        Wc, V_, fcThi, fcTlo, H_);
    k_gemm_mfma<<<dim3(32 * 125), dim3(256), 0, stream>>>(
        H1hi, H1lo, fcThi, fcTlo, fcb + (size_t)chunk * 16000,
        out + (size_t)chunk * 16000, 32, 125, H_, V_);
  }

  // ---- final hidden ----
  k_hidden<<<dim3(32768 / 256), dim3(256), 0, stream>>>(H0hi, H0lo, H1hi, H1lo,
                                                        out + (size_t)B_ * T_ * V_);
}